// Round 1
// baseline (18656.261 us; speedup 1.0000x reference)
//
#include <hip/hip_runtime.h>
#include <math.h>

#define NTOK 16130   // 1 + 127*127
#define NPAD 16384
#define PADF 254
#define NB   2
#define DM   512
#define NH   8
#define HD   64
#define LM   256
#define SEG  64

// ---------------- reductions (256-thread blocks, wave64) ----------------
__device__ __forceinline__ float wred_max(float v){
  #pragma unroll
  for(int o=32;o;o>>=1) v=fmaxf(v,__shfl_xor(v,o));
  return v;
}
__device__ __forceinline__ float wred_sum(float v){
  #pragma unroll
  for(int o=32;o;o>>=1) v+=__shfl_xor(v,o);
  return v;
}
__device__ __forceinline__ float block_max256(float v, float* s4){
  v=wred_max(v);
  if((threadIdx.x&63)==0) s4[threadIdx.x>>6]=v;
  __syncthreads();
  v=fmaxf(fmaxf(s4[0],s4[1]),fmaxf(s4[2],s4[3]));
  __syncthreads();
  return v;
}
__device__ __forceinline__ float block_sum256(float v, float* s4){
  v=wred_sum(v);
  if((threadIdx.x&63)==0) s4[threadIdx.x>>6]=v;
  __syncthreads();
  v=s4[0]+s4[1]+s4[2]+s4[3];
  __syncthreads();
  return v;
}

// ---------------- fc1: (32000x1024)@(1024x512)+bias, relu, scatter ----------------
__global__ __launch_bounds__(256) void k_gemm_fc1(
    const float* __restrict__ A, const float* __restrict__ W,
    const float* __restrict__ bias, float* __restrict__ h)
{
  const int K=1024, Nn=512;
  __shared__ float As[16][65], Bs[16][65];
  int tid=threadIdx.x;
  int row0=blockIdx.y*64, col0=blockIdx.x*64;
  int ty=tid>>4, tx=tid&15;
  float acc[4][4]={};
  for(int k0=0;k0<K;k0+=16){
    #pragma unroll
    for(int i=0;i<4;i++){int idx=tid+256*i; int r=idx>>4, kk=idx&15;
      As[kk][r]=A[(size_t)(row0+r)*K + k0+kk];}
    #pragma unroll
    for(int i=0;i<4;i++){int idx=tid+256*i; int kk=idx>>6, c=idx&63;
      Bs[kk][c]=W[(size_t)(k0+kk)*Nn + col0+c];}
    __syncthreads();
    #pragma unroll
    for(int kk=0;kk<16;kk++){
      float a[4],b[4];
      #pragma unroll
      for(int i=0;i<4;i++) a[i]=As[kk][ty*4+i];
      #pragma unroll
      for(int j=0;j<4;j++) b[j]=Bs[kk][tx*4+j];
      #pragma unroll
      for(int i=0;i<4;i++)
        #pragma unroll
        for(int j=0;j<4;j++) acc[i][j]+=a[i]*b[j];
    }
    __syncthreads();
  }
  #pragma unroll
  for(int i=0;i<4;i++){
    int r=row0+ty*4+i; int bb=r/16000, ii=r%16000;
    #pragma unroll
    for(int j=0;j<4;j++){
      int c=col0+tx*4+j;
      float val=fmaxf(acc[i][j]+bias[c],0.f);
      h[((size_t)bb*NTOK + 1 + ii)*DM + c]=val;
      if(ii<129) h[((size_t)bb*NTOK + 16001 + ii)*DM + c]=val;
    }
  }
}

__global__ void k_cls(const float* __restrict__ cls, float* __restrict__ h){
  int t=blockIdx.x*256+threadIdx.x;  // 1024 total
  if(t<2*DM) h[(size_t)(t>>9)*NTOK*DM + (t&511)]=cls[t&511];
}

// ---------------- layernorm + front zero-pad ----------------
__global__ __launch_bounds__(256) void k_lnpad(
    const float* __restrict__ h, const float* __restrict__ g,
    const float* __restrict__ bta, float* __restrict__ xln)
{
  int r=blockIdx.x;          // 0..32767
  int bb=r>>14, i=r&16383;
  int t=threadIdx.x;
  float* dst=xln+(size_t)r*DM;
  if(i<PADF){ dst[t]=0.f; dst[t+256]=0.f; return; }
  const float* src=h+((size_t)bb*NTOK + (i-PADF))*DM;
  float x0=src[t], x1=src[t+256];
  __shared__ float s4[4];
  float mu=block_sum256(x0+x1,s4)*(1.f/512.f);
  float d0=x0-mu, d1=x1-mu;
  float var=block_sum256(d0*d0+d1*d1,s4)*(1.f/512.f);
  float rst=rsqrtf(var+1e-5f);
  dst[t]    =d0*rst*g[t]    +bta[t];
  dst[t+256]=d1*rst*g[t+256]+bta[t+256];
}

// ---------------- qkv: (32768x512)@(512x1536), scatter head-major ----------------
__global__ __launch_bounds__(256) void k_gemm_qkv(
    const float* __restrict__ A, const float* __restrict__ W,
    float* __restrict__ qo, float* __restrict__ ko, float* __restrict__ vo)
{
  const int K=DM, Nn=3*DM;
  __shared__ float As[16][65], Bs[16][65];
  int tid=threadIdx.x;
  int row0=blockIdx.y*64, col0=blockIdx.x*64;
  int ty=tid>>4, tx=tid&15;
  float acc[4][4]={};
  for(int k0=0;k0<K;k0+=16){
    #pragma unroll
    for(int i=0;i<4;i++){int idx=tid+256*i; int r=idx>>4, kk=idx&15;
      As[kk][r]=A[(size_t)(row0+r)*K + k0+kk];}
    #pragma unroll
    for(int i=0;i<4;i++){int idx=tid+256*i; int kk=idx>>6, c=idx&63;
      Bs[kk][c]=W[(size_t)(k0+kk)*Nn + col0+c];}
    __syncthreads();
    #pragma unroll
    for(int kk=0;kk<16;kk++){
      float a[4],b[4];
      #pragma unroll
      for(int i=0;i<4;i++) a[i]=As[kk][ty*4+i];
      #pragma unroll
      for(int j=0;j<4;j++) b[j]=Bs[kk][tx*4+j];
      #pragma unroll
      for(int i=0;i<4;i++)
        #pragma unroll
        for(int j=0;j<4;j++) acc[i][j]+=a[i]*b[j];
    }
    __syncthreads();
  }
  #pragma unroll
  for(int i=0;i<4;i++){
    int r=row0+ty*4+i; int bb=r>>14, rr=r&16383;
    #pragma unroll
    for(int j=0;j<4;j++){
      int c=col0+tx*4+j;
      int which=c>>9, hcol=c&511, head=hcol>>6, dd=hcol&63;
      float val=acc[i][j];
      size_t o=(((size_t)bb*NH+head)*NPAD + rr)*HD + dd;
      if(which==0)      qo[o]=val*0.125f;
      else if(which==1) ko[o]=val;
      else              vo[o]=val;
    }
  }
}

// ---------------- landmark means ----------------
__global__ void k_lmean(const float* __restrict__ src, float* __restrict__ dst){
  int bh=blockIdx.x>>8, s=blockIdx.x&255, d=threadIdx.x;  // 64 threads
  const float* p=src + (((size_t)bh*NPAD)+s*SEG)*HD + d;
  float acc=0.f;
  #pragma unroll
  for(int l=0;l<SEG;l++) acc+=p[(size_t)l*HD];
  dst[((size_t)bh*LM+s)*HD+d]=acc*(1.f/64.f);
}

// ---------------- attn2 = softmax(ql @ kl^T) ----------------
__global__ __launch_bounds__(256) void k_attn2(
    const float* __restrict__ ql, const float* __restrict__ kl, float* __restrict__ attn2)
{
  __shared__ float qrow[64]; __shared__ float s4[4];
  int bh=blockIdx.x>>8, i=blockIdx.x&255, j=threadIdx.x;
  if(j<64) qrow[j]=ql[((size_t)bh*LM+i)*HD+j];
  __syncthreads();
  const float* kp=kl+((size_t)bh*LM+j)*HD;
  float l=0.f;
  #pragma unroll
  for(int d=0;d<64;d++) l+=qrow[d]*kp[d];
  float m=block_max256(l,s4);
  float e=__expf(l-m);
  float s=block_sum256(e,s4);
  attn2[((size_t)bh*LM+i)*LM+j]=e/s;
}

// ---------------- pinv helpers ----------------
__global__ void k_rowsum(const float* __restrict__ x, float* __restrict__ rs){
  __shared__ float s4[4];
  size_t row=blockIdx.x;
  float v=x[row*256+threadIdx.x];
  float s=block_sum256(v,s4);
  if(threadIdx.x==0) rs[row]=s;
}
__global__ void k_colsum(const float* __restrict__ x, float* __restrict__ cs){
  int bh=blockIdx.x, j=threadIdx.x;
  const float* p=x+(size_t)bh*65536;
  float s=0.f;
  for(int i=0;i<256;i++) s+=p[(size_t)i*256+j];
  cs[bh*256+j]=s;
}
__global__ void k_pinvscale(const float* __restrict__ rs, const float* __restrict__ cs,
                            float* __restrict__ scale){
  __shared__ float s4[4];
  float mr=-1e30f, mc=-1e30f;
  for(int i=threadIdx.x;i<4096;i+=256){ mr=fmaxf(mr,rs[i]); mc=fmaxf(mc,cs[i]); }
  mr=block_max256(mr,s4);
  mc=block_max256(mc,s4);
  if(threadIdx.x==0) scale[0]=1.f/(mr*mc);
}
__global__ void k_zinit(const float* __restrict__ x, const float* __restrict__ scale,
                        float* __restrict__ z){
  int bh=blockIdx.x>>8, i=blockIdx.x&255, j=threadIdx.x;
  z[((size_t)bh*LM+i)*LM+j]=x[((size_t)bh*LM+j)*LM+i]*scale[0];
}
__global__ void k_negident(const float* __restrict__ in, float* __restrict__ out, float c0){
  size_t idx=(size_t)blockIdx.x*256+threadIdx.x;
  int i=(idx>>8)&255, j=idx&255;
  out[idx]=((i==j)?c0:0.f)-in[idx];
}

// ---------------- batched 256-class GEMM (pinv + W2) ----------------
__global__ __launch_bounds__(256) void k_bmm(
    const float* __restrict__ Ag, const float* __restrict__ Bg, float* __restrict__ Cg,
    int M, int N, int K, float alpha)
{
  const float* A=Ag+(size_t)blockIdx.z*M*K;
  const float* Bm=Bg+(size_t)blockIdx.z*K*N;
  float* C=Cg+(size_t)blockIdx.z*M*N;
  __shared__ float As[16][65], Bs[16][65];
  int tid=threadIdx.x;
  int row0=blockIdx.y*64, col0=blockIdx.x*64;
  int ty=tid>>4, tx=tid&15;
  float acc[4][4]={};
  for(int k0=0;k0<K;k0+=16){
    #pragma unroll
    for(int i=0;i<4;i++){int idx=tid+256*i; int r=idx>>4, kk=idx&15;
      As[kk][r]=A[(size_t)(row0+r)*K + k0+kk];}
    #pragma unroll
    for(int i=0;i<4;i++){int idx=tid+256*i; int kk=idx>>6, c=idx&63;
      Bs[kk][c]=Bm[(size_t)(k0+kk)*N + col0+c];}
    __syncthreads();
    #pragma unroll
    for(int kk=0;kk<16;kk++){
      float a[4],b[4];
      #pragma unroll
      for(int i=0;i<4;i++) a[i]=As[kk][ty*4+i];
      #pragma unroll
      for(int j=0;j<4;j++) b[j]=Bs[kk][tx*4+j];
      #pragma unroll
      for(int i=0;i<4;i++)
        #pragma unroll
        for(int j=0;j<4;j++) acc[i][j]+=a[i]*b[j];
    }
    __syncthreads();
  }
  #pragma unroll
  for(int i=0;i<4;i++){
    int r=row0+ty*4+i;
    #pragma unroll
    for(int j=0;j<4;j++) C[(size_t)r*N + col0+tx*4+j]=alpha*acc[i][j];
  }
}

// ---------------- attn3@v : flash-style, one block per (bh,landmark) ----------------
__global__ __launch_bounds__(256) void k_attn3v(
    const float* __restrict__ ql, const float* __restrict__ kk_,
    const float* __restrict__ vv, float* __restrict__ out)
{
  int bh=blockIdx.x>>8, i=blockIdx.x&255, t=threadIdx.x;
  __shared__ float qrow[64], p[256], s4[4], part[4][64], acc[64], state[2];
  if(t<64){ qrow[t]=ql[((size_t)bh*LM+i)*HD+t]; acc[t]=0.f; }
  if(t==0){ state[0]=-1e30f; state[1]=0.f; }
  __syncthreads();
  const float* kbase=kk_+(size_t)bh*NPAD*HD;
  const float* vbase=vv +(size_t)bh*NPAD*HD;
  for(int ch=0; ch<NPAD; ch+=256){
    const float* krow=kbase+(size_t)(ch+t)*HD;
    float l=0.f;
    #pragma unroll
    for(int d=0;d<64;d++) l+=qrow[d]*krow[d];
    float mc=block_max256(l,s4);
    float mold=state[0];
    float mnew=fmaxf(mold,mc);
    float e=__expf(l-mnew);
    p[t]=e;
    float es=block_sum256(e,s4);     // includes barriers -> p[] visible
    float f=__expf(mold-mnew);
    int td=t&63, pa=t>>6;
    float a=0.f;
    const float* vp=vbase+(size_t)(ch+pa*64)*HD+td;
    #pragma unroll
    for(int l2=0;l2<64;l2++) a+=p[pa*64+l2]*vp[(size_t)l2*HD];
    part[pa][td]=a;
    __syncthreads();
    if(t<64) acc[t]=acc[t]*f + part[0][t]+part[1][t]+part[2][t]+part[3][t];
    if(t==0){ state[1]=state[1]*f+es; state[0]=mnew; }
    __syncthreads();
  }
  if(t<64) out[((size_t)bh*LM+i)*HD+t]=acc[t]/state[1];
}

// ---------------- attn1 @ W2 : one block per query row ----------------
__global__ __launch_bounds__(256) void k_attn1(
    const float* __restrict__ qq, const float* __restrict__ kl,
    const float* __restrict__ W2, float* __restrict__ aoh)
{
  int bh=blockIdx.x>>14, i=blockIdx.x&16383, t=threadIdx.x;
  __shared__ float qrow[64], p[256], s4[4], part[4][64];
  if(t<64) qrow[t]=qq[((size_t)bh*NPAD+i)*HD+t];
  __syncthreads();
  const float* kp=kl+((size_t)bh*LM+t)*HD;
  float l=0.f;
  #pragma unroll
  for(int d=0;d<64;d++) l+=qrow[d]*kp[d];
  float m=block_max256(l,s4);
  float e=__expf(l-m);
  float s=block_sum256(e,s4);
  p[t]=e/s;
  __syncthreads();
  int td=t&63, pa=t>>6;
  const float* wp=W2+((size_t)bh*LM+pa*64)*HD+td;
  float a=0.f;
  #pragma unroll
  for(int j=0;j<64;j++) a+=p[pa*64+j]*wp[(size_t)j*HD];
  part[pa][td]=a;
  __syncthreads();
  if(t<64) aoh[((size_t)bh*NPAD+i)*HD+t]=part[0][t]+part[1][t]+part[2][t]+part[3][t];
}

// ---------------- depthwise 33-tap conv on v, += into aoh ----------------
__global__ void k_resconv(const float* __restrict__ vv, const float* __restrict__ rw,
                          float* __restrict__ aoh){
  size_t idx=(size_t)blockIdx.x*256+threadIdx.x;  // 2*8*16384*64
  int d=idx&63; size_t r=idx>>6; int i=r&16383; int bh=(int)(r>>14); int hh=bh&7;
  const float* vb=vv+((size_t)bh*NPAD)*HD+d;
  float a=0.f;
  #pragma unroll
  for(int tk=0;tk<33;tk++){
    int src=i+tk-16;
    if(src>=0 && src<NPAD) a+=vb[(size_t)src*HD]*rw[hh*33+tk];
  }
  aoh[idx]+=a;
}

// ---------------- head-major -> row-major merge ----------------
__global__ void k_headmerge(const float* __restrict__ aoh, float* __restrict__ ao){
  size_t idx=(size_t)blockIdx.x*256+threadIdx.x;  // 2*16384*512
  int c=idx&511; size_t r=idx>>9; int i=r&16383; int bb=(int)(r>>14);
  int hh=c>>6, dd=c&63;
  ao[idx]=aoh[(((size_t)bb*NH+hh)*NPAD+i)*HD+dd];
}

// ---------------- out proj: (32768x512)@(512x512)+bias, residual add into h ----------------
__global__ __launch_bounds__(256) void k_gemm_proj(
    const float* __restrict__ A, const float* __restrict__ W,
    const float* __restrict__ bias, float* __restrict__ h)
{
  const int K=DM, Nn=DM;
  __shared__ float As[16][65], Bs[16][65];
  int tid=threadIdx.x;
  int row0=blockIdx.y*64, col0=blockIdx.x*64;
  int ty=tid>>4, tx=tid&15;
  float acc[4][4]={};
  for(int k0=0;k0<K;k0+=16){
    #pragma unroll
    for(int i=0;i<4;i++){int idx=tid+256*i; int r=idx>>4, kk=idx&15;
      As[kk][r]=A[(size_t)(row0+r)*K + k0+kk];}
    #pragma unroll
    for(int i=0;i<4;i++){int idx=tid+256*i; int kk=idx>>6, c=idx&63;
      Bs[kk][c]=W[(size_t)(k0+kk)*Nn + col0+c];}
    __syncthreads();
    #pragma unroll
    for(int kk=0;kk<16;kk++){
      float a[4],b[4];
      #pragma unroll
      for(int i=0;i<4;i++) a[i]=As[kk][ty*4+i];
      #pragma unroll
      for(int j=0;j<4;j++) b[j]=Bs[kk][tx*4+j];
      #pragma unroll
      for(int i=0;i<4;i++)
        #pragma unroll
        for(int j=0;j<4;j++) acc[i][j]+=a[i]*b[j];
    }
    __syncthreads();
  }
  #pragma unroll
  for(int i=0;i<4;i++){
    int r=row0+ty*4+i; int bb=r>>14, rr=r&16383;
    if(rr<PADF) continue;
    #pragma unroll
    for(int j=0;j<4;j++){
      int c=col0+tx*4+j;
      h[((size_t)bb*NTOK + (rr-PADF))*DM + c]+=acc[i][j]+bias[c];
    }
  }
}

// ---------------- PPEG: y = cnn + dw7 + dw5 + dw3 (127x127, depthwise 512) ----------------
__global__ void k_ppeg(const float* __restrict__ src,
                       const float* __restrict__ w7, const float* __restrict__ b7,
                       const float* __restrict__ w5, const float* __restrict__ b5,
                       const float* __restrict__ w3, const float* __restrict__ b3,
                       float* __restrict__ h){
  size_t idx=(size_t)blockIdx.x*256+threadIdx.x;   // 2*16129*512
  int c=idx&511; size_t r=idx>>9; int pos=(int)(r%16129); int bb=(int)(r/16129);
  int y=pos/127, x=pos%127;
  const float* base=src+((size_t)bb*NTOK+1)*DM+c;
  float acc=base[(size_t)pos*DM] + b7[c]+b5[c]+b3[c];
  #pragma unroll
  for(int ky=0;ky<7;ky++){ int yy=y+ky-3; if(yy<0||yy>=127) continue;
    #pragma unroll
    for(int kx=0;kx<7;kx++){ int xx=x+kx-3; if(xx<0||xx>=127) continue;
      acc+=base[(size_t)(yy*127+xx)*DM]*w7[(size_t)c*49+ky*7+kx]; } }
  #pragma unroll
  for(int ky=0;ky<5;ky++){ int yy=y+ky-2; if(yy<0||yy>=127) continue;
    #pragma unroll
    for(int kx=0;kx<5;kx++){ int xx=x+kx-2; if(xx<0||xx>=127) continue;
      acc+=base[(size_t)(yy*127+xx)*DM]*w5[(size_t)c*25+ky*5+kx]; } }
  #pragma unroll
  for(int ky=0;ky<3;ky++){ int yy=y+ky-1; if(yy<0||yy>=127) continue;
    #pragma unroll
    for(int kx=0;kx<3;kx++){ int xx=x+kx-1; if(xx<0||xx>=127) continue;
      acc+=base[(size_t)(yy*127+xx)*DM]*w3[(size_t)c*9+ky*3+kx]; } }
  h[((size_t)bb*NTOK+1+pos)*DM+c]=acc;
}

// ---------------- final: LN(h[:,0]) @ fc2 + b ----------------
__global__ __launch_bounds__(256) void k_final(
    const float* __restrict__ h, const float* __restrict__ g, const float* __restrict__ bta,
    const float* __restrict__ w, const float* __restrict__ fb, float* __restrict__ out)
{
  int bb=blockIdx.x, t=threadIdx.x;
  const float* src=h+(size_t)bb*NTOK*DM;
  float x0=src[t], x1=src[t+256];
  __shared__ float s4[4];
  float mu=block_sum256(x0+x1,s4)*(1.f/512.f);
  float d0=x0-mu, d1=x1-mu;
  float var=block_sum256(d0*d0+d1*d1,s4)*(1.f/512.f);
  float rst=rsqrtf(var+1e-5f);
  float y0=d0*rst*g[t]+bta[t], y1=d1*rst*g[t+256]+bta[t+256];
  float dot=block_sum256(y0*w[t]+y1*w[t+256],s4);
  if(t==0) out[bb]=dot+fb[0];
}

// =======================================================================
extern "C" void kernel_launch(void* const* d_in, const int* in_sizes, int n_in,
                              void* d_out, int out_size, void* d_ws, size_t ws_size,
                              hipStream_t stream){
  (void)in_sizes; (void)n_in; (void)out_size;
  const float* features=(const float*)d_in[0];
  const float* fc1_w  =(const float*)d_in[1];
  const float* fc1_b  =(const float*)d_in[2];
  const float* cls_tok=(const float*)d_in[3];
  const float* fc2_w  =(const float*)d_in[24];
  const float* fc2_b  =(const float*)d_in[25];
  float* out=(float*)d_out;

  char* wp=(char*)d_ws;
  auto alloc=[&](size_t floats)->float*{
    float* p=(float*)wp; wp+=((floats*4+255)/256)*256; return p;
  };
  float* h   =alloc((size_t)NB*NTOK*DM);
  float* xln =alloc((size_t)NB*NPAD*DM);
  float* q   =alloc((size_t)NB*NPAD*DM);
  float* kbuf=alloc((size_t)NB*NPAD*DM);
  float* v   =alloc((size_t)NB*NPAD*DM);
  float* ql  =alloc((size_t)16*LM*HD);
  float* kl  =alloc((size_t)16*LM*HD);
  float* attn2=alloc((size_t)16*LM*LM);
  float* z0  =alloc((size_t)16*LM*LM);
  float* z1  =alloc((size_t)16*LM*LM);
  float* Ab  =alloc((size_t)16*LM*LM);
  float* Ub  =alloc((size_t)16*LM*LM);
  float* Tb  =alloc((size_t)16*LM*LM);
  float* a3v =alloc((size_t)16*LM*HD);
  float* W2b =alloc((size_t)16*LM*HD);
  float* rs  =alloc(4096);
  float* cs  =alloc(4096);
  float* scl =alloc(64);
  (void)ws_size;
  float* aoh=kbuf;   // reuse: k dead after attn3v
  float* ao =xln;    // reuse: xln dead after qkv

  auto nystrom=[&](const float* ng, const float* nbias, const float* qkvw,
                   const float* outw, const float* outb, const float* resw){
    k_lnpad<<<NB*NPAD,256,0,stream>>>(h, ng, nbias, xln);
    k_gemm_qkv<<<dim3(24,512),256,0,stream>>>(xln, qkvw, q, kbuf, v);
    k_lmean<<<4096,64,0,stream>>>(q, ql);
    k_lmean<<<4096,64,0,stream>>>(kbuf, kl);
    k_attn2<<<4096,256,0,stream>>>(ql, kl, attn2);
    k_rowsum<<<4096,256,0,stream>>>(attn2, rs);
    k_colsum<<<16,256,0,stream>>>(attn2, cs);
    k_pinvscale<<<1,256,0,stream>>>(rs, cs, scl);
    k_zinit<<<4096,256,0,stream>>>(attn2, scl, z0);
    float* zc=z0; float* zn=z1;
    for(int it=0;it<6;it++){
      k_bmm<<<dim3(4,4,16),256,0,stream>>>(attn2, zc, Ab, 256,256,256, 1.f);
      k_negident<<<4096,256,0,stream>>>(Ab, Tb, 7.f);
      k_bmm<<<dim3(4,4,16),256,0,stream>>>(Ab, Tb, Ub, 256,256,256, 1.f);
      k_negident<<<4096,256,0,stream>>>(Ub, Ub, 15.f);
      k_bmm<<<dim3(4,4,16),256,0,stream>>>(Ab, Ub, Tb, 256,256,256, 1.f);
      k_negident<<<4096,256,0,stream>>>(Tb, Tb, 13.f);
      k_bmm<<<dim3(4,4,16),256,0,stream>>>(zc, Tb, zn, 256,256,256, 0.25f);
      float* tp=zc; zc=zn; zn=tp;
    }
    k_attn3v<<<4096,256,0,stream>>>(ql, kbuf, v, a3v);
    k_bmm<<<dim3(1,4,16),256,0,stream>>>(zc, a3v, W2b, 256,64,256, 1.f);
    k_attn1<<<NB*NH*NPAD,256,0,stream>>>(q, kl, W2b, aoh);
    k_resconv<<<65536,256,0,stream>>>(v, resw, aoh);
    k_headmerge<<<65536,256,0,stream>>>(aoh, ao);
    k_gemm_proj<<<dim3(8,512),256,0,stream>>>(ao, outw, outb, h);
  };

  // fc1 + relu + dup + cls
  k_gemm_fc1<<<dim3(8,500),256,0,stream>>>(features, fc1_w, fc1_b, h);
  k_cls<<<4,256,0,stream>>>(cls_tok, h);

  // layer 1 attention
  nystrom((const float*)d_in[4],(const float*)d_in[5],(const float*)d_in[6],
          (const float*)d_in[7],(const float*)d_in[8],(const float*)d_in[9]);

  // PPEG (q buffer is free here; use as conv source copy)
  float* tmp=q;
  hipMemcpyAsync(tmp, h, (size_t)NB*NTOK*DM*4, hipMemcpyDeviceToDevice, stream);
  k_ppeg<<<64516,256,0,stream>>>(tmp,
      (const float*)d_in[10],(const float*)d_in[11],
      (const float*)d_in[12],(const float*)d_in[13],
      (const float*)d_in[14],(const float*)d_in[15], h);

  // layer 2 attention
  nystrom((const float*)d_in[16],(const float*)d_in[17],(const float*)d_in[18],
          (const float*)d_in[19],(const float*)d_in[20],(const float*)d_in[21]);

  // final LN(row0) @ fc2
  k_final<<<2,256,0,stream>>>(h,(const float*)d_in[22],(const float*)d_in[23],
                              fc2_w, fc2_b, out);
}

// Round 2
// 9851.801 us; speedup vs baseline: 1.8937x; 1.8937x over previous
//
#include <hip/hip_runtime.h>
#include <math.h>

#define NTOK 16130   // 1 + 127*127
#define NPAD 16384
#define PADF 254
#define NB   2
#define DM   512
#define NH   8
#define HD   64
#define LM   256
#define SEG  64

// ---------------- reductions (wave64) ----------------
__device__ __forceinline__ float wred_max(float v){
  #pragma unroll
  for(int o=32;o;o>>=1) v=fmaxf(v,__shfl_xor(v,o));
  return v;
}
__device__ __forceinline__ float wred_sum(float v){
  #pragma unroll
  for(int o=32;o;o>>=1) v+=__shfl_xor(v,o);
  return v;
}
__device__ __forceinline__ float block_max256(float v, float* s4){
  v=wred_max(v);
  if((threadIdx.x&63)==0) s4[threadIdx.x>>6]=v;
  __syncthreads();
  v=fmaxf(fmaxf(s4[0],s4[1]),fmaxf(s4[2],s4[3]));
  __syncthreads();
  return v;
}
__device__ __forceinline__ float block_sum256(float v, float* s4){
  v=wred_sum(v);
  if((threadIdx.x&63)==0) s4[threadIdx.x>>6]=v;
  __syncthreads();
  v=s4[0]+s4[1]+s4[2]+s4[3];
  __syncthreads();
  return v;
}
// uniform-lane broadcast via v_readlane (no DS traffic)
__device__ __forceinline__ float RL(float v, int l){
  return __int_as_float(__builtin_amdgcn_readlane(__float_as_int(v), l));
}

// ---------------- fc1: (32000x1024)@(1024x512)+bias, relu, scatter ----------------
__global__ __launch_bounds__(256) void k_gemm_fc1(
    const float* __restrict__ A, const float* __restrict__ W,
    const float* __restrict__ bias, float* __restrict__ h)
{
  const int K=1024, Nn=512;
  __shared__ float As[16][65], Bs[16][65];
  int tid=threadIdx.x;
  int row0=blockIdx.y*64, col0=blockIdx.x*64;
  int ty=tid>>4, tx=tid&15;
  float acc[4][4]={};
  for(int k0=0;k0<K;k0+=16){
    #pragma unroll
    for(int i=0;i<4;i++){int idx=tid+256*i; int r=idx>>4, kk=idx&15;
      As[kk][r]=A[(size_t)(row0+r)*K + k0+kk];}
    #pragma unroll
    for(int i=0;i<4;i++){int idx=tid+256*i; int kk=idx>>6, c=idx&63;
      Bs[kk][c]=W[(size_t)(k0+kk)*Nn + col0+c];}
    __syncthreads();
    #pragma unroll
    for(int kk=0;kk<16;kk++){
      float a[4],b[4];
      #pragma unroll
      for(int i=0;i<4;i++) a[i]=As[kk][ty*4+i];
      #pragma unroll
      for(int j=0;j<4;j++) b[j]=Bs[kk][tx*4+j];
      #pragma unroll
      for(int i=0;i<4;i++)
        #pragma unroll
        for(int j=0;j<4;j++) acc[i][j]+=a[i]*b[j];
    }
    __syncthreads();
  }
  #pragma unroll
  for(int i=0;i<4;i++){
    int r=row0+ty*4+i; int bb=r/16000, ii=r%16000;
    #pragma unroll
    for(int j=0;j<4;j++){
      int c=col0+tx*4+j;
      float val=fmaxf(acc[i][j]+bias[c],0.f);
      h[((size_t)bb*NTOK + 1 + ii)*DM + c]=val;
      if(ii<129) h[((size_t)bb*NTOK + 16001 + ii)*DM + c]=val;
    }
  }
}

__global__ void k_cls(const float* __restrict__ cls, float* __restrict__ h){
  int t=blockIdx.x*256+threadIdx.x;  // 1024 total
  if(t<2*DM) h[(size_t)(t>>9)*NTOK*DM + (t&511)]=cls[t&511];
}

// ---------------- layernorm + front zero-pad ----------------
__global__ __launch_bounds__(256) void k_lnpad(
    const float* __restrict__ h, const float* __restrict__ g,
    const float* __restrict__ bta, float* __restrict__ xln)
{
  int r=blockIdx.x;          // 0..32767
  int bb=r>>14, i=r&16383;
  int t=threadIdx.x;
  float* dst=xln+(size_t)r*DM;
  if(i<PADF){ dst[t]=0.f; dst[t+256]=0.f; return; }
  const float* src=h+((size_t)bb*NTOK + (i-PADF))*DM;
  float x0=src[t], x1=src[t+256];
  __shared__ float s4[4];
  float mu=block_sum256(x0+x1,s4)*(1.f/512.f);
  float d0=x0-mu, d1=x1-mu;
  float var=block_sum256(d0*d0+d1*d1,s4)*(1.f/512.f);
  float rst=rsqrtf(var+1e-5f);
  dst[t]    =d0*rst*g[t]    +bta[t];
  dst[t+256]=d1*rst*g[t+256]+bta[t+256];
}

// ---------------- qkv: (32768x512)@(512x1536), scatter head-major ----------------
__global__ __launch_bounds__(256) void k_gemm_qkv(
    const float* __restrict__ A, const float* __restrict__ W,
    float* __restrict__ qo, float* __restrict__ ko, float* __restrict__ vo)
{
  const int K=DM, Nn=3*DM;
  __shared__ float As[16][65], Bs[16][65];
  int tid=threadIdx.x;
  int row0=blockIdx.y*64, col0=blockIdx.x*64;
  int ty=tid>>4, tx=tid&15;
  float acc[4][4]={};
  for(int k0=0;k0<K;k0+=16){
    #pragma unroll
    for(int i=0;i<4;i++){int idx=tid+256*i; int r=idx>>4, kk=idx&15;
      As[kk][r]=A[(size_t)(row0+r)*K + k0+kk];}
    #pragma unroll
    for(int i=0;i<4;i++){int idx=tid+256*i; int kk=idx>>6, c=idx&63;
      Bs[kk][c]=W[(size_t)(k0+kk)*Nn + col0+c];}
    __syncthreads();
    #pragma unroll
    for(int kk=0;kk<16;kk++){
      float a[4],b[4];
      #pragma unroll
      for(int i=0;i<4;i++) a[i]=As[kk][ty*4+i];
      #pragma unroll
      for(int j=0;j<4;j++) b[j]=Bs[kk][tx*4+j];
      #pragma unroll
      for(int i=0;i<4;i++)
        #pragma unroll
        for(int j=0;j<4;j++) acc[i][j]+=a[i]*b[j];
    }
    __syncthreads();
  }
  #pragma unroll
  for(int i=0;i<4;i++){
    int r=row0+ty*4+i; int bb=r>>14, rr=r&16383;
    #pragma unroll
    for(int j=0;j<4;j++){
      int c=col0+tx*4+j;
      int which=c>>9, hcol=c&511, head=hcol>>6, dd=hcol&63;
      float val=acc[i][j];
      size_t o=(((size_t)bb*NH+head)*NPAD + rr)*HD + dd;
      if(which==0)      qo[o]=val*0.125f;
      else if(which==1) ko[o]=val;
      else              vo[o]=val;
    }
  }
}

// ---------------- landmark means ----------------
__global__ void k_lmean(const float* __restrict__ src, float* __restrict__ dst){
  int bh=blockIdx.x>>8, s=blockIdx.x&255, d=threadIdx.x;  // 64 threads
  const float* p=src + (((size_t)bh*NPAD)+s*SEG)*HD + d;
  float acc=0.f;
  #pragma unroll
  for(int l=0;l<SEG;l++) acc+=p[(size_t)l*HD];
  dst[((size_t)bh*LM+s)*HD+d]=acc*(1.f/64.f);
}

// ---------------- attn2 = softmax(ql @ kl^T) ----------------
__global__ __launch_bounds__(256) void k_attn2(
    const float* __restrict__ ql, const float* __restrict__ kl, float* __restrict__ attn2)
{
  __shared__ float qrow[64]; __shared__ float s4[4];
  int bh=blockIdx.x>>8, i=blockIdx.x&255, j=threadIdx.x;
  if(j<64) qrow[j]=ql[((size_t)bh*LM+i)*HD+j];
  __syncthreads();
  const float* kp=kl+((size_t)bh*LM+j)*HD;
  float l=0.f;
  #pragma unroll
  for(int d=0;d<64;d++) l+=qrow[d]*kp[d];
  float m=block_max256(l,s4);
  float e=__expf(l-m);
  float s=block_sum256(e,s4);
  attn2[((size_t)bh*LM+i)*LM+j]=e/s;
}

// ---------------- pinv helpers ----------------
__global__ void k_rowsum(const float* __restrict__ x, float* __restrict__ rs){
  __shared__ float s4[4];
  size_t row=blockIdx.x;
  float v=x[row*256+threadIdx.x];
  float s=block_sum256(v,s4);
  if(threadIdx.x==0) rs[row]=s;
}
__global__ void k_colsum(const float* __restrict__ x, float* __restrict__ cs){
  int bh=blockIdx.x, j=threadIdx.x;
  const float* p=x+(size_t)bh*65536;
  float s=0.f;
  for(int i=0;i<256;i++) s+=p[(size_t)i*256+j];
  cs[bh*256+j]=s;
}
__global__ void k_pinvscale(const float* __restrict__ rs, const float* __restrict__ cs,
                            float* __restrict__ scale){
  __shared__ float s4[4];
  float mr=-1e30f, mc=-1e30f;
  for(int i=threadIdx.x;i<4096;i+=256){ mr=fmaxf(mr,rs[i]); mc=fmaxf(mc,cs[i]); }
  mr=block_max256(mr,s4);
  mc=block_max256(mc,s4);
  if(threadIdx.x==0) scale[0]=1.f/(mr*mc);
}
__global__ void k_zinit(const float* __restrict__ x, const float* __restrict__ scale,
                        float* __restrict__ z){
  int bh=blockIdx.x>>8, i=blockIdx.x&255, j=threadIdx.x;
  z[((size_t)bh*LM+i)*LM+j]=x[((size_t)bh*LM+j)*LM+i]*scale[0];
}
__global__ void k_negident(const float* __restrict__ in, float* __restrict__ out, float c0){
  size_t idx=(size_t)blockIdx.x*256+threadIdx.x;
  int i=(idx>>8)&255, j=idx&255;
  out[idx]=((i==j)?c0:0.f)-in[idx];
}

// ---------------- batched 256-class GEMM (pinv + W2) ----------------
__global__ __launch_bounds__(256) void k_bmm(
    const float* __restrict__ Ag, const float* __restrict__ Bg, float* __restrict__ Cg,
    int M, int N, int K, float alpha)
{
  const float* A=Ag+(size_t)blockIdx.z*M*K;
  const float* Bm=Bg+(size_t)blockIdx.z*K*N;
  float* C=Cg+(size_t)blockIdx.z*M*N;
  __shared__ float As[16][65], Bs[16][65];
  int tid=threadIdx.x;
  int row0=blockIdx.y*64, col0=blockIdx.x*64;
  int ty=tid>>4, tx=tid&15;
  float acc[4][4]={};
  for(int k0=0;k0<K;k0+=16){
    #pragma unroll
    for(int i=0;i<4;i++){int idx=tid+256*i; int r=idx>>4, kk=idx&15;
      As[kk][r]=A[(size_t)(row0+r)*K + k0+kk];}
    #pragma unroll
    for(int i=0;i<4;i++){int idx=tid+256*i; int kk=idx>>6, c=idx&63;
      Bs[kk][c]=Bm[(size_t)(k0+kk)*N + col0+c];}
    __syncthreads();
    #pragma unroll
    for(int kk=0;kk<16;kk++){
      float a[4],b[4];
      #pragma unroll
      for(int i=0;i<4;i++) a[i]=As[kk][ty*4+i];
      #pragma unroll
      for(int j=0;j<4;j++) b[j]=Bs[kk][tx*4+j];
      #pragma unroll
      for(int i=0;i<4;i++)
        #pragma unroll
        for(int j=0;j<4;j++) acc[i][j]+=a[i]*b[j];
    }
    __syncthreads();
  }
  #pragma unroll
  for(int i=0;i<4;i++){
    int r=row0+ty*4+i;
    #pragma unroll
    for(int j=0;j<4;j++) C[(size_t)r*N + col0+tx*4+j]=alpha*acc[i][j];
  }
}

// ---------------- attn3@v : 8 landmark rows/block share streamed K/V LDS chunks ----
__global__ __launch_bounds__(256) void k_attn3v2(
    const float* __restrict__ ql, const float* __restrict__ kk_,
    const float* __restrict__ vv, float* __restrict__ out)
{
  __shared__ float Ks[64][65], Vs[64][65];
  int bh=blockIdx.y;
  int row0=blockIdx.x*8;
  int t=threadIdx.x, lane=t&63, w=t>>6;
  int r0=row0+2*w, r1=r0+1;
  float q0=ql[((size_t)bh*LM+r0)*HD+lane];
  float q1=ql[((size_t)bh*LM+r1)*HD+lane];
  float acc0=0.f, acc1=0.f, m0=-3e38f, m1=-3e38f, s0=0.f, s1=0.f;
  const float* kb=kk_+(size_t)bh*NPAD*HD;
  const float* vb=vv +(size_t)bh*NPAD*HD;
  int kk=t>>2, dc=(t&3)*16;
  for(int ch=0; ch<NPAD; ch+=64){
    __syncthreads();
    const float* kp=kb+(size_t)(ch+kk)*HD+dc;
    const float* vp=vb+(size_t)(ch+kk)*HD+dc;
    #pragma unroll
    for(int i=0;i<16;i+=4){
      float4 a=*(const float4*)(kp+i);
      Ks[kk][dc+i]=a.x; Ks[kk][dc+i+1]=a.y; Ks[kk][dc+i+2]=a.z; Ks[kk][dc+i+3]=a.w;
      float4 b2=*(const float4*)(vp+i);
      Vs[kk][dc+i]=b2.x; Vs[kk][dc+i+1]=b2.y; Vs[kk][dc+i+2]=b2.z; Vs[kk][dc+i+3]=b2.w;
    }
    __syncthreads();
    float l0=0.f,l1=0.f;
    #pragma unroll 8
    for(int d=0;d<64;d++){
      float kv=Ks[lane][d];
      l0+=RL(q0,d)*kv; l1+=RL(q1,d)*kv;
    }
    float m0n=fmaxf(m0, wred_max(l0));
    float m1n=fmaxf(m1, wred_max(l1));
    float f0=__expf(m0-m0n), f1=__expf(m1-m1n);
    float p0=__expf(l0-m0n), p1=__expf(l1-m1n);
    s0=s0*f0+wred_sum(p0); s1=s1*f1+wred_sum(p1);
    acc0*=f0; acc1*=f1;
    #pragma unroll 8
    for(int k2=0;k2<64;k2++){
      float vvv=Vs[k2][lane];
      acc0+=RL(p0,k2)*vvv; acc1+=RL(p1,k2)*vvv;
    }
    m0=m0n; m1=m1n;
  }
  out[((size_t)bh*LM+r0)*HD+lane]=acc0/s0;
  out[((size_t)bh*LM+r1)*HD+lane]=acc1/s1;
}

// ---------------- attn1 @ W2 : 32 rows/block, kl^T+W2 staged f32 in 2 halves ------
__global__ __launch_bounds__(256) void k_attn1b(
    const float* __restrict__ qq, const float* __restrict__ kl,
    const float* __restrict__ W2, float* __restrict__ aoh)
{
  __shared__ float klT[64][128];   // [d][j-within-half]
  __shared__ float W2s[128][64];   // [j-within-half][d]
  int bh=blockIdx.y;
  int row0=blockIdx.x*32;
  int t=threadIdx.x, lane=t&63, w=t>>6;
  float acc[8], mrun[8], srun[8], qreg[8];
  #pragma unroll
  for(int r=0;r<8;r++){
    acc[r]=0.f; mrun[r]=-3.0e38f; srun[r]=0.f;
    qreg[r]=qq[((size_t)bh*NPAD + row0 + w*8 + r)*HD + lane];
  }
  for(int half=0; half<2; ++half){
    __syncthreads();
    {
      int j=t&127, db=(t>>7)*32;
      const float* kp = kl + ((size_t)bh*LM + half*128 + j)*HD + db;
      #pragma unroll
      for(int i=0;i<32;i+=4){
        float4 v4 = *(const float4*)(kp+i);
        klT[db+i  ][j]=v4.x; klT[db+i+1][j]=v4.y;
        klT[db+i+2][j]=v4.z; klT[db+i+3][j]=v4.w;
      }
      int j2=t>>1, dc=(t&1)*32;
      const float* wp = W2 + ((size_t)bh*LM + half*128 + j2)*HD + dc;
      float* dst=&W2s[j2][dc];
      #pragma unroll
      for(int i=0;i<32;i+=4) *(float4*)(dst+i) = *(const float4*)(wp+i);
    }
    __syncthreads();
    #pragma unroll
    for(int rp=0;rp<4;rp++){
      float l0a=0.f,l1a=0.f,l0b=0.f,l1b=0.f;
      #pragma unroll 8
      for(int d=0;d<64;d++){
        float qa=RL(qreg[2*rp],d), qb=RL(qreg[2*rp+1],d);
        float2 kv=*(const float2*)&klT[d][2*lane];
        l0a+=qa*kv.x; l1a+=qa*kv.y;
        l0b+=qb*kv.x; l1b+=qb*kv.y;
      }
      float mca=wred_max(fmaxf(l0a,l1a));
      float mcb=wred_max(fmaxf(l0b,l1b));
      float mna=fmaxf(mrun[2*rp],mca), mnb=fmaxf(mrun[2*rp+1],mcb);
      float fa=__expf(mrun[2*rp]-mna), fb=__expf(mrun[2*rp+1]-mnb);
      float p0a=__expf(l0a-mna), p1a=__expf(l1a-mna);
      float p0b=__expf(l0b-mnb), p1b=__expf(l1b-mnb);
      srun[2*rp  ]=srun[2*rp  ]*fa + wred_sum(p0a+p1a);
      srun[2*rp+1]=srun[2*rp+1]*fb + wred_sum(p0b+p1b);
      float aa=acc[2*rp]*fa, ab=acc[2*rp+1]*fb;
      #pragma unroll 8
      for(int s=0;s<64;s++){
        float w0=W2s[2*s][lane], w1=W2s[2*s+1][lane];
        aa+=RL(p0a,s)*w0+RL(p1a,s)*w1;
        ab+=RL(p0b,s)*w0+RL(p1b,s)*w1;
      }
      acc[2*rp]=aa; acc[2*rp+1]=ab;
      mrun[2*rp]=mna; mrun[2*rp+1]=mnb;
    }
  }
  #pragma unroll
  for(int r=0;r<8;r++)
    aoh[((size_t)bh*NPAD + row0 + w*8 + r)*HD + lane]=acc[r]/srun[r];
}

// ---------------- depthwise 33-tap conv on v, += into aoh ----------------
__global__ void k_resconv(const float* __restrict__ vv, const float* __restrict__ rw,
                          float* __restrict__ aoh){
  size_t idx=(size_t)blockIdx.x*256+threadIdx.x;  // 2*8*16384*64
  int d=idx&63; size_t r=idx>>6; int i=r&16383; int bh=(int)(r>>14); int hh=bh&7;
  const float* vb=vv+((size_t)bh*NPAD)*HD+d;
  float a=0.f;
  #pragma unroll
  for(int tk=0;tk<33;tk++){
    int src=i+tk-16;
    if(src>=0 && src<NPAD) a+=vb[(size_t)src*HD]*rw[hh*33+tk];
  }
  aoh[idx]+=a;
}

// ---------------- head-major -> row-major merge ----------------
__global__ void k_headmerge(const float* __restrict__ aoh, float* __restrict__ ao){
  size_t idx=(size_t)blockIdx.x*256+threadIdx.x;  // 2*16384*512
  int c=idx&511; size_t r=idx>>9; int i=r&16383; int bb=(int)(r>>14);
  int hh=c>>6, dd=c&63;
  ao[idx]=aoh[(((size_t)bb*NH+hh)*NPAD+i)*HD+dd];
}

// ---------------- out proj: (32768x512)@(512x512)+bias, residual add into h --------
__global__ __launch_bounds__(256) void k_gemm_proj(
    const float* __restrict__ A, const float* __restrict__ W,
    const float* __restrict__ bias, float* __restrict__ h)
{
  const int K=DM, Nn=DM;
  __shared__ float As[16][65], Bs[16][65];
  int tid=threadIdx.x;
  int row0=blockIdx.y*64, col0=blockIdx.x*64;
  int ty=tid>>4, tx=tid&15;
  float acc[4][4]={};
  for(int k0=0;k0<K;k0+=16){
    #pragma unroll
    for(int i=0;i<4;i++){int idx=tid+256*i; int r=idx>>4, kk=idx&15;
      As[kk][r]=A[(size_t)(row0+r)*K + k0+kk];}
    #pragma unroll
    for(int i=0;i<4;i++){int idx=tid+256*i; int kk=idx>>6, c=idx&63;
      Bs[kk][c]=W[(size_t)(k0+kk)*Nn + col0+c];}
    __syncthreads();
    #pragma unroll
    for(int kk=0;kk<16;kk++){
      float a[4],b[4];
      #pragma unroll
      for(int i=0;i<4;i++) a[i]=As[kk][ty*4+i];
      #pragma unroll
      for(int j=0;j<4;j++) b[j]=Bs[kk][tx*4+j];
      #pragma unroll
      for(int i=0;i<4;i++)
        #pragma unroll
        for(int j=0;j<4;j++) acc[i][j]+=a[i]*b[j];
    }
    __syncthreads();
  }
  #pragma unroll
  for(int i=0;i<4;i++){
    int r=row0+ty*4+i; int bb=r>>14, rr=r&16383;
    if(rr<PADF) continue;
    #pragma unroll
    for(int j=0;j<4;j++){
      int c=col0+tx*4+j;
      h[((size_t)bb*NTOK + (rr-PADF))*DM + c]+=acc[i][j]+bias[c];
    }
  }
}

// ---------------- PPEG weight prep: transpose to [tap][channel] + fused bias -------
__global__ void k_wprep(const float* __restrict__ w7, const float* __restrict__ b7,
                        const float* __restrict__ w5, const float* __restrict__ b5,
                        const float* __restrict__ w3, const float* __restrict__ b3,
                        float* __restrict__ wcat){
  int t=blockIdx.x*256+threadIdx.x; // 84*512
  if(t>=84*512) return;
  int r=t>>9, c=t&511;
  float v;
  if(r<49)      v=w7[(size_t)c*49+r];
  else if(r<74) v=w5[(size_t)c*25+(r-49)];
  else if(r<83) v=w3[(size_t)c*9+(r-74)];
  else          v=b7[c]+b5[c]+b3[c];
  wcat[t]=v;
}

// ---------------- PPEG: LDS-tiled 6x6x64ch stencil (7x7 + 5x5 + 3x3) --------------
__global__ __launch_bounds__(256) void k_ppeg2(
    const float* __restrict__ src, const float* __restrict__ wcat,
    float* __restrict__ h)
{
  __shared__ float patch[144][64];   // 12x12 halo patch
  __shared__ float ws[84][64];       // 83 taps + fused bias
  int gx=blockIdx.x%22, gy=blockIdx.x/22;
  int cz=blockIdx.y, bb=blockIdx.z;
  int t=threadIdx.x, c=t&63, g=t>>6;
  int ty0=gy*6, tx0=gx*6;
  const float* base=src+((size_t)bb*NTOK+1)*DM + cz*64 + c;
  #pragma unroll
  for(int i=0;i<36;i++){
    int p=g+4*i;
    int py=p/12, px=p%12;
    int yy=ty0-3+py, xx=tx0-3+px;
    float v=0.f;
    if(yy>=0&&yy<127&&xx>=0&&xx<127) v=base[(size_t)(yy*127+xx)*DM];
    patch[p][c]=v;
  }
  #pragma unroll
  for(int i=0;i<21;i++){
    int r=g+4*i; if(r<84) ws[r][c]=wcat[(size_t)r*DM + cz*64 + c];
  }
  __syncthreads();
  float acc[9];
  int oy[9], ox[9];
  #pragma unroll
  for(int i=0;i<9;i++){
    int p=g*9+i; oy[i]=p/6; ox[i]=p%6;
    acc[i]=patch[(oy[i]+3)*12+(ox[i]+3)][c]+ws[83][c];
  }
  for(int ky=0;ky<7;ky++)
    for(int kx=0;kx<7;kx++){
      float wv=ws[ky*7+kx][c];
      #pragma unroll
      for(int i=0;i<9;i++)
        acc[i]+=patch[(oy[i]+ky)*12+ox[i]+kx][c]*wv;
    }
  for(int ky=0;ky<5;ky++)
    for(int kx=0;kx<5;kx++){
      float wv=ws[49+ky*5+kx][c];
      #pragma unroll
      for(int i=0;i<9;i++)
        acc[i]+=patch[(oy[i]+1+ky)*12+ox[i]+1+kx][c]*wv;
    }
  for(int ky=0;ky<3;ky++)
    for(int kx=0;kx<3;kx++){
      float wv=ws[74+ky*3+kx][c];
      #pragma unroll
      for(int i=0;i<9;i++)
        acc[i]+=patch[(oy[i]+2+ky)*12+ox[i]+2+kx][c]*wv;
    }
  #pragma unroll
  for(int i=0;i<9;i++){
    int y=ty0+oy[i], x=tx0+ox[i];
    if(y<127&&x<127)
      h[((size_t)bb*NTOK+1+(size_t)(y*127+x))*DM + cz*64 + c]=acc[i];
  }
}

// ---------------- final: LN(h[:,0]) @ fc2 + b ----------------
__global__ __launch_bounds__(256) void k_final(
    const float* __restrict__ h, const float* __restrict__ g, const float* __restrict__ bta,
    const float* __restrict__ w, const float* __restrict__ fb, float* __restrict__ out)
{
  int bb=blockIdx.x, t=threadIdx.x;
  const float* src=h+(size_t)bb*NTOK*DM;
  float x0=src[t], x1=src[t+256];
  __shared__ float s4[4];
  float mu=block_sum256(x0+x1,s4)*(1.f/512.f);
  float d0=x0-mu, d1=x1-mu;
  float var=block_sum256(d0*d0+d1*d1,s4)*(1.f/512.f);
  float rst=rsqrtf(var+1e-5f);
  float y0=d0*rst*g[t]+bta[t], y1=d1*rst*g[t+256]+bta[t+256];
  float dot=block_sum256(y0*w[t]+y1*w[t+256],s4);
  if(t==0) out[bb]=dot+fb[0];
}

// =======================================================================
extern "C" void kernel_launch(void* const* d_in, const int* in_sizes, int n_in,
                              void* d_out, int out_size, void* d_ws, size_t ws_size,
                              hipStream_t stream){
  (void)in_sizes; (void)n_in; (void)out_size;
  const float* features=(const float*)d_in[0];
  const float* fc1_w  =(const float*)d_in[1];
  const float* fc1_b  =(const float*)d_in[2];
  const float* cls_tok=(const float*)d_in[3];
  const float* fc2_w  =(const float*)d_in[24];
  const float* fc2_b  =(const float*)d_in[25];
  float* out=(float*)d_out;

  char* wp=(char*)d_ws;
  auto alloc=[&](size_t floats)->float*{
    float* p=(float*)wp; wp+=((floats*4+255)/256)*256; return p;
  };
  float* h   =alloc((size_t)NB*NTOK*DM);
  float* xln =alloc((size_t)NB*NPAD*DM);
  float* q   =alloc((size_t)NB*NPAD*DM);
  float* kbuf=alloc((size_t)NB*NPAD*DM);
  float* v   =alloc((size_t)NB*NPAD*DM);
  float* ql  =alloc((size_t)16*LM*HD);
  float* kl  =alloc((size_t)16*LM*HD);
  float* attn2=alloc((size_t)16*LM*LM);
  float* z0  =alloc((size_t)16*LM*LM);
  float* z1  =alloc((size_t)16*LM*LM);
  float* Ab  =alloc((size_t)16*LM*LM);
  float* Ub  =alloc((size_t)16*LM*LM);
  float* Tb  =alloc((size_t)16*LM*LM);
  float* a3v =alloc((size_t)16*LM*HD);
  float* W2b =alloc((size_t)16*LM*HD);
  float* rs  =alloc(4096);
  float* cs  =alloc(4096);
  float* scl =alloc(64);
  (void)ws_size;
  float* aoh=kbuf;   // reuse: k dead after attn3v
  float* ao =xln;    // reuse: xln dead after qkv

  auto nystrom=[&](const float* ng, const float* nbias, const float* qkvw,
                   const float* outw, const float* outb, const float* resw){
    k_lnpad<<<NB*NPAD,256,0,stream>>>(h, ng, nbias, xln);
    k_gemm_qkv<<<dim3(24,512),256,0,stream>>>(xln, qkvw, q, kbuf, v);
    k_lmean<<<4096,64,0,stream>>>(q, ql);
    k_lmean<<<4096,64,0,stream>>>(kbuf, kl);
    k_attn2<<<4096,256,0,stream>>>(ql, kl, attn2);
    k_rowsum<<<4096,256,0,stream>>>(attn2, rs);
    k_colsum<<<16,256,0,stream>>>(attn2, cs);
    k_pinvscale<<<1,256,0,stream>>>(rs, cs, scl);
    k_zinit<<<4096,256,0,stream>>>(attn2, scl, z0);
    float* zc=z0; float* zn=z1;
    for(int it=0;it<6;it++){
      k_bmm<<<dim3(4,4,16),256,0,stream>>>(attn2, zc, Ab, 256,256,256, 1.f);
      k_negident<<<4096,256,0,stream>>>(Ab, Tb, 7.f);
      k_bmm<<<dim3(4,4,16),256,0,stream>>>(Ab, Tb, Ub, 256,256,256, 1.f);
      k_negident<<<4096,256,0,stream>>>(Ub, Ub, 15.f);
      k_bmm<<<dim3(4,4,16),256,0,stream>>>(Ab, Ub, Tb, 256,256,256, 1.f);
      k_negident<<<4096,256,0,stream>>>(Tb, Tb, 13.f);
      k_bmm<<<dim3(4,4,16),256,0,stream>>>(zc, Tb, zn, 256,256,256, 0.25f);
      float* tp=zc; zc=zn; zn=tp;
    }
    k_attn3v2<<<dim3(32,16),256,0,stream>>>(ql, kbuf, v, a3v);
    k_bmm<<<dim3(1,4,16),256,0,stream>>>(zc, a3v, W2b, 256,64,256, 1.f);
    k_attn1b<<<dim3(512,16),256,0,stream>>>(q, kl, W2b, aoh);
    k_resconv<<<65536,256,0,stream>>>(v, resw, aoh);
    k_headmerge<<<65536,256,0,stream>>>(aoh, ao);
    k_gemm_proj<<<dim3(8,512),256,0,stream>>>(ao, outw, outb, h);
  };

  // fc1 + relu + dup + cls
  k_gemm_fc1<<<dim3(8,500),256,0,stream>>>(features, fc1_w, fc1_b, h);
  k_cls<<<4,256,0,stream>>>(cls_tok, h);

  // layer 1 attention
  nystrom((const float*)d_in[4],(const float*)d_in[5],(const float*)d_in[6],
          (const float*)d_in[7],(const float*)d_in[8],(const float*)d_in[9]);

  // PPEG: copy h, build transposed weight table, tiled stencil
  float* tmp=q;
  float* wcat=attn2;  // free at this point
  hipMemcpyAsync(tmp, h, (size_t)NB*NTOK*DM*4, hipMemcpyDeviceToDevice, stream);
  k_wprep<<<168,256,0,stream>>>(
      (const float*)d_in[10],(const float*)d_in[11],
      (const float*)d_in[12],(const float*)d_in[13],
      (const float*)d_in[14],(const float*)d_in[15], wcat);
  k_ppeg2<<<dim3(484,8,2),256,0,stream>>>(tmp, wcat, h);

  // layer 2 attention
  nystrom((const float*)d_in[16],(const float*)d_in[17],(const float*)d_in[18],
          (const float*)d_in[19],(const float*)d_in[20],(const float*)d_in[21]);

  // final LN(row0) @ fc2
  k_final<<<2,256,0,stream>>>(h,(const float*)d_in[22],(const float*)d_in[23],
                              fc2_w, fc2_b, out);
}

// Round 3
// 6105.568 us; speedup vs baseline: 3.0556x; 1.6136x over previous
//
#include <hip/hip_runtime.h>
#include <math.h>

#define NTOK 16130   // 1 + 127*127
#define NPAD 16384
#define PADF 254
#define NB   2
#define DM   512
#define NH   8
#define HD   64
#define LM   256
#define SEG  64

typedef __attribute__((ext_vector_type(8))) short short8v;
typedef __attribute__((ext_vector_type(4))) float f32x4;
typedef unsigned short ushortv;

// ---------------- reductions (wave64) ----------------
__device__ __forceinline__ float wred_max(float v){
  #pragma unroll
  for(int o=32;o;o>>=1) v=fmaxf(v,__shfl_xor(v,o));
  return v;
}
__device__ __forceinline__ float wred_sum(float v){
  #pragma unroll
  for(int o=32;o;o>>=1) v+=__shfl_xor(v,o);
  return v;
}
__device__ __forceinline__ float block_max256(float v, float* s4){
  v=wred_max(v);
  if((threadIdx.x&63)==0) s4[threadIdx.x>>6]=v;
  __syncthreads();
  v=fmaxf(fmaxf(s4[0],s4[1]),fmaxf(s4[2],s4[3]));
  __syncthreads();
  return v;
}
__device__ __forceinline__ float block_sum256(float v, float* s4){
  v=wred_sum(v);
  if((threadIdx.x&63)==0) s4[threadIdx.x>>6]=v;
  __syncthreads();
  v=s4[0]+s4[1]+s4[2]+s4[3];
  __syncthreads();
  return v;
}
__device__ __forceinline__ float RL(float v, int l){
  return __int_as_float(__builtin_amdgcn_readlane(__float_as_int(v), l));
}
__device__ __forceinline__ unsigned short f2bf(float f){
  unsigned u=__float_as_uint(f);
  u = u + 0x7FFFu + ((u>>16)&1u);
  return (unsigned short)(u>>16);
}

// ---------------- conversions ----------------
__global__ void k_f2bf4(const float* __restrict__ x, unsigned short* __restrict__ y, int n4){
  int i=blockIdx.x*256+threadIdx.x; if(i>=n4) return;
  float4 v=((const float4*)x)[i];
  ushort4 r; r.x=f2bf(v.x); r.y=f2bf(v.y); r.z=f2bf(v.z); r.w=f2bf(v.w);
  ((ushort4*)y)[i]=r;
}
// W[K][N] f32 -> Wt[N][K] bf16
__global__ void k_wconv_t(const float* __restrict__ W, unsigned short* __restrict__ Wt,
                          int K, int N){
  int idx=blockIdx.x*256+threadIdx.x; if(idx>=K*N) return;
  int k=idx/N, n=idx%N;
  Wt[(size_t)n*K+k]=f2bf(W[idx]);
}

// ---------------- MFMA bf16 GEMM: 128x128 tile, BK=32 ----------------
// A [M][K] bf16 row-major, Bt [N][K] bf16 (B transposed). f32 accum.
// MODE 0: fc1 (relu+bias, scatter to h with dup rows)
// MODE 1: qkv scatter head-major (q scaled 0.125)
// MODE 2: proj residual add into h, skip pad rows
template<int MODE>
__global__ __launch_bounds__(256) void k_mfma_gemm(
    const unsigned short* __restrict__ A, const unsigned short* __restrict__ Bt,
    int M, int N, int K,
    const float* __restrict__ bias,
    float* __restrict__ o0, float* __restrict__ o1, float* __restrict__ o2)
{
  __shared__ unsigned short As[128*32];
  __shared__ unsigned short Bs[128*32];
  int t=threadIdx.x;
  int row0=blockIdx.y*128, col0=blockIdx.x*128;
  int lane=t&63, w=t>>6, wr=w>>1, wc=w&1, lr=lane&15, kg=lane>>4;
  f32x4 acc[4][4];
  #pragma unroll
  for(int m=0;m<4;m++)
    #pragma unroll
    for(int n=0;n<4;n++) acc[m][n]=(f32x4){0.f,0.f,0.f,0.f};

  short8v ra[2], rb[2];
  #pragma unroll
  for(int i=0;i<2;i++){
    int flat=i*256+t, r=flat>>2, k8=flat&3;
    ra[i]=*(const short8v*)(A +(size_t)(row0+r)*K + k8*8);
    rb[i]=*(const short8v*)(Bt+(size_t)(col0+r)*K + k8*8);
  }
  int k0=0;
  for(;;){
    __syncthreads();
    #pragma unroll
    for(int i=0;i<2;i++){
      int flat=i*256+t;
      *(short8v*)(As+flat*8)=ra[i];
      *(short8v*)(Bs+flat*8)=rb[i];
    }
    __syncthreads();
    k0+=32;
    if(k0<K){
      #pragma unroll
      for(int i=0;i<2;i++){
        int flat=i*256+t, r=flat>>2, k8=flat&3;
        ra[i]=*(const short8v*)(A +(size_t)(row0+r)*K + k0 + k8*8);
        rb[i]=*(const short8v*)(Bt+(size_t)(col0+r)*K + k0 + k8*8);
      }
    }
    short8v af[4], bf[4];
    #pragma unroll
    for(int m=0;m<4;m++) af[m]=*(const short8v*)(As+(wr*64+m*16+lr)*32 + kg*8);
    #pragma unroll
    for(int n=0;n<4;n++) bf[n]=*(const short8v*)(Bs+(wc*64+n*16+lr)*32 + kg*8);
    #pragma unroll
    for(int m=0;m<4;m++)
      #pragma unroll
      for(int n=0;n<4;n++)
        acc[m][n]=__builtin_amdgcn_mfma_f32_16x16x32_bf16(af[m],bf[n],acc[m][n],0,0,0);
    if(k0>=K) break;
  }
  // epilogue
  #pragma unroll
  for(int m=0;m<4;m++){
    int rbase=row0 + wr*64 + m*16 + kg*4;
    #pragma unroll
    for(int j=0;j<4;j++){
      int r=rbase+j;
      #pragma unroll
      for(int n=0;n<4;n++){
        int c=col0 + wc*64 + n*16 + lr;
        float val=acc[m][n][j];
        if(MODE==0){
          int bb=(r>=16000)?1:0, ii=r-bb*16000;
          float v=fmaxf(val+bias[c],0.f);
          o0[((size_t)bb*NTOK + 1 + ii)*DM + c]=v;
          if(ii<129) o0[((size_t)bb*NTOK + 16001 + ii)*DM + c]=v;
        } else if(MODE==1){
          int bb=r>>14, rr=r&16383;
          int which=c>>9, hcol=c&511, head=hcol>>6, dd=hcol&63;
          size_t o=(((size_t)bb*NH+head)*NPAD + rr)*HD + dd;
          if(which==0)      o0[o]=val*0.125f;
          else if(which==1) o1[o]=val;
          else              o2[o]=val;
        } else {
          int bb=r>>14, rr=r&16383;
          if(rr>=PADF)
            o0[((size_t)bb*NTOK + (rr-PADF))*DM + c]+=val+bias[c];
        }
      }
    }
  }
}

__global__ void k_cls(const float* __restrict__ cls, float* __restrict__ h){
  int t=blockIdx.x*256+threadIdx.x;
  if(t<2*DM) h[(size_t)(t>>9)*NTOK*DM + (t&511)]=cls[t&511];
}

// ---------------- layernorm + front zero-pad -> bf16 ----------------
__global__ __launch_bounds__(256) void k_lnpad(
    const float* __restrict__ h, const float* __restrict__ g,
    const float* __restrict__ bta, unsigned short* __restrict__ xln)
{
  int r=blockIdx.x;
  int bb=r>>14, i=r&16383;
  int t=threadIdx.x;
  unsigned short* dst=xln+(size_t)r*DM;
  if(i<PADF){ dst[t]=0; dst[t+256]=0; return; }
  const float* src=h+((size_t)bb*NTOK + (i-PADF))*DM;
  float x0=src[t], x1=src[t+256];
  __shared__ float s4[4];
  float mu=block_sum256(x0+x1,s4)*(1.f/512.f);
  float d0=x0-mu, d1=x1-mu;
  float var=block_sum256(d0*d0+d1*d1,s4)*(1.f/512.f);
  float rst=rsqrtf(var+1e-5f);
  dst[t]    =f2bf(d0*rst*g[t]    +bta[t]);
  dst[t+256]=f2bf(d1*rst*g[t+256]+bta[t+256]);
}

// ---------------- landmark means ----------------
__global__ void k_lmean(const float* __restrict__ src, float* __restrict__ dst){
  int bh=blockIdx.x>>8, s=blockIdx.x&255, d=threadIdx.x;
  const float* p=src + (((size_t)bh*NPAD)+s*SEG)*HD + d;
  float acc=0.f;
  #pragma unroll
  for(int l=0;l<SEG;l++) acc+=p[(size_t)l*HD];
  dst[((size_t)bh*LM+s)*HD+d]=acc*(1.f/64.f);
}

// ---------------- attn2 = softmax(ql @ kl^T) ----------------
__global__ __launch_bounds__(256) void k_attn2(
    const float* __restrict__ ql, const float* __restrict__ kl, float* __restrict__ attn2)
{
  __shared__ float qrow[64]; __shared__ float s4[4];
  int bh=blockIdx.x>>8, i=blockIdx.x&255, j=threadIdx.x;
  if(j<64) qrow[j]=ql[((size_t)bh*LM+i)*HD+j];
  __syncthreads();
  const float* kp=kl+((size_t)bh*LM+j)*HD;
  float l=0.f;
  #pragma unroll
  for(int d=0;d<64;d++) l+=qrow[d]*kp[d];
  float m=block_max256(l,s4);
  float e=__expf(l-m);
  float s=block_sum256(e,s4);
  attn2[((size_t)bh*LM+i)*LM+j]=e/s;
}

// ---------------- pinv helpers ----------------
__global__ void k_rowsum(const float* __restrict__ x, float* __restrict__ rs){
  __shared__ float s4[4];
  size_t row=blockIdx.x;
  float v=x[row*256+threadIdx.x];
  float s=block_sum256(v,s4);
  if(threadIdx.x==0) rs[row]=s;
}
__global__ void k_colsum(const float* __restrict__ x, float* __restrict__ cs){
  int bh=blockIdx.x, j=threadIdx.x;
  const float* p=x+(size_t)bh*65536;
  float s=0.f;
  for(int i=0;i<256;i++) s+=p[(size_t)i*256+j];
  cs[bh*256+j]=s;
}
__global__ void k_pinvscale(const float* __restrict__ rs, const float* __restrict__ cs,
                            float* __restrict__ scale){
  __shared__ float s4[4];
  float mr=-1e30f, mc=-1e30f;
  for(int i=threadIdx.x;i<4096;i+=256){ mr=fmaxf(mr,rs[i]); mc=fmaxf(mc,cs[i]); }
  mr=block_max256(mr,s4);
  mc=block_max256(mc,s4);
  if(threadIdx.x==0) scale[0]=1.f/(mr*mc);
}
__global__ void k_zinit(const float* __restrict__ x, const float* __restrict__ scale,
                        float* __restrict__ z){
  int bh=blockIdx.x>>8, i=blockIdx.x&255, j=threadIdx.x;
  z[((size_t)bh*LM+i)*LM+j]=x[((size_t)bh*LM+j)*LM+i]*scale[0];
}

// ---------------- batched GEMM with fused (cI - X) on B-read and epilogue ---------
// B' = (bc!=0) ? bc*I - B : B ;  out = (ec!=0) ? ec*I - A@B' : alpha*(A@B')
__global__ __launch_bounds__(256) void k_bmm(
    const float* __restrict__ Ag, const float* __restrict__ Bg, float* __restrict__ Cg,
    int M, int N, int K, float alpha, float bc, float ec)
{
  const float* A=Ag+(size_t)blockIdx.z*M*K;
  const float* Bm=Bg+(size_t)blockIdx.z*K*N;
  float* C=Cg+(size_t)blockIdx.z*M*N;
  __shared__ float As[16][65], Bs[16][65];
  int tid=threadIdx.x;
  int row0=blockIdx.y*64, col0=blockIdx.x*64;
  int ty=tid>>4, tx=tid&15;
  float acc[4][4]={};
  for(int k0=0;k0<K;k0+=16){
    #pragma unroll
    for(int i=0;i<4;i++){int idx=tid+256*i; int r=idx>>4, kk=idx&15;
      As[kk][r]=A[(size_t)(row0+r)*K + k0+kk];}
    #pragma unroll
    for(int i=0;i<4;i++){int idx=tid+256*i; int kk=idx>>6, c=idx&63;
      float bv=Bm[(size_t)(k0+kk)*N + col0+c];
      if(bc!=0.f) bv=((k0+kk)==(col0+c)?bc:0.f)-bv;
      Bs[kk][c]=bv;}
    __syncthreads();
    #pragma unroll
    for(int kk=0;kk<16;kk++){
      float a[4],b[4];
      #pragma unroll
      for(int i=0;i<4;i++) a[i]=As[kk][ty*4+i];
      #pragma unroll
      for(int j=0;j<4;j++) b[j]=Bs[kk][tx*4+j];
      #pragma unroll
      for(int i=0;i<4;i++)
        #pragma unroll
        for(int j=0;j<4;j++) acc[i][j]+=a[i]*b[j];
    }
    __syncthreads();
  }
  #pragma unroll
  for(int i=0;i<4;i++){
    int r=row0+ty*4+i;
    #pragma unroll
    for(int j=0;j<4;j++){
      int c=col0+tx*4+j;
      float v;
      if(ec!=0.f) v=(r==c?ec:0.f)-acc[i][j];
      else        v=alpha*acc[i][j];
      C[(size_t)r*N + c]=v;
    }
  }
}

// ---------------- attn3@v split-K flash: partials per (bh, chunk, row) ----------
__global__ __launch_bounds__(256) void k_attn3v3(
    const float* __restrict__ ql, const float* __restrict__ kk_,
    const float* __restrict__ vv, float* __restrict__ pacc, float* __restrict__ pms)
{
  __shared__ float Ks[64][65], Vs[64][65];
  int ck=blockIdx.x, rg=blockIdx.y, bh=blockIdx.z;
  int row0=rg*8;
  int t=threadIdx.x, lane=t&63, w=t>>6;
  int r0=row0+2*w, r1=r0+1;
  float q0=ql[((size_t)bh*LM+r0)*HD+lane];
  float q1=ql[((size_t)bh*LM+r1)*HD+lane];
  float acc0=0.f, acc1=0.f, m0=-3e38f, m1=-3e38f, s0=0.f, s1=0.f;
  const float* kb=kk_+(size_t)bh*NPAD*HD;
  const float* vb=vv +(size_t)bh*NPAD*HD;
  int kk=t>>2, dc=(t&3)*16;
  int ch0=ck*2048;
  for(int ch=ch0; ch<ch0+2048; ch+=64){
    __syncthreads();
    const float* kp=kb+(size_t)(ch+kk)*HD+dc;
    const float* vp=vb+(size_t)(ch+kk)*HD+dc;
    #pragma unroll
    for(int i=0;i<16;i+=4){
      float4 a=*(const float4*)(kp+i);
      Ks[kk][dc+i]=a.x; Ks[kk][dc+i+1]=a.y; Ks[kk][dc+i+2]=a.z; Ks[kk][dc+i+3]=a.w;
      float4 b2=*(const float4*)(vp+i);
      Vs[kk][dc+i]=b2.x; Vs[kk][dc+i+1]=b2.y; Vs[kk][dc+i+2]=b2.z; Vs[kk][dc+i+3]=b2.w;
    }
    __syncthreads();
    float l0=0.f,l1=0.f;
    #pragma unroll 8
    for(int d=0;d<64;d++){
      float kv=Ks[lane][d];
      l0+=RL(q0,d)*kv; l1+=RL(q1,d)*kv;
    }
    float m0n=fmaxf(m0, wred_max(l0));
    float m1n=fmaxf(m1, wred_max(l1));
    float f0=__expf(m0-m0n), f1=__expf(m1-m1n);
    float p0=__expf(l0-m0n), p1=__expf(l1-m1n);
    s0=s0*f0+wred_sum(p0); s1=s1*f1+wred_sum(p1);
    acc0*=f0; acc1*=f1;
    #pragma unroll 8
    for(int k2=0;k2<64;k2++){
      float vvv=Vs[k2][lane];
      acc0+=RL(p0,k2)*vvv; acc1+=RL(p1,k2)*vvv;
    }
    m0=m0n; m1=m1n;
  }
  size_t pb=((size_t)bh*8+ck)*256;
  pacc[(pb+r0)*64+lane]=acc0;
  pacc[(pb+r1)*64+lane]=acc1;
  if(lane==0){
    pms[(pb+r0)*2]=m0; pms[(pb+r0)*2+1]=s0;
    pms[(pb+r1)*2]=m1; pms[(pb+r1)*2+1]=s1;
  }
}
__global__ __launch_bounds__(256) void k_attn3vc(
    const float* __restrict__ pacc, const float* __restrict__ pms,
    float* __restrict__ out)
{
  int gid=blockIdx.x*4 + (threadIdx.x>>6);   // over 4096 rows
  int bh=gid>>8, row=gid&255, lane=threadIdx.x&63;
  float ms[8], ss[8], M=-3e38f;
  #pragma unroll
  for(int c=0;c<8;c++){
    size_t pb=((size_t)bh*8+c)*256+row;
    ms[c]=pms[pb*2]; ss[c]=pms[pb*2+1];
    M=fmaxf(M,ms[c]);
  }
  float S=0.f, a=0.f;
  #pragma unroll
  for(int c=0;c<8;c++){
    float f=__expf(ms[c]-M);
    S+=ss[c]*f;
    a+=pacc[(((size_t)bh*8+c)*256+row)*64+lane]*f;
  }
  out[((size_t)bh*LM+row)*HD+lane]=a/S;
}

// ---------------- attn1 @ W2 : 32 rows/block, kl^T+W2 staged in 2 halves ------
__global__ __launch_bounds__(256) void k_attn1b(
    const float* __restrict__ qq, const float* __restrict__ kl,
    const float* __restrict__ W2, float* __restrict__ aoh)
{
  __shared__ float klT[64][128];
  __shared__ float W2s[128][64];
  int bh=blockIdx.y;
  int row0=blockIdx.x*32;
  int t=threadIdx.x, lane=t&63, w=t>>6;
  float acc[8], mrun[8], srun[8], qreg[8];
  #pragma unroll
  for(int r=0;r<8;r++){
    acc[r]=0.f; mrun[r]=-3.0e38f; srun[r]=0.f;
    qreg[r]=qq[((size_t)bh*NPAD + row0 + w*8 + r)*HD + lane];
  }
  for(int half=0; half<2; ++half){
    __syncthreads();
    {
      int j=t&127, db=(t>>7)*32;
      const float* kp = kl + ((size_t)bh*LM + half*128 + j)*HD + db;
      #pragma unroll
      for(int i=0;i<32;i+=4){
        float4 v4 = *(const float4*)(kp+i);
        klT[db+i  ][j]=v4.x; klT[db+i+1][j]=v4.y;
        klT[db+i+2][j]=v4.z; klT[db+i+3][j]=v4.w;
      }
      int j2=t>>1, dc=(t&1)*32;
      const float* wp = W2 + ((size_t)bh*LM + half*128 + j2)*HD + dc;
      float* dst=&W2s[j2][dc];
      #pragma unroll
      for(int i=0;i<32;i+=4) *(float4*)(dst+i) = *(const float4*)(wp+i);
    }
    __syncthreads();
    #pragma unroll
    for(int rp=0;rp<4;rp++){
      float l0a=0.f,l1a=0.f,l0b=0.f,l1b=0.f;
      #pragma unroll 8
      for(int d=0;d<64;d++){
        float qa=RL(qreg[2*rp],d), qb=RL(qreg[2*rp+1],d);
        float2 kv=*(const float2*)&klT[d][2*lane];
        l0a+=qa*kv.x; l1a+=qa*kv.y;
        l0b+=qb*kv.x; l1b+=qb*kv.y;
      }
      float mca=wred_max(fmaxf(l0a,l1a));
      float mcb=wred_max(fmaxf(l0b,l1b));
      float mna=fmaxf(mrun[2*rp],mca), mnb=fmaxf(mrun[2*rp+1],mcb);
      float fa=__expf(mrun[2*rp]-mna), fb=__expf(mrun[2*rp+1]-mnb);
      float p0a=__expf(l0a-mna), p1a=__expf(l1a-mna);
      float p0b=__expf(l0b-mnb), p1b=__expf(l1b-mnb);
      srun[2*rp  ]=srun[2*rp  ]*fa + wred_sum(p0a+p1a);
      srun[2*rp+1]=srun[2*rp+1]*fb + wred_sum(p0b+p1b);
      float aa=acc[2*rp]*fa, ab=acc[2*rp+1]*fb;
      #pragma unroll 8
      for(int s=0;s<64;s++){
        float w0=W2s[2*s][lane], w1=W2s[2*s+1][lane];
        aa+=RL(p0a,s)*w0+RL(p1a,s)*w1;
        ab+=RL(p0b,s)*w0+RL(p1b,s)*w1;
      }
      acc[2*rp]=aa; acc[2*rp+1]=ab;
      mrun[2*rp]=mna; mrun[2*rp+1]=mnb;
    }
  }
  #pragma unroll
  for(int r=0;r<8;r++)
    aoh[((size_t)bh*NPAD + row0 + w*8 + r)*HD + lane]=acc[r]/srun[r];
}

// ---------------- depthwise 33-tap conv on v, += into aoh ----------------
__global__ void k_resconv(const float* __restrict__ vv, const float* __restrict__ rw,
                          float* __restrict__ aoh){
  size_t idx=(size_t)blockIdx.x*256+threadIdx.x;
  int d=idx&63; size_t r=idx>>6; int i=r&16383; int bh=(int)(r>>14); int hh=bh&7;
  const float* vb=vv+((size_t)bh*NPAD)*HD+d;
  float a=0.f;
  #pragma unroll
  for(int tk=0;tk<33;tk++){
    int src=i+tk-16;
    if(src>=0 && src<NPAD) a+=vb[(size_t)src*HD]*rw[hh*33+tk];
  }
  aoh[idx]+=a;
}

// ---------------- head-major -> row-major merge -> bf16 ----------------
__global__ void k_headmerge(const float* __restrict__ aoh, unsigned short* __restrict__ ao){
  size_t idx=(size_t)blockIdx.x*256+threadIdx.x;
  int c=idx&511; size_t r=idx>>9; int i=r&16383; int bb=(int)(r>>14);
  int hh=c>>6, dd=c&63;
  ao[idx]=f2bf(aoh[(((size_t)bb*NH+hh)*NPAD+i)*HD+dd]);
}

// ---------------- PPEG weight prep ----------------
__global__ void k_wprep(const float* __restrict__ w7, const float* __restrict__ b7,
                        const float* __restrict__ w5, const float* __restrict__ b5,
                        const float* __restrict__ w3, const float* __restrict__ b3,
                        float* __restrict__ wcat){
  int t=blockIdx.x*256+threadIdx.x;
  if(t>=84*512) return;
  int r=t>>9, c=t&511;
  float v;
  if(r<49)      v=w7[(size_t)c*49+r];
  else if(r<74) v=w5[(size_t)c*25+(r-49)];
  else if(r<83) v=w3[(size_t)c*9+(r-74)];
  else          v=b7[c]+b5[c]+b3[c];
  wcat[t]=v;
}

// ---------------- PPEG: LDS-tiled 6x6x64ch stencil ----------------
__global__ __launch_bounds__(256) void k_ppeg2(
    const float* __restrict__ src, const float* __restrict__ wcat,
    float* __restrict__ h)
{
  __shared__ float patch[144][64];
  __shared__ float ws[84][64];
  int gx=blockIdx.x%22, gy=blockIdx.x/22;
  int cz=blockIdx.y, bb=blockIdx.z;
  int t=threadIdx.x, c=t&63, g=t>>6;
  int ty0=gy*6, tx0=gx*6;
  const float* base=src+((size_t)bb*NTOK+1)*DM + cz*64 + c;
  #pragma unroll
  for(int i=0;i<36;i++){
    int p=g+4*i;
    int py=p/12, px=p%12;
    int yy=ty0-3+py, xx=tx0-3+px;
    float v=0.f;
    if(yy>=0&&yy<127&&xx>=0&&xx<127) v=base[(size_t)(yy*127+xx)*DM];
    patch[p][c]=v;
  }
  #pragma unroll
  for(int i=0;i<21;i++){
    int r=g+4*i; if(r<84) ws[r][c]=wcat[(size_t)r*DM + cz*64 + c];
  }
  __syncthreads();
  float acc[9];
  int oy[9], ox[9];
  #pragma unroll
  for(int i=0;i<9;i++){
    int p=g*9+i; oy[i]=p/6; ox[i]=p%6;
    acc[i]=patch[(oy[i]+3)*12+(ox[i]+3)][c]+ws[83][c];
  }
  for(int ky=0;ky<7;ky++)
    for(int kx=0;kx<7;kx++){
      float wv=ws[ky*7+kx][c];
      #pragma unroll
      for(int i=0;i<9;i++)
        acc[i]+=patch[(oy[i]+ky)*12+ox[i]+kx][c]*wv;
    }
  for(int ky=0;ky<5;ky++)
    for(int kx=0;kx<5;kx++){
      float wv=ws[49+ky*5+kx][c];
      #pragma unroll
      for(int i=0;i<9;i++)
        acc[i]+=patch[(oy[i]+1+ky)*12+ox[i]+1+kx][c]*wv;
    }
  for(int ky=0;ky<3;ky++)
    for(int kx=0;kx<3;kx++){
      float wv=ws[74+ky*3+kx][c];
      #pragma unroll
      for(int i=0;i<9;i++)
        acc[i]+=patch[(oy[i]+2+ky)*12+ox[i]+2+kx][c]*wv;
    }
  #pragma unroll
  for(int i=0;i<9;i++){
    int y=ty0+oy[i], x=tx0+ox[i];
    if(y<127&&x<127)
      h[((size_t)bb*NTOK+1+(size_t)(y*127+x))*DM + cz*64 + c]=acc[i];
  }
}

// ---------------- final: LN(h[:,0]) @ fc2 + b ----------------
__global__ __launch_bounds__(256) void k_final(
    const float* __restrict__ h, const float* __restrict__ g, const float* __restrict__ bta,
    const float* __restrict__ w, const float* __restrict__ fb, float* __restrict__ out)
{
  int bb=blockIdx.x, t=threadIdx.x;
  const float* src=h+(size_t)bb*NTOK*DM;
  float x0=src[t], x1=src[t+256];
  __shared__ float s4[4];
  float mu=block_sum256(x0+x1,s4)*(1.f/512.f);
  float d0=x0-mu, d1=x1-mu;
  float var=block_sum256(d0*d0+d1*d1,s4)*(1.f/512.f);
  float rst=rsqrtf(var+1e-5f);
  float y0=d0*rst*g[t]+bta[t], y1=d1*rst*g[t+256]+bta[t+256];
  float dot=block_sum256(y0*w[t]+y1*w[t+256],s4);
  if(t==0) out[bb]=dot+fb[0];
}

// =======================================================================
extern "C" void kernel_launch(void* const* d_in, const int* in_sizes, int n_in,
                              void* d_out, int out_size, void* d_ws, size_t ws_size,
                              hipStream_t stream){
  (void)in_sizes; (void)n_in; (void)out_size; (void)ws_size;
  const float* features=(const float*)d_in[0];
  const float* fc1_w  =(const float*)d_in[1];
  const float* fc1_b  =(const float*)d_in[2];
  const float* cls_tok=(const float*)d_in[3];
  const float* fc2_w  =(const float*)d_in[24];
  const float* fc2_b  =(const float*)d_in[25];
  float* out=(float*)d_out;

  char* wp=(char*)d_ws;
  auto allocB=[&](size_t bytes)->char*{
    char* p=wp; wp+=((bytes+255)/256)*256; return p;
  };
  float* h    =(float*)allocB((size_t)NB*NTOK*DM*4);
  float* q    =(float*)allocB((size_t)NB*NPAD*DM*4);
  float* kbuf =(float*)allocB((size_t)NB*NPAD*DM*4);
  float* v    =(float*)allocB((size_t)NB*NPAD*DM*4);
  unsigned short* xlnb=(unsigned short*)allocB((size_t)NB*NPAD*DM*2);
  unsigned short* featbf=(unsigned short*)allocB((size_t)32000*1024*2);
  unsigned short* wtf=(unsigned short*)allocB((size_t)512*1024*2);
  unsigned short* wtq=(unsigned short*)allocB((size_t)1536*512*2);
  unsigned short* wtp=(unsigned short*)allocB((size_t)512*512*2);
  float* ql  =(float*)allocB((size_t)16*LM*HD*4);
  float* kl  =(float*)allocB((size_t)16*LM*HD*4);
  float* attn2=(float*)allocB((size_t)16*LM*LM*4);
  float* z0  =(float*)allocB((size_t)16*LM*LM*4);
  float* z1  =(float*)allocB((size_t)16*LM*LM*4);
  float* Ab  =(float*)allocB((size_t)16*LM*LM*4);
  float* Ub  =(float*)allocB((size_t)16*LM*LM*4);
  float* Tb  =(float*)allocB((size_t)16*LM*LM*4);
  float* a3v =(float*)allocB((size_t)16*LM*HD*4);
  float* W2b =(float*)allocB((size_t)16*LM*HD*4);
  float* pacc=(float*)allocB((size_t)16*8*LM*HD*4);
  float* pms =(float*)allocB((size_t)16*8*LM*2*4);
  float* rs  =(float*)allocB(4096*4);
  float* cs  =(float*)allocB(4096*4);
  float* scl =(float*)allocB(64*4);

  float* aoh=kbuf;            // reuse: k dead after attn3v
  unsigned short* ao=xlnb;    // reuse: xln dead after qkv

  auto nystrom=[&](const float* ng, const float* nbias, const float* qkvw,
                   const float* outw, const float* outb, const float* resw){
    k_lnpad<<<NB*NPAD,256,0,stream>>>(h, ng, nbias, xlnb);
    k_wconv_t<<<(512*1536+255)/256,256,0,stream>>>(qkvw, wtq, 512, 1536);
    k_mfma_gemm<1><<<dim3(12,256),256,0,stream>>>(xlnb, wtq, 32768,1536,512,
                                                  nullptr, q, kbuf, v);
    k_lmean<<<4096,64,0,stream>>>(q, ql);
    k_lmean<<<4096,64,0,stream>>>(kbuf, kl);
    k_attn2<<<4096,256,0,stream>>>(ql, kl, attn2);
    k_rowsum<<<4096,256,0,stream>>>(attn2, rs);
    k_colsum<<<16,256,0,stream>>>(attn2, cs);
    k_pinvscale<<<1,256,0,stream>>>(rs, cs, scl);
    k_zinit<<<4096,256,0,stream>>>(attn2, scl, z0);
    float* zc=z0; float* zn=z1;
    for(int it=0;it<6;it++){
      k_bmm<<<dim3(4,4,16),256,0,stream>>>(attn2, zc, Ab, 256,256,256, 1.f, 0.f, 0.f);
      k_bmm<<<dim3(4,4,16),256,0,stream>>>(Ab, Ab, Ub, 256,256,256, 1.f, 7.f, 15.f);
      k_bmm<<<dim3(4,4,16),256,0,stream>>>(Ab, Ub, Tb, 256,256,256, 1.f, 0.f, 13.f);
      k_bmm<<<dim3(4,4,16),256,0,stream>>>(zc, Tb, zn, 256,256,256, 0.25f, 0.f, 0.f);
      float* tp=zc; zc=zn; zn=tp;
    }
    k_attn3v3<<<dim3(8,32,16),256,0,stream>>>(ql, kbuf, v, pacc, pms);
    k_attn3vc<<<1024,256,0,stream>>>(pacc, pms, a3v);
    k_bmm<<<dim3(1,4,16),256,0,stream>>>(zc, a3v, W2b, 256,64,256, 1.f, 0.f, 0.f);
    k_attn1b<<<dim3(512,16),256,0,stream>>>(q, kl, W2b, aoh);
    k_resconv<<<65536,256,0,stream>>>(v, resw, aoh);
    k_headmerge<<<65536,256,0,stream>>>(aoh, ao);
    k_wconv_t<<<(512*512+255)/256,256,0,stream>>>(outw, wtp, 512, 512);
    k_mfma_gemm<2><<<dim3(4,256),256,0,stream>>>(ao, wtp, 32768,512,512,
                                                 outb, h, nullptr, nullptr);
  };

  // fc1 + relu + dup + cls (bf16 MFMA)
  k_f2bf4<<<32000,256,0,stream>>>(features, featbf, 32000*1024/4);
  k_wconv_t<<<(1024*512+255)/256,256,0,stream>>>(fc1_w, wtf, 1024, 512);
  k_mfma_gemm<0><<<dim3(4,250),256,0,stream>>>(featbf, wtf, 32000,512,1024,
                                               fc1_b, h, nullptr, nullptr);
  k_cls<<<4,256,0,stream>>>(cls_tok, h);

  // layer 1 attention
  nystrom((const float*)d_in[4],(const float*)d_in[5],(const float*)d_in[6],
          (const float*)d_in[7],(const float*)d_in[8],(const float*)d_in[9]);

  // PPEG
  float* tmp=q;
  float* wcat=attn2;
  hipMemcpyAsync(tmp, h, (size_t)NB*NTOK*DM*4, hipMemcpyDeviceToDevice, stream);
  k_wprep<<<168,256,0,stream>>>(
      (const float*)d_in[10],(const float*)d_in[11],
      (const float*)d_in[12],(const float*)d_in[13],
      (const float*)d_in[14],(const float*)d_in[15], wcat);
  k_ppeg2<<<dim3(484,8,2),256,0,stream>>>(tmp, wcat, h);

  // layer 2 attention
  nystrom((const float*)d_in[16],(const float*)d_in[17],(const float*)d_in[18],
          (const float*)d_in[19],(const float*)d_in[20],(const float*)d_in[21]);

  // final LN(row0) @ fc2
  k_final<<<2,256,0,stream>>>(h,(const float*)d_in[22],(const float*)d_in[23],
                              fc2_w, fc2_b, out);
}

// Round 4
// 2558.512 us; speedup vs baseline: 7.2918x; 2.3864x over previous
//
#include <hip/hip_runtime.h>
#include <math.h>

#define NTOK 16130   // 1 + 127*127
#define NPAD 16384
#define PADF 254
#define NB   2
#define DM   512
#define NH   8
#define HD   64
#define LM   256
#define SEG  64

typedef __attribute__((ext_vector_type(8))) short short8v;
typedef __attribute__((ext_vector_type(4))) float f32x4;

// ---------------- helpers ----------------
__device__ __forceinline__ float wred_max(float v){
  #pragma unroll
  for(int o=32;o;o>>=1) v=fmaxf(v,__shfl_xor(v,o));
  return v;
}
__device__ __forceinline__ float wred_sum(float v){
  #pragma unroll
  for(int o=32;o;o>>=1) v+=__shfl_xor(v,o);
  return v;
}
__device__ __forceinline__ float block_max256(float v, float* s4){
  v=wred_max(v);
  if((threadIdx.x&63)==0) s4[threadIdx.x>>6]=v;
  __syncthreads();
  v=fmaxf(fmaxf(s4[0],s4[1]),fmaxf(s4[2],s4[3]));
  __syncthreads();
  return v;
}
__device__ __forceinline__ float block_sum256(float v, float* s4){
  v=wred_sum(v);
  if((threadIdx.x&63)==0) s4[threadIdx.x>>6]=v;
  __syncthreads();
  v=s4[0]+s4[1]+s4[2]+s4[3];
  __syncthreads();
  return v;
}
__device__ __forceinline__ unsigned short f2bf(float f){
  unsigned u=__float_as_uint(f);
  u = u + 0x7FFFu + ((u>>16)&1u);
  return (unsigned short)(u>>16);
}
__device__ __forceinline__ float bf2f(unsigned short u){
  return __uint_as_float(((unsigned)u)<<16);
}
__device__ __forceinline__ unsigned cvtpk(float a, float b){
  unsigned r;
  asm("v_cvt_pk_bf16_f32 %0, %1, %2" : "=v"(r) : "v"(a), "v"(b));
  return r;
}

// ---------------- conversions ----------------
__global__ void k_f2bf4(const float* __restrict__ x, unsigned short* __restrict__ y, int n4){
  int i=blockIdx.x*256+threadIdx.x; if(i>=n4) return;
  float4 v=((const float4*)x)[i];
  ushort4 r; r.x=f2bf(v.x); r.y=f2bf(v.y); r.z=f2bf(v.z); r.w=f2bf(v.w);
  ((ushort4*)y)[i]=r;
}
// W[K][N] f32 -> Wt[N][K] bf16
__global__ void k_wconv_t(const float* __restrict__ W, unsigned short* __restrict__ Wt,
                          int K, int N){
  int idx=blockIdx.x*256+threadIdx.x; if(idx>=K*N) return;
  int k=idx/N, n=idx%N;
  Wt[(size_t)n*K+k]=f2bf(W[idx]);
}
__global__ void k_split(const float* __restrict__ x, unsigned short* __restrict__ hi,
                        unsigned short* __restrict__ lo, int n){
  int i=blockIdx.x*256+threadIdx.x; if(i>=n) return;
  float v=x[i]; unsigned short h=f2bf(v);
  hi[i]=h; lo[i]=f2bf(v-bf2f(h));
}

// ---------------- MFMA bf16 GEMM: 128x128 tile, BK=32 ----------------
template<int MODE>
__global__ __launch_bounds__(256) void k_mfma_gemm(
    const unsigned short* __restrict__ A, const unsigned short* __restrict__ Bt,
    int M, int N, int K,
    const float* __restrict__ bias,
    void* __restrict__ o0, void* __restrict__ o1, void* __restrict__ o2)
{
  __shared__ unsigned short As[128*32];
  __shared__ unsigned short Bs[128*32];
  int t=threadIdx.x;
  int row0=blockIdx.y*128, col0=blockIdx.x*128;
  int lane=t&63, w=t>>6, wr=w>>1, wc=w&1, lr=lane&15, kg=lane>>4;
  f32x4 acc[4][4];
  #pragma unroll
  for(int m=0;m<4;m++)
    #pragma unroll
    for(int n=0;n<4;n++) acc[m][n]=(f32x4){0.f,0.f,0.f,0.f};

  short8v ra[2], rb[2];
  #pragma unroll
  for(int i=0;i<2;i++){
    int flat=i*256+t, r=flat>>2, k8=flat&3;
    ra[i]=*(const short8v*)(A +(size_t)(row0+r)*K + k8*8);
    rb[i]=*(const short8v*)(Bt+(size_t)(col0+r)*K + k8*8);
  }
  int k0=0;
  for(;;){
    __syncthreads();
    #pragma unroll
    for(int i=0;i<2;i++){
      int flat=i*256+t;
      *(short8v*)(As+flat*8)=ra[i];
      *(short8v*)(Bs+flat*8)=rb[i];
    }
    __syncthreads();
    k0+=32;
    if(k0<K){
      #pragma unroll
      for(int i=0;i<2;i++){
        int flat=i*256+t, r=flat>>2, k8=flat&3;
        ra[i]=*(const short8v*)(A +(size_t)(row0+r)*K + k0 + k8*8);
        rb[i]=*(const short8v*)(Bt+(size_t)(col0+r)*K + k0 + k8*8);
      }
    }
    short8v af[4], bf[4];
    #pragma unroll
    for(int m=0;m<4;m++) af[m]=*(const short8v*)(As+(wr*64+m*16+lr)*32 + kg*8);
    #pragma unroll
    for(int n=0;n<4;n++) bf[n]=*(const short8v*)(Bs+(wc*64+n*16+lr)*32 + kg*8);
    #pragma unroll
    for(int m=0;m<4;m++)
      #pragma unroll
      for(int n=0;n<4;n++)
        acc[m][n]=__builtin_amdgcn_mfma_f32_16x16x32_bf16(af[m],bf[n],acc[m][n],0,0,0);
    if(k0>=K) break;
  }
  // epilogue
  #pragma unroll
  for(int m=0;m<4;m++){
    int rbase=row0 + wr*64 + m*16 + kg*4;
    #pragma unroll
    for(int j=0;j<4;j++){
      int r=rbase+j;
      #pragma unroll
      for(int n=0;n<4;n++){
        int c=col0 + wc*64 + n*16 + lr;
        float val=acc[m][n][j];
        if(MODE==0){
          float* h=(float*)o0;
          int bb=(r>=16000)?1:0, ii=r-bb*16000;
          float vv=fmaxf(val+bias[c],0.f);
          h[((size_t)bb*NTOK + 1 + ii)*DM + c]=vv;
          if(ii<129) h[((size_t)bb*NTOK + 16001 + ii)*DM + c]=vv;
        } else if(MODE==1){
          int bb=r>>14, rr=r&16383;
          int which=c>>9, hcol=c&511, head=hcol>>6, dd=hcol&63;
          size_t o=(((size_t)bb*NH+head)*NPAD + rr)*HD + dd;
          if(which==0)      ((unsigned short*)o0)[o]=f2bf(val*0.125f);
          else if(which==1) ((unsigned short*)o1)[o]=f2bf(val);
          else              ((float*)o2)[o]=val;
        } else {
          float* h=(float*)o0;
          int bb=r>>14, rr=r&16383;
          if(rr>=PADF)
            h[((size_t)bb*NTOK + (rr-PADF))*DM + c]+=val+bias[c];
        }
      }
    }
  }
}

__global__ void k_cls(const float* __restrict__ cls, float* __restrict__ h){
  int t=blockIdx.x*256+threadIdx.x;
  if(t<2*DM) h[(size_t)(t>>9)*NTOK*DM + (t&511)]=cls[t&511];
}

// ---------------- layernorm + front zero-pad -> bf16 ----------------
__global__ __launch_bounds__(256) void k_lnpad(
    const float* __restrict__ h, const float* __restrict__ g,
    const float* __restrict__ bta, unsigned short* __restrict__ xln)
{
  int r=blockIdx.x;
  int bb=r>>14, i=r&16383;
  int t=threadIdx.x;
  unsigned short* dst=xln+(size_t)r*DM;
  if(i<PADF){ dst[t]=0; dst[t+256]=0; return; }
  const float* src=h+((size_t)bb*NTOK + (i-PADF))*DM;
  float x0=src[t], x1=src[t+256];
  __shared__ float s4[4];
  float mu=block_sum256(x0+x1,s4)*(1.f/512.f);
  float d0=x0-mu, d1=x1-mu;
  float var=block_sum256(d0*d0+d1*d1,s4)*(1.f/512.f);
  float rst=rsqrtf(var+1e-5f);
  dst[t]    =f2bf(d0*rst*g[t]    +bta[t]);
  dst[t+256]=f2bf(d1*rst*g[t+256]+bta[t+256]);
}

// ---------------- landmark means (bf16 in, f32+bf16 out) ----------------
__global__ void k_lmean(const unsigned short* __restrict__ src, float* __restrict__ dstf,
                        unsigned short* __restrict__ dstb){
  int bh=blockIdx.x>>8, s=blockIdx.x&255, d=threadIdx.x;  // 64 threads
  const unsigned short* p=src + (((size_t)bh*NPAD)+s*SEG)*HD + d;
  float acc=0.f;
  #pragma unroll
  for(int l=0;l<SEG;l++) acc+=bf2f(p[(size_t)l*HD]);
  float m=acc*(1.f/64.f);
  dstf[((size_t)bh*LM+s)*HD+d]=m;
  dstb[((size_t)bh*LM+s)*HD+d]=f2bf(m);
}

// ---------------- v f32 head-major -> vt bf16 [bh][64][NPAD] ----------------
__global__ __launch_bounds__(256) void k_vtrans(
    const float* __restrict__ v, unsigned short* __restrict__ vt)
{
  __shared__ unsigned short tile[64][72];
  int kt=blockIdx.x, bh=blockIdx.y;
  int t=threadIdx.x;
  int r=t>>2, sgq=t&3;
  const float* src=v + ((size_t)bh*NPAD + kt*64 + r)*HD + sgq*16;
  #pragma unroll
  for(int i=0;i<16;i+=4){
    float4 f4=*(const float4*)(src+i);
    tile[r][sgq*16+i  ]=f2bf(f4.x);
    tile[r][sgq*16+i+1]=f2bf(f4.y);
    tile[r][sgq*16+i+2]=f2bf(f4.z);
    tile[r][sgq*16+i+3]=f2bf(f4.w);
  }
  __syncthreads();
  int d=t>>2;
  union{unsigned short u[16]; short8v v8[2];} pk;
  #pragma unroll
  for(int i=0;i<16;i++) pk.u[i]=tile[sgq*16+i][d];
  short8v* dst=(short8v*)(vt + ((size_t)bh*HD + d)*NPAD + kt*64 + sgq*16);
  dst[0]=pk.v8[0]; dst[1]=pk.v8[1];
}

// ---------------- attn2 = softmax(ql @ kl^T) f32 ----------------
__global__ __launch_bounds__(256) void k_attn2(
    const float* __restrict__ ql, const float* __restrict__ kl, float* __restrict__ attn2)
{
  __shared__ float qrow[64]; __shared__ float s4[4];
  int bh=blockIdx.x>>8, i=blockIdx.x&255, j=threadIdx.x;
  if(j<64) qrow[j]=ql[((size_t)bh*LM+i)*HD+j];
  __syncthreads();
  const float* kp=kl+((size_t)bh*LM+j)*HD;
  float l=0.f;
  #pragma unroll
  for(int d=0;d<64;d++) l+=qrow[d]*kp[d];
  float m=block_max256(l,s4);
  float e=__expf(l-m);
  float s=block_sum256(e,s4);
  attn2[((size_t)bh*LM+i)*LM+j]=e/s;
}

// ---------------- pinv helpers ----------------
__global__ void k_rowsum(const float* __restrict__ x, float* __restrict__ rs){
  __shared__ float s4[4];
  size_t row=blockIdx.x;
  float v=x[row*256+threadIdx.x];
  float s=block_sum256(v,s4);
  if(threadIdx.x==0) rs[row]=s;
}
__global__ void k_colsum(const float* __restrict__ x, float* __restrict__ cs){
  int bh=blockIdx.x, j=threadIdx.x;
  const float* p=x+(size_t)bh*65536;
  float s=0.f;
  for(int i=0;i<256;i++) s+=p[(size_t)i*256+j];
  cs[bh*256+j]=s;
}
__global__ void k_pinvscale(const float* __restrict__ rs, const float* __restrict__ cs,
                            float* __restrict__ scale){
  __shared__ float s4[4];
  float mr=-1e30f, mc=-1e30f;
  for(int i=threadIdx.x;i<4096;i+=256){ mr=fmaxf(mr,rs[i]); mc=fmaxf(mc,cs[i]); }
  mr=block_max256(mr,s4);
  mc=block_max256(mc,s4);
  if(threadIdx.x==0) scale[0]=1.f/(mr*mc);
}
__global__ void k_zinit_hl(const float* __restrict__ x, const float* __restrict__ scale,
    unsigned short* __restrict__ zh, unsigned short* __restrict__ zl,
    unsigned short* __restrict__ zth, unsigned short* __restrict__ ztl){
  int bh=blockIdx.x>>8, i=blockIdx.x&255, j=threadIdx.x;
  float s=scale[0];
  size_t base=(size_t)bh*65536;
  float vn=x[base+(size_t)j*256+i]*s;   // z0[i][j] = X^T * s
  float vt=x[base+(size_t)i*256+j]*s;   // z0^T[i][j]
  size_t o=base+(size_t)i*256+j;
  unsigned short h=f2bf(vn); zh[o]=h; zl[o]=f2bf(vn-bf2f(h));
  h=f2bf(vt); zth[o]=h; ztl[o]=f2bf(vt-bf2f(h));
}

// ---------------- hi/lo split bf16 MFMA batched GEMM (pinv chain) -----------
// MODE 0: C=A@B (emit normal+trans)    MODE 1: C=15I-7X+acc (trans only)
// MODE 2: C=13I-acc (trans only)       MODE 3: C=0.25*acc (normal+trans)
// MODE 4: C=acc (trans only, hi only; Ndim=64)
template<int MODE>
__global__ __launch_bounds__(256) void k_bmm3(
    const unsigned short* __restrict__ Ah, const unsigned short* __restrict__ Al,
    const unsigned short* __restrict__ Bth, const unsigned short* __restrict__ Btl,
    const unsigned short* __restrict__ Xh, const unsigned short* __restrict__ Xl,
    unsigned short* __restrict__ Cnh, unsigned short* __restrict__ Cnl,
    unsigned short* __restrict__ Cth, unsigned short* __restrict__ Ctl,
    int Ndim)
{
  __shared__ unsigned short AsH[64*40], AsL[64*40], BsH[64*40], BsL[64*40];
  int bh=blockIdx.z;
  int n0=blockIdx.x*64, m0=blockIdx.y*64;
  int t=threadIdx.x, lane=t&63, w=t>>6;
  int c=lane&15, g=lane>>4;
  int wr=(w>>1)*32, wc=(w&1)*32;
  f32x4 acc[2][2];
  #pragma unroll
  for(int i=0;i<2;i++)
    #pragma unroll
    for(int j=0;j<2;j++) acc[i][j]=(f32x4){0.f,0.f,0.f,0.f};
  size_t Abase=(size_t)bh*65536;
  size_t Bbase=(size_t)bh*(size_t)Ndim*256;
  int r=t>>2, sg=t&3;
  for(int k0=0;k0<256;k0+=32){
    __syncthreads();
    *(short8v*)(AsH+r*40+sg*8)=*(const short8v*)(Ah +Abase+(size_t)(m0+r)*256+k0+sg*8);
    *(short8v*)(AsL+r*40+sg*8)=*(const short8v*)(Al +Abase+(size_t)(m0+r)*256+k0+sg*8);
    *(short8v*)(BsH+r*40+sg*8)=*(const short8v*)(Bth+Bbase+(size_t)(n0+r)*256+k0+sg*8);
    *(short8v*)(BsL+r*40+sg*8)=*(const short8v*)(Btl+Bbase+(size_t)(n0+r)*256+k0+sg*8);
    __syncthreads();
    short8v bhf[2], blf[2];
    #pragma unroll
    for(int nt=0;nt<2;nt++){
      bhf[nt]=*(const short8v*)(BsH+(wc+nt*16+c)*40+g*8);
      blf[nt]=*(const short8v*)(BsL+(wc+nt*16+c)*40+g*8);
    }
    #pragma unroll
    for(int mt=0;mt<2;mt++){
      short8v ahh=*(const short8v*)(AsH+(wr+mt*16+c)*40+g*8);
      short8v all=*(const short8v*)(AsL+(wr+mt*16+c)*40+g*8);
      #pragma unroll
      for(int nt=0;nt<2;nt++){
        acc[mt][nt]=__builtin_amdgcn_mfma_f32_16x16x32_bf16(ahh,bhf[nt],acc[mt][nt],0,0,0);
        acc[mt][nt]=__builtin_amdgcn_mfma_f32_16x16x32_bf16(ahh,blf[nt],acc[mt][nt],0,0,0);
        acc[mt][nt]=__builtin_amdgcn_mfma_f32_16x16x32_bf16(all,bhf[nt],acc[mt][nt],0,0,0);
      }
    }
  }
  #pragma unroll
  for(int mt=0;mt<2;mt++)
    #pragma unroll
    for(int nt=0;nt<2;nt++){
      int rb=m0+wr+mt*16+g*4;
      int cc=n0+wc+nt*16+c;
      float vv[4];
      #pragma unroll
      for(int j=0;j<4;j++){
        float a=acc[mt][nt][j];
        int rr=rb+j;
        if(MODE==1){
          float xv=bf2f(Xh[Abase+(size_t)rr*256+cc])+bf2f(Xl[Abase+(size_t)rr*256+cc]);
          a=(rr==cc?15.f:0.f)-7.f*xv+a;
        } else if(MODE==2){
          a=(rr==cc?13.f:0.f)-a;
        } else if(MODE==3){
          a*=0.25f;
        }
        vv[j]=a;
      }
      if(MODE==0||MODE==3){
        #pragma unroll
        for(int j=0;j<4;j++){
          unsigned short h=f2bf(vv[j]);
          Cnh[Abase+(size_t)(rb+j)*256+cc]=h;
          Cnl[Abase+(size_t)(rb+j)*256+cc]=f2bf(vv[j]-bf2f(h));
        }
      }
      {
        ushort4 hv, lv;
        hv.x=f2bf(vv[0]); hv.y=f2bf(vv[1]); hv.z=f2bf(vv[2]); hv.w=f2bf(vv[3]);
        lv.x=f2bf(vv[0]-bf2f(hv.x)); lv.y=f2bf(vv[1]-bf2f(hv.y));
        lv.z=f2bf(vv[2]-bf2f(hv.z)); lv.w=f2bf(vv[3]-bf2f(hv.w));
        size_t co=((size_t)bh*Ndim+cc)*256+rb;
        *(ushort4*)(Cth+co)=hv;
        if(MODE!=4) *(ushort4*)(Ctl+co)=lv;
      }
    }
}

// ---------------- attn3@v : MFMA flash, split-K 16 chunks --------------------
__global__ __launch_bounds__(512) void k_attn3m(
    const unsigned short* __restrict__ qlb,
    const unsigned short* __restrict__ kb,
    const unsigned short* __restrict__ vtb,
    float* __restrict__ pacc, float* __restrict__ pms)
{
  __shared__ unsigned short Ks[64*72];
  __shared__ unsigned short Vs[64*72];
  int ck=blockIdx.x, bh=blockIdx.y;
  int t=threadIdx.x, lane=t&63, w=t>>6;
  int c=lane&15, g=lane>>4;
  short8v Qf[2][2];
  #pragma unroll
  for(int n=0;n<2;n++)
    #pragma unroll
    for(int kw=0;kw<2;kw++)
      Qf[n][kw]=*(const short8v*)(qlb + ((size_t)bh*LM + w*32 + n*16 + c)*HD + kw*32 + g*8);
  f32x4 accO[4][2];
  float mrun[2], srun[2];
  #pragma unroll
  for(int n=0;n<2;n++){
    mrun[n]=-3e38f; srun[n]=0.f;
    #pragma unroll
    for(int d=0;d<4;d++) accO[d][n]=(f32x4){0.f,0.f,0.f,0.f};
  }
  int sr=t>>3, sgk=t&7;
  for(int sc=0;sc<16;++sc){
    int key0=ck*1024 + sc*64;
    __syncthreads();
    *(short8v*)(Ks + sr*72 + sgk*8) =
      *(const short8v*)(kb + ((size_t)bh*NPAD + key0 + sr)*HD + sgk*8);
    *(short8v*)(Vs + sr*72 + sgk*8) =
      *(const short8v*)(vtb + ((size_t)bh*HD + sr)*NPAD + key0 + sgk*8);
    __syncthreads();
    f32x4 s[4][2];
    #pragma unroll
    for(int mt=0;mt<4;mt++){
      short8v a0=*(const short8v*)(Ks + (mt*16+c)*72 + g*8);
      short8v a1=*(const short8v*)(Ks + (mt*16+c)*72 + 32 + g*8);
      #pragma unroll
      for(int n=0;n<2;n++){
        f32x4 z=(f32x4){0.f,0.f,0.f,0.f};
        z=__builtin_amdgcn_mfma_f32_16x16x32_bf16(a0,Qf[n][0],z,0,0,0);
        z=__builtin_amdgcn_mfma_f32_16x16x32_bf16(a1,Qf[n][1],z,0,0,0);
        s[mt][n]=z;
      }
    }
    unsigned U[2][4][2];
    #pragma unroll
    for(int n=0;n<2;n++){
      float cm=-3e38f;
      #pragma unroll
      for(int mt=0;mt<4;mt++)
        #pragma unroll
        for(int j=0;j<4;j++) cm=fmaxf(cm,s[mt][n][j]);
      cm=fmaxf(cm,__shfl_xor(cm,16));
      cm=fmaxf(cm,__shfl_xor(cm,32));
      float mnew=fmaxf(mrun[n],cm);
      float f=__expf(mrun[n]-mnew);
      mrun[n]=mnew;
      float ps=0.f;
      #pragma unroll
      for(int mt=0;mt<4;mt++){
        float p0=__expf(s[mt][n][0]-mnew);
        float p1=__expf(s[mt][n][1]-mnew);
        float p2=__expf(s[mt][n][2]-mnew);
        float p3=__expf(s[mt][n][3]-mnew);
        ps+=p0+p1+p2+p3;
        U[n][mt][0]=cvtpk(p0,p1);
        U[n][mt][1]=cvtpk(p2,p3);
      }
      ps+=__shfl_xor(ps,16); ps+=__shfl_xor(ps,32);
      srun[n]=srun[n]*f+ps;
      #pragma unroll
      for(int d=0;d<4;d++){
        accO[d][n][0]*=f; accO[d][n][1]*=f; accO[d][n][2]*=f; accO[d][n][3]*=f;
      }
    }
    #pragma unroll
    for(int kw=0;kw<2;kw++){
      short8v pf[2];
      #pragma unroll
      for(int n=0;n<2;n++){
        union{unsigned u[4]; short8v v;} pk;
        #pragma unroll
        for(int wd=0;wd<4;wd++){
          int sl=c+16*(((g&1)<<1)+(wd>>1));
          unsigned va=(unsigned)__shfl((int)U[n][kw*2  ][wd&1],sl);
          unsigned vb=(unsigned)__shfl((int)U[n][kw*2+1][wd&1],sl);
          pk.u[wd]=(lane>=32)?vb:va;
        }
        pf[n]=pk.v;
      }
      #pragma unroll
      for(int d=0;d<4;d++){
        short8v vf=*(const short8v*)(Vs + (d*16+c)*72 + kw*32 + g*8);
        accO[d][0]=__builtin_amdgcn_mfma_f32_16x16x32_bf16(vf,pf[0],accO[d][0],0,0,0);
        accO[d][1]=__builtin_amdgcn_mfma_f32_16x16x32_bf16(vf,pf[1],accO[d][1],0,0,0);
      }
    }
  }
  size_t pb=((size_t)bh*16+ck)*LM;
  #pragma unroll
  for(int n=0;n<2;n++){
    int q=w*32+n*16+c;
    #pragma unroll
    for(int d=0;d<4;d++)
      *(f32x4*)(pacc + (pb+q)*HD + d*16 + g*4)=accO[d][n];
    if(g==0){ pms[(pb+q)*2]=mrun[n]; pms[(pb+q)*2+1]=srun[n]; }
  }
}
__global__ __launch_bounds__(256) void k_attn3vc(
    const float* __restrict__ pacc, const float* __restrict__ pms,
    unsigned short* __restrict__ a3vth, unsigned short* __restrict__ a3vtl)
{
  int gid=blockIdx.x*4+(threadIdx.x>>6);
  int bh=gid>>8, row=gid&255, lane=threadIdx.x&63;
  float M=-3e38f;
  float ms[16], ss[16];
  #pragma unroll
  for(int c=0;c<16;c++){
    size_t pb=((size_t)bh*16+c)*LM+row;
    ms[c]=pms[pb*2]; ss[c]=pms[pb*2+1];
    M=fmaxf(M,ms[c]);
  }
  float S=0.f,a=0.f;
  #pragma unroll
  for(int c=0;c<16;c++){
    float f=__expf(ms[c]-M);
    S+=ss[c]*f;
    a+=pacc[(((size_t)bh*16+c)*LM+row)*HD+lane]*f;
  }
  float v=a/S;
  unsigned short hi=f2bf(v);
  a3vth[((size_t)bh*HD+lane)*LM+row]=hi;
  a3vtl[((size_t)bh*HD+lane)*LM+row]=f2bf(v-bf2f(hi));
}

// ---------------- attn1 @ W2 : MFMA, 256 landmarks one-shot ------------------
__global__ __launch_bounds__(512) void k_attn1m(
    const unsigned short* __restrict__ qb,
    const unsigned short* __restrict__ klb,
    const unsigned short* __restrict__ w2t,
    float* __restrict__ aoh)
{
  __shared__ unsigned short klS[256*72];
  __shared__ unsigned short w2S[64*264];
  int qt=blockIdx.x, bh=blockIdx.y;
  int t=threadIdx.x, lane=t&63, w=t>>6;
  int c=lane&15, g=lane>>4;
  {
    int r=t>>1, hf=t&1;
    const short8v* s=(const short8v*)(klb + ((size_t)bh*LM+r)*HD + hf*32);
    short8v* d=(short8v*)(klS + r*72 + hf*32);
    d[0]=s[0]; d[1]=s[1]; d[2]=s[2]; d[3]=s[3];
    int r2=t>>3, sg2=t&7;
    const short8v* s2=(const short8v*)(w2t + ((size_t)bh*HD+r2)*LM + sg2*32);
    short8v* d2=(short8v*)(w2S + r2*264 + sg2*32);
    d2[0]=s2[0]; d2[1]=s2[1]; d2[2]=s2[2]; d2[3]=s2[3];
  }
  __syncthreads();
  int q0=qt*256 + w*32;
  #pragma unroll
  for(int n=0;n<2;n++){
    const unsigned short* qrow=qb + ((size_t)bh*NPAD + q0 + n*16 + c)*HD;
    short8v qf0=*(const short8v*)(qrow + g*8);
    short8v qf1=*(const short8v*)(qrow + 32 + g*8);
    f32x4 s[16];
    #pragma unroll
    for(int mt=0;mt<16;mt++){
      short8v a0=*(const short8v*)(klS + (mt*16+c)*72 + g*8);
      short8v a1=*(const short8v*)(klS + (mt*16+c)*72 + 32 + g*8);
      f32x4 z=(f32x4){0.f,0.f,0.f,0.f};
      z=__builtin_amdgcn_mfma_f32_16x16x32_bf16(a0,qf0,z,0,0,0);
      z=__builtin_amdgcn_mfma_f32_16x16x32_bf16(a1,qf1,z,0,0,0);
      s[mt]=z;
    }
    float M=-3e38f;
    #pragma unroll
    for(int mt=0;mt<16;mt++)
      #pragma unroll
      for(int j=0;j<4;j++) M=fmaxf(M,s[mt][j]);
    M=fmaxf(M,__shfl_xor(M,16));
    M=fmaxf(M,__shfl_xor(M,32));
    float sum=0.f;
    unsigned U[16][2];
    #pragma unroll
    for(int mt=0;mt<16;mt++){
      float p0=__expf(s[mt][0]-M);
      float p1=__expf(s[mt][1]-M);
      float p2=__expf(s[mt][2]-M);
      float p3=__expf(s[mt][3]-M);
      sum+=p0+p1+p2+p3;
      U[mt][0]=cvtpk(p0,p1);
      U[mt][1]=cvtpk(p2,p3);
    }
    sum+=__shfl_xor(sum,16); sum+=__shfl_xor(sum,32);
    float inv=1.f/sum;
    f32x4 accO[4];
    #pragma unroll
    for(int d=0;d<4;d++) accO[d]=(f32x4){0.f,0.f,0.f,0.f};
    #pragma unroll
    for(int kw=0;kw<8;kw++){
      union{unsigned u[4]; short8v v;} pk;
      #pragma unroll
      for(int wd=0;wd<4;wd++){
        int sl=c+16*(((g&1)<<1)+(wd>>1));
        unsigned va=(unsigned)__shfl((int)U[kw*2  ][wd&1],sl);
        unsigned vb=(unsigned)__shfl((int)U[kw*2+1][wd&1],sl);
        pk.u[wd]=(lane>=32)?vb:va;
      }
      #pragma unroll
      for(int d=0;d<4;d++){
        short8v vf=*(const short8v*)(w2S + (d*16+c)*264 + kw*32 + g*8);
        accO[d]=__builtin_amdgcn_mfma_f32_16x16x32_bf16(vf,pk.v,accO[d],0,0,0);
      }
    }
    int q=q0+n*16+c;
    #pragma unroll
    for(int d=0;d<4;d++){
      f32x4 o=accO[d];
      o[0]*=inv; o[1]*=inv; o[2]*=inv; o[3]*=inv;
      *(f32x4*)(aoh + ((size_t)bh*NPAD+q)*HD + d*16 + g*4)=o;
    }
  }
}

// ---------------- depthwise 33-tap conv on v, += into aoh ----------------
__global__ void k_resconv(const float* __restrict__ vv, const float* __restrict__ rw,
                          float* __restrict__ aoh){
  size_t idx=(size_t)blockIdx.x*256+threadIdx.x;
  int d=idx&63; size_t r=idx>>6; int i=r&16383; int bh=(int)(r>>14); int hh=bh&7;
  const float* vb=vv+((size_t)bh*NPAD)*HD+d;
  float a=0.f;
  #pragma unroll
  for(int tk=0;tk<33;tk++){
    int src=i+tk-16;
    if(src>=0 && src<NPAD) a+=vb[(size_t)src*HD]*rw[hh*33+tk];
  }
  aoh[idx]+=a;
}

// ---------------- head-major -> row-major merge -> bf16 ----------------
__global__ void k_headmerge(const float* __restrict__ aoh, unsigned short* __restrict__ ao){
  size_t idx=(size_t)blockIdx.x*256+threadIdx.x;
  int c=idx&511; size_t r=idx>>9; int i=r&16383; int bb=(int)(r>>14);
  int hh=c>>6, dd=c&63;
  ao[idx]=f2bf(aoh[(((size_t)bb*NH+hh)*NPAD+i)*HD+dd]);
}

// ---------------- PPEG weight prep ----------------
__global__ void k_wprep(const float* __restrict__ w7, const float* __restrict__ b7,
                        const float* __restrict__ w5, const float* __restrict__ b5,
                        const float* __restrict__ w3, const float* __restrict__ b3,
                        float* __restrict__ wcat){
  int t=blockIdx.x*256+threadIdx.x;
  if(t>=84*512) return;
  int r=t>>9, c=t&511;
  float v;
  if(r<49)      v=w7[(size_t)c*49+r];
  else if(r<74) v=w5[(size_t)c*25+(r-49)];
  else if(r<83) v=w3[(size_t)c*9+(r-74)];
  else          v=b7[c]+b5[c]+b3[c];
  wcat[t]=v;
}

// ---------------- PPEG: LDS-tiled 6x6x64ch stencil ----------------
__global__ __launch_bounds__(256) void k_ppeg2(
    const float* __restrict__ src, const float* __restrict__ wcat,
    float* __restrict__ h)
{
  __shared__ float patch[144][64];
  __shared__ float ws[84][64];
  int gx=blockIdx.x%22, gy=blockIdx.x/22;
  int cz=blockIdx.y, bb=blockIdx.z;
  int t=threadIdx.x, c=t&63, g=t>>6;
  int ty0=gy*6, tx0=gx*6;
  const float* base=src+((size_t)bb*NTOK+1)*DM + cz*64 + c;
  #pragma unroll
  for(int i=0;i<36;i++){
    int p=g+4*i;
    int py=p/12, px=p%12;
    int yy=ty0-3+py, xx=tx0-3+px;
    float v=0.f;
    if(yy>=0&&yy<127&&xx>=0&&xx<127) v=base[(size_t)(yy*127+xx)*DM];
    patch[p][c]=v;
  }
  #pragma unroll
  for(int i=0;i<21;i++){
    int r=g+4*i; if(r<84) ws[r][c]=wcat[(size_t)r*DM + cz*64 + c];
  }
  __syncthreads();
  float acc[9];
  int oy[9], ox[9];
  #pragma unroll
  for(int i=0;i<9;i++){
    int p=g*9+i; oy[i]=p/6; ox[i]=p%6;
    acc[i]=patch[(oy[i]+3)*12+(ox[i]+3)][c]+ws[83][c];
  }
  for(int ky=0;ky<7;ky++)
    for(int kx=0;kx<7;kx++){
      float wv=ws[ky*7+kx][c];
      #pragma unroll
      for(int i=0;i<9;i++)
        acc[i]+=patch[(oy[i]+ky)*12+ox[i]+kx][c]*wv;
    }
  for(int ky=0;ky<5;ky++)
    for(int kx=0;kx<5;kx++){
      float wv=ws[49+ky*5+kx][c];
      #pragma unroll
      for(int i=0;i<9;i++)
        acc[i]+=patch[(oy[i]+1+ky)*12+ox[i]+1+kx][c]*wv;
    }
  for(int ky=0;ky<3;ky++)
    for(int kx=0;kx<3;kx++){
      float wv=ws[74+ky*3+kx][c];
      #pragma unroll
      for(int i=0;i<9;i++)
        acc[i]+=patch[(oy[i]+2+ky)*12+ox[i]+2+kx][c]*wv;
    }
  #pragma unroll
  for(int i=0;i<9;i++){
    int y=ty0+oy[i], x=tx0+ox[i];
    if(y<127&&x<127)
      h[((size_t)bb*NTOK+1+(size_t)(y*127+x))*DM + cz*64 + c]=acc[i];
  }
}

// ---------------- final: LN(h[:,0]) @ fc2 + b ----------------
__global__ __launch_bounds__(256) void k_final(
    const float* __restrict__ h, const float* __restrict__ g, const float* __restrict__ bta,
    const float* __restrict__ w, const float* __restrict__ fb, float* __restrict__ out)
{
  int bb=blockIdx.x, t=threadIdx.x;
  const float* src=h+(size_t)bb*NTOK*DM;
  float x0=src[t], x1=src[t+256];
  __shared__ float s4[4];
  float mu=block_sum256(x0+x1,s4)*(1.f/512.f);
  float d0=x0-mu, d1=x1-mu;
  float var=block_sum256(d0*d0+d1*d1,s4)*(1.f/512.f);
  float rst=rsqrtf(var+1e-5f);
  float y0=d0*rst*g[t]+bta[t], y1=d1*rst*g[t+256]+bta[t+256];
  float dot=block_sum256(y0*w[t]+y1*w[t+256],s4);
  if(t==0) out[bb]=dot+fb[0];
}

// =======================================================================
extern "C" void kernel_launch(void* const* d_in, const int* in_sizes, int n_in,
                              void* d_out, int out_size, void* d_ws, size_t ws_size,
                              hipStream_t stream){
  (void)in_sizes; (void)n_in; (void)out_size; (void)ws_size;
  const float* features=(const float*)d_in[0];
  const float* fc1_w  =(const float*)d_in[1];
  const float* fc1_b  =(const float*)d_in[2];
  const float* cls_tok=(const float*)d_in[3];
  const float* fc2_w  =(const float*)d_in[24];
  const float* fc2_b  =(const float*)d_in[25];
  float* out=(float*)d_out;

  char* wp=(char*)d_ws;
  auto allocB=[&](size_t bytes)->char*{
    char* p=wp; wp+=((bytes+255)/256)*256; return p;
  };
  float* h    =(float*)allocB((size_t)NB*NTOK*DM*4);
  float* v    =(float*)allocB((size_t)NB*NPAD*DM*4);
  unsigned short* xlnb=(unsigned short*)allocB((size_t)NB*NPAD*DM*2);
  unsigned short* qb  =(unsigned short*)allocB((size_t)NB*NPAD*DM*2);
  unsigned short* kb  =(unsigned short*)allocB((size_t)NB*NPAD*DM*2);
  unsigned short* vtb =(unsigned short*)allocB((size_t)NB*NPAD*DM*2);
  float* aoh  =(float*)allocB((size_t)NB*NPAD*DM*4);
  unsigned short* featbf=(unsigned short*)aoh;   // overlay: featbf dead before aoh used
  unsigned short* wtf=(unsigned short*)allocB((size_t)512*1024*2);
  unsigned short* wtq=(unsigned short*)allocB((size_t)1536*512*2);
  unsigned short* wtp=(unsigned short*)allocB((size_t)512*512*2);
  float* ql =(float*)allocB((size_t)16*LM*HD*4);
  float* kl =(float*)allocB((size_t)16*LM*HD*4);
  unsigned short* qlb=(unsigned short*)allocB((size_t)16*LM*HD*2);
  unsigned short* klb=(unsigned short*)allocB((size_t)16*LM*HD*2);
  float* attn2=(float*)allocB((size_t)16*LM*LM*4);
  unsigned short* a2h=(unsigned short*)allocB((size_t)16*LM*LM*2);
  unsigned short* a2l=(unsigned short*)allocB((size_t)16*LM*LM*2);
  unsigned short* zb[8];
  for(int i=0;i<8;i++) zb[i]=(unsigned short*)allocB((size_t)16*LM*LM*2);
  unsigned short* Abh=(unsigned short*)allocB((size_t)16*LM*LM*2);
  unsigned short* Abl=(unsigned short*)allocB((size_t)16*LM*LM*2);
  unsigned short* Abth=(unsigned short*)allocB((size_t)16*LM*LM*2);
  unsigned short* Abtl=(unsigned short*)allocB((size_t)16*LM*LM*2);
  unsigned short* Ubth=(unsigned short*)allocB((size_t)16*LM*LM*2);
  unsigned short* Ubtl=(unsigned short*)allocB((size_t)16*LM*LM*2);
  unsigned short* Tbth=(unsigned short*)allocB((size_t)16*LM*LM*2);
  unsigned short* Tbtl=(unsigned short*)allocB((size_t)16*LM*LM*2);
  unsigned short* a3vth=(unsigned short*)allocB((size_t)16*HD*LM*2);
  unsigned short* a3vtl=(unsigned short*)allocB((size_t)16*HD*LM*2);
  unsigned short* w2t=(unsigned short*)allocB((size_t)16*HD*LM*2);
  float* pacc=(float*)allocB((size_t)16*16*LM*HD*4);
  float* pms =(float*)allocB((size_t)16*16*LM*2*4);
  float* rs  =(float*)allocB(4096*4);
  float* cs  =(float*)allocB(4096*4);
  float* scl =(float*)allocB(64*4);

  unsigned short* ao=xlnb;   // reuse: xln dead after qkv

  auto nystrom=[&](const float* ng, const float* nbias, const float* qkvw,
                   const float* outw, const float* outb, const float* resw){
    k_lnpad<<<NB*NPAD,256,0,stream>>>(h, ng, nbias, xlnb);
    k_wconv_t<<<(512*1536+255)/256,256,0,stream>>>(qkvw, wtq, 512, 1536);
    k_mfma_gemm<1><<<dim3(12,256),256,0,stream>>>(xlnb, wtq, 32768,1536,512,
                                                  nullptr, qb, kb, v);
    k_lmean<<<4096,64,0,stream>>>(qb, ql, qlb);
    k_lmean<<<4096,64,0,stream>>>(kb, kl, klb);
    k_vtrans<<<dim3(256,16),256,0,stream>>>(v, vtb);
    k_attn2<<<4096,256,0,stream>>>(ql, kl, attn2);
    k_split<<<4096,256,0,stream>>>(attn2, a2h, a2l, 16*65536);
    k_rowsum<<<4096,256,0,stream>>>(attn2, rs);
    k_colsum<<<16,256,0,stream>>>(attn2, cs);
    k_pinvscale<<<1,256,0,stream>>>(rs, cs, scl);
    k_zinit_hl<<<4096,256,0,stream>>>(attn2, scl, zb[0],zb[1],zb[2],zb[3]);
    unsigned short *zch=zb[0],*zcl=zb[1],*zcth=zb[2],*zctl=zb[3];
    unsigned short *znh=zb[4],*znl=zb[5],*znth=zb[6],*zntl=zb[7];
    for(int it=0;it<6;it++){
      k_bmm3<0><<<dim3(4,4,16),256,0,stream>>>(a2h,a2l, zcth,zctl, nullptr,nullptr,
                                               Abh,Abl, Abth,Abtl, 256);
      k_bmm3<1><<<dim3(4,4,16),256,0,stream>>>(Abh,Abl, Abth,Abtl, Abh,Abl,
                                               nullptr,nullptr, Ubth,Ubtl, 256);
      k_bmm3<2><<<dim3(4,4,16),256,0,stream>>>(Abh,Abl, Ubth,Ubtl, nullptr,nullptr,
                                               nullptr,nullptr, Tbth,Tbtl, 256);
      k_bmm3<3><<<dim3(4,4,16),256,0,stream>>>(zch,zcl, Tbth,Tbtl, nullptr,nullptr,
                                               znh,znl, znth,zntl, 256);
      unsigned short* tp;
      tp=zch; zch=znh; znh=tp;  tp=zcl; zcl=znl; znl=tp;
      tp=zcth; zcth=znth; znth=tp;  tp=zctl; zctl=zntl; zntl=tp;
    }
    k_attn3m<<<dim3(16,16),512,0,stream>>>(qlb, kb, vtb, pacc, pms);
    k_attn3vc<<<1024,256,0,stream>>>(pacc, pms, a3vth, a3vtl);
    k_bmm3<4><<<dim3(1,4,16),256,0,stream>>>(zch,zcl, a3vth,a3vtl, nullptr,nullptr,
                                             nullptr,nullptr, w2t,nullptr, 64);
    k_attn1m<<<dim3(64,16),512,0,stream>>>(qb, klb, w2t, aoh);
    k_resconv<<<65536,256,0,stream>>>(v, resw, aoh);
    k_headmerge<<<65536,256,0,stream>>>(aoh, ao);
    k_wconv_t<<<(512*512+255)/256,256,0,stream>>>(outw, wtp, 512, 512);
    k_mfma_gemm<2><<<dim3(4,256),256,0,stream>>>(ao, wtp, 32768,512,512,
                                                 outb, h, nullptr, nullptr);
  };

  // fc1 + relu + dup + cls (bf16 MFMA)
  k_f2bf4<<<32000,256,0,stream>>>(features, featbf, 32000*1024/4);
  k_wconv_t<<<(1024*512+255)/256,256,0,stream>>>(fc1_w, wtf, 1024, 512);
  k_mfma_gemm<0><<<dim3(4,250),256,0,stream>>>(featbf, wtf, 32000,512,1024,
                                               fc1_b, h, nullptr, nullptr);
  k_cls<<<4,256,0,stream>>>(cls_tok, h);

  // layer 1 attention
  nystrom((const float*)d_in[4],(const float*)d_in[5],(const float*)d_in[6],
          (const float*)d_in[7],(const float*)d_in[8],(const float*)d_in[9]);

  // PPEG (aoh free between layers; use as conv source copy)
  float* tmp=aoh;
  float* wcat=attn2;
  hipMemcpyAsync(tmp, h, (size_t)NB*NTOK*DM*4, hipMemcpyDeviceToDevice, stream);
  k_wprep<<<168,256,0,stream>>>(
      (const float*)d_in[10],(const float*)d_in[11],
      (const float*)d_in[12],(const float*)d_in[13],
      (const float*)d_in[14],(const float*)d_in[15], wcat);
  k_ppeg2<<<dim3(484,8,2),256,0,stream>>>(tmp, wcat, h);

  // layer 2 attention
  nystrom((const float*)d_in[16],(const float*)d_in[17],(const float*)d_in[18],
          (const float*)d_in[19],(const float*)d_in[20],(const float*)d_in[21]);

  // final LN(row0) @ fc2
  k_final<<<2,256,0,stream>>>(h,(const float*)d_in[22],(const float*)d_in[23],
                              fc2_w, fc2_b, out);
}

// Round 5
// 1673.092 us; speedup vs baseline: 11.1508x; 1.5292x over previous
//
#include <hip/hip_runtime.h>
#include <math.h>

#define NTOK 16130   // 1 + 127*127
#define NPAD 16384
#define PADF 254
#define NB   2
#define DM   512
#define NH   8
#define HD   64
#define LM   256
#define SEG  64

typedef __attribute__((ext_vector_type(8))) short short8v;
typedef __attribute__((ext_vector_type(4))) float f32x4;

// ---------------- helpers ----------------
__device__ __forceinline__ float wred_max(float v){
  #pragma unroll
  for(int o=32;o;o>>=1) v=fmaxf(v,__shfl_xor(v,o));
  return v;
}
__device__ __forceinline__ float wred_sum(float v){
  #pragma unroll
  for(int o=32;o;o>>=1) v+=__shfl_xor(v,o);
  return v;
}
__device__ __forceinline__ float block_max256(float v, float* s4){
  v=wred_max(v);
  if((threadIdx.x&63)==0) s4[threadIdx.x>>6]=v;
  __syncthreads();
  v=fmaxf(fmaxf(s4[0],s4[1]),fmaxf(s4[2],s4[3]));
  __syncthreads();
  return v;
}
__device__ __forceinline__ float block_sum256(float v, float* s4){
  v=wred_sum(v);
  if((threadIdx.x&63)==0) s4[threadIdx.x>>6]=v;
  __syncthreads();
  v=s4[0]+s4[1]+s4[2]+s4[3];
  __syncthreads();
  return v;
}
__device__ __forceinline__ unsigned short f2bf(float f){
  unsigned u=__float_as_uint(f);
  u = u + 0x7FFFu + ((u>>16)&1u);
  return (unsigned short)(u>>16);
}
__device__ __forceinline__ float bf2f(unsigned short u){
  return __uint_as_float(((unsigned)u)<<16);
}
__device__ __forceinline__ unsigned cvtpk(float a, float b){
  unsigned r;
  asm("v_cvt_pk_bf16_f32 %0, %1, %2" : "=v"(r) : "v"(a), "v"(b));
  return r;
}

// ---------------- conversions ----------------
// W[K][N] f32 -> Wt[N][K] bf16
__global__ void k_wconv_t(const float* __restrict__ W, unsigned short* __restrict__ Wt,
                          int K, int N){
  int idx=blockIdx.x*256+threadIdx.x; if(idx>=K*N) return;
  int k=idx/N, n=idx%N;
  Wt[(size_t)n*K+k]=f2bf(W[idx]);
}

// ---------------- MFMA bf16 GEMM: 128x128 tile, BK=32 ----------------
// ASRC 0: A bf16 row-major; ASRC 1: A f32 row-major (converted in staging)
template<int MODE, int ASRC>
__global__ __launch_bounds__(256) void k_mfma_gemm(
    const void* __restrict__ Ap, const unsigned short* __restrict__ Bt,
    int M, int N, int K,
    const float* __restrict__ bias,
    void* __restrict__ o0, void* __restrict__ o1, void* __restrict__ o2)
{
  __shared__ unsigned short As[128*32];
  __shared__ unsigned short Bs[128*32];
  int t=threadIdx.x;
  int row0=blockIdx.y*128, col0=blockIdx.x*128;
  int lane=t&63, w=t>>6, wr=w>>1, wc=w&1, lr=lane&15, kg=lane>>4;
  f32x4 acc[4][4];
  #pragma unroll
  for(int m=0;m<4;m++)
    #pragma unroll
    for(int n=0;n<4;n++) acc[m][n]=(f32x4){0.f,0.f,0.f,0.f};

  auto loadA=[&](int r,int kofs)->short8v{
    if constexpr(ASRC==0){
      return *(const short8v*)((const unsigned short*)Ap+(size_t)(row0+r)*K+kofs);
    } else {
      const float* Af=(const float*)Ap;
      float4 f0=*(const float4*)(Af+(size_t)(row0+r)*K+kofs);
      float4 f1=*(const float4*)(Af+(size_t)(row0+r)*K+kofs+4);
      union{unsigned u[4]; short8v v;} pk;
      pk.u[0]=cvtpk(f0.x,f0.y); pk.u[1]=cvtpk(f0.z,f0.w);
      pk.u[2]=cvtpk(f1.x,f1.y); pk.u[3]=cvtpk(f1.z,f1.w);
      return pk.v;
    }
  };

  short8v ra[2], rb[2];
  #pragma unroll
  for(int i=0;i<2;i++){
    int flat=i*256+t, r=flat>>2, k8=flat&3;
    ra[i]=loadA(r, k8*8);
    rb[i]=*(const short8v*)(Bt+(size_t)(col0+r)*K + k8*8);
  }
  int k0=0;
  for(;;){
    __syncthreads();
    #pragma unroll
    for(int i=0;i<2;i++){
      int flat=i*256+t;
      *(short8v*)(As+flat*8)=ra[i];
      *(short8v*)(Bs+flat*8)=rb[i];
    }
    __syncthreads();
    k0+=32;
    if(k0<K){
      #pragma unroll
      for(int i=0;i<2;i++){
        int flat=i*256+t, r=flat>>2, k8=flat&3;
        ra[i]=loadA(r, k0+k8*8);
        rb[i]=*(const short8v*)(Bt+(size_t)(col0+r)*K + k0 + k8*8);
      }
    }
    short8v af[4], bf[4];
    #pragma unroll
    for(int m=0;m<4;m++) af[m]=*(const short8v*)(As+(wr*64+m*16+lr)*32 + kg*8);
    #pragma unroll
    for(int n=0;n<4;n++) bf[n]=*(const short8v*)(Bs+(wc*64+n*16+lr)*32 + kg*8);
    #pragma unroll
    for(int m=0;m<4;m++)
      #pragma unroll
      for(int n=0;n<4;n++)
        acc[m][n]=__builtin_amdgcn_mfma_f32_16x16x32_bf16(af[m],bf[n],acc[m][n],0,0,0);
    if(k0>=K) break;
  }
  // epilogue
  #pragma unroll
  for(int m=0;m<4;m++){
    int rbase=row0 + wr*64 + m*16 + kg*4;
    #pragma unroll
    for(int j=0;j<4;j++){
      int r=rbase+j;
      #pragma unroll
      for(int n=0;n<4;n++){
        int c=col0 + wc*64 + n*16 + lr;
        float val=acc[m][n][j];
        if(MODE==0){
          float* h=(float*)o0;
          int bb=(r>=16000)?1:0, ii=r-bb*16000;
          float vv=fmaxf(val+bias[c],0.f);
          h[((size_t)bb*NTOK + 1 + ii)*DM + c]=vv;
          if(ii<129) h[((size_t)bb*NTOK + 16001 + ii)*DM + c]=vv;
        } else if(MODE==1){
          int bb=r>>14, rr=r&16383;
          int which=c>>9, hcol=c&511, head=hcol>>6, dd=hcol&63;
          size_t o=(((size_t)bb*NH+head)*NPAD + rr)*HD + dd;
          if(which==0)      ((unsigned short*)o0)[o]=f2bf(val*0.125f);
          else if(which==1) ((unsigned short*)o1)[o]=f2bf(val);
          else              ((float*)o2)[o]=val;
        } else {
          float* h=(float*)o0;
          int bb=r>>14, rr=r&16383;
          if(rr>=PADF)
            h[((size_t)bb*NTOK + (rr-PADF))*DM + c]+=val+bias[c];
        }
      }
    }
  }
}

__global__ void k_cls(const float* __restrict__ cls, float* __restrict__ h){
  int t=blockIdx.x*256+threadIdx.x;
  if(t<2*DM) h[(size_t)(t>>9)*NTOK*DM + (t&511)]=cls[t&511];
}

// ---------------- layernorm + front zero-pad -> bf16 ----------------
__global__ __launch_bounds__(256) void k_lnpad(
    const float* __restrict__ h, const float* __restrict__ g,
    const float* __restrict__ bta, unsigned short* __restrict__ xln)
{
  int r=blockIdx.x;
  int bb=r>>14, i=r&16383;
  int t=threadIdx.x;
  unsigned short* dst=xln+(size_t)r*DM;
  if(i<PADF){ dst[t]=0; dst[t+256]=0; return; }
  const float* src=h+((size_t)bb*NTOK + (i-PADF))*DM;
  float x0=src[t], x1=src[t+256];
  __shared__ float s4[4];
  float mu=block_sum256(x0+x1,s4)*(1.f/512.f);
  float d0=x0-mu, d1=x1-mu;
  float var=block_sum256(d0*d0+d1*d1,s4)*(1.f/512.f);
  float rst=rsqrtf(var+1e-5f);
  dst[t]    =f2bf(d0*rst*g[t]    +bta[t]);
  dst[t+256]=f2bf(d1*rst*g[t+256]+bta[t+256]);
}

// ---------------- landmark means (bf16 in, f32+bf16 out) ----------------
__global__ void k_lmean(const unsigned short* __restrict__ src, float* __restrict__ dstf,
                        unsigned short* __restrict__ dstb){
  int bh=blockIdx.x>>8, s=blockIdx.x&255, d=threadIdx.x;  // 64 threads
  const unsigned short* p=src + (((size_t)bh*NPAD)+s*SEG)*HD + d;
  float acc=0.f;
  #pragma unroll
  for(int l=0;l<SEG;l++) acc+=bf2f(p[(size_t)l*HD]);
  float m=acc*(1.f/64.f);
  dstf[((size_t)bh*LM+s)*HD+d]=m;
  dstb[((size_t)bh*LM+s)*HD+d]=f2bf(m);
}

// ---------------- v f32 head-major -> vt bf16 [bh][64][NPAD] ----------------
__global__ __launch_bounds__(256) void k_vtrans(
    const float* __restrict__ v, unsigned short* __restrict__ vt)
{
  __shared__ unsigned short tile[64][72];
  int kt=blockIdx.x, bh=blockIdx.y;
  int t=threadIdx.x;
  int r=t>>2, sgq=t&3;
  const float* src=v + ((size_t)bh*NPAD + kt*64 + r)*HD + sgq*16;
  #pragma unroll
  for(int i=0;i<16;i+=4){
    float4 f4=*(const float4*)(src+i);
    tile[r][sgq*16+i  ]=f2bf(f4.x);
    tile[r][sgq*16+i+1]=f2bf(f4.y);
    tile[r][sgq*16+i+2]=f2bf(f4.z);
    tile[r][sgq*16+i+3]=f2bf(f4.w);
  }
  __syncthreads();
  int d=t>>2;
  union{unsigned short u[16]; short8v v8[2];} pk;
  #pragma unroll
  for(int i=0;i<16;i++) pk.u[i]=tile[sgq*16+i][d];
  short8v* dst=(short8v*)(vt + ((size_t)bh*HD + d)*NPAD + kt*64 + sgq*16);
  dst[0]=pk.v8[0]; dst[1]=pk.v8[1];
}

// ---------------- attn2 = softmax(ql @ kl^T) f32 + fused hi/lo split --------
__global__ __launch_bounds__(256) void k_attn2(
    const float* __restrict__ ql, const float* __restrict__ kl,
    float* __restrict__ attn2,
    unsigned short* __restrict__ a2h, unsigned short* __restrict__ a2l)
{
  __shared__ float qrow[64]; __shared__ float s4[4];
  int bh=blockIdx.x>>8, i=blockIdx.x&255, j=threadIdx.x;
  if(j<64) qrow[j]=ql[((size_t)bh*LM+i)*HD+j];
  __syncthreads();
  const float* kp=kl+((size_t)bh*LM+j)*HD;
  float l=0.f;
  #pragma unroll
  for(int d=0;d<64;d++) l+=qrow[d]*kp[d];
  float m=block_max256(l,s4);
  float e=__expf(l-m);
  float s=block_sum256(e,s4);
  float pv=e/s;
  size_t o=((size_t)bh*LM+i)*LM+j;
  attn2[o]=pv;
  unsigned short hh=f2bf(pv);
  a2h[o]=hh; a2l[o]=f2bf(pv-bf2f(hh));
}

// ---------------- pinv helpers (rowsum of softmax == 1, skip it) ------------
__global__ void k_colsum(const float* __restrict__ x, float* __restrict__ cs){
  int bh=blockIdx.x, j=threadIdx.x;
  const float* p=x+(size_t)bh*65536;
  float s=0.f;
  for(int i=0;i<256;i++) s+=p[(size_t)i*256+j];
  cs[bh*256+j]=s;
}
__global__ void k_pinvscale(const float* __restrict__ cs, float* __restrict__ scale){
  __shared__ float s4[4];
  float mc=-1e30f;
  for(int i=threadIdx.x;i<4096;i+=256) mc=fmaxf(mc,cs[i]);
  mc=block_max256(mc,s4);
  if(threadIdx.x==0) scale[0]=1.f/mc;
}
__global__ void k_zinit_hl(const float* __restrict__ x, const float* __restrict__ scale,
    unsigned short* __restrict__ zh, unsigned short* __restrict__ zl,
    unsigned short* __restrict__ zth, unsigned short* __restrict__ ztl){
  int bh=blockIdx.x>>8, i=blockIdx.x&255, j=threadIdx.x;
  float s=scale[0];
  size_t base=(size_t)bh*65536;
  float vn=x[base+(size_t)j*256+i]*s;   // z0[i][j] = X^T * s
  float vt=x[base+(size_t)i*256+j]*s;   // z0^T[i][j]
  size_t o=base+(size_t)i*256+j;
  unsigned short h=f2bf(vn); zh[o]=h; zl[o]=f2bf(vn-bf2f(h));
  h=f2bf(vt); zth[o]=h; ztl[o]=f2bf(vt-bf2f(h));
}

// ---------------- hi/lo split bf16 MFMA batched GEMM (pinv chain) -----------
// MODE 0: C=A@B (emit normal+trans)    MODE 1: C=15I-7X+acc (trans only)
// MODE 2: C=13I-acc (trans only)       MODE 3: C=0.25*acc (normal+trans)
// MODE 4: C=acc (trans only, hi only; Ndim=64)
// PREC 0: single bf16 product; PREC 1: hi/lo 3-product (f32-equivalent)
template<int MODE, int PREC>
__global__ __launch_bounds__(256) void k_bmm3(
    const unsigned short* __restrict__ Ah, const unsigned short* __restrict__ Al,
    const unsigned short* __restrict__ Bth, const unsigned short* __restrict__ Btl,
    const unsigned short* __restrict__ Xh, const unsigned short* __restrict__ Xl,
    unsigned short* __restrict__ Cnh, unsigned short* __restrict__ Cnl,
    unsigned short* __restrict__ Cth, unsigned short* __restrict__ Ctl,
    int Ndim)
{
  __shared__ unsigned short AsH[64*40], BsH[64*40];
  __shared__ unsigned short AsL[PREC?64*40:8], BsL[PREC?64*40:8];
  int bh=blockIdx.z;
  int n0=blockIdx.x*64, m0=blockIdx.y*64;
  int t=threadIdx.x, lane=t&63, w=t>>6;
  int c=lane&15, g=lane>>4;
  int wr=(w>>1)*32, wc=(w&1)*32;
  f32x4 acc[2][2];
  #pragma unroll
  for(int i=0;i<2;i++)
    #pragma unroll
    for(int j=0;j<2;j++) acc[i][j]=(f32x4){0.f,0.f,0.f,0.f};
  size_t Abase=(size_t)bh*65536;
  size_t Bbase=(size_t)bh*(size_t)Ndim*256;
  int r=t>>2, sg=t&3;
  for(int k0=0;k0<256;k0+=32){
    __syncthreads();
    *(short8v*)(AsH+r*40+sg*8)=*(const short8v*)(Ah +Abase+(size_t)(m0+r)*256+k0+sg*8);
    *(short8v*)(BsH+r*40+sg*8)=*(const short8v*)(Bth+Bbase+(size_t)(n0+r)*256+k0+sg*8);
    if constexpr(PREC==1){
      *(short8v*)(AsL+r*40+sg*8)=*(const short8v*)(Al +Abase+(size_t)(m0+r)*256+k0+sg*8);
      *(short8v*)(BsL+r*40+sg*8)=*(const short8v*)(Btl+Bbase+(size_t)(n0+r)*256+k0+sg*8);
    }
    __syncthreads();
    short8v bhf[2], blf[2];
    #pragma unroll
    for(int nt=0;nt<2;nt++){
      bhf[nt]=*(const short8v*)(BsH+(wc+nt*16+c)*40+g*8);
      if constexpr(PREC==1) blf[nt]=*(const short8v*)(BsL+(wc+nt*16+c)*40+g*8);
    }
    #pragma unroll
    for(int mt=0;mt<2;mt++){
      short8v ahh=*(const short8v*)(AsH+(wr+mt*16+c)*40+g*8);
      short8v all;
      if constexpr(PREC==1) all=*(const short8v*)(AsL+(wr+mt*16+c)*40+g*8);
      #pragma unroll
      for(int nt=0;nt<2;nt++){
        acc[mt][nt]=__builtin_amdgcn_mfma_f32_16x16x32_bf16(ahh,bhf[nt],acc[mt][nt],0,0,0);
        if constexpr(PREC==1){
          acc[mt][nt]=__builtin_amdgcn_mfma_f32_16x16x32_bf16(ahh,blf[nt],acc[mt][nt],0,0,0);
          acc[mt][nt]=__builtin_amdgcn_mfma_f32_16x16x32_bf16(all,bhf[nt],acc[mt][nt],0,0,0);
        }
      }
    }
  }
  #pragma unroll
  for(int mt=0;mt<2;mt++)
    #pragma unroll
    for(int nt=0;nt<2;nt++){
      int rb=m0+wr+mt*16+g*4;
      int cc=n0+wc+nt*16+c;
      float vv[4];
      #pragma unroll
      for(int j=0;j<4;j++){
        float a=acc[mt][nt][j];
        int rr=rb+j;
        if(MODE==1){
          float xv=bf2f(Xh[Abase+(size_t)rr*256+cc])+bf2f(Xl[Abase+(size_t)rr*256+cc]);
          a=(rr==cc?15.f:0.f)-7.f*xv+a;
        } else if(MODE==2){
          a=(rr==cc?13.f:0.f)-a;
        } else if(MODE==3){
          a*=0.25f;
        }
        vv[j]=a;
      }
      if(MODE==0||MODE==3){
        #pragma unroll
        for(int j=0;j<4;j++){
          unsigned short h=f2bf(vv[j]);
          Cnh[Abase+(size_t)(rb+j)*256+cc]=h;
          Cnl[Abase+(size_t)(rb+j)*256+cc]=f2bf(vv[j]-bf2f(h));
        }
      }
      {
        ushort4 hv, lv;
        hv.x=f2bf(vv[0]); hv.y=f2bf(vv[1]); hv.z=f2bf(vv[2]); hv.w=f2bf(vv[3]);
        lv.x=f2bf(vv[0]-bf2f(hv.x)); lv.y=f2bf(vv[1]-bf2f(hv.y));
        lv.z=f2bf(vv[2]-bf2f(hv.z)); lv.w=f2bf(vv[3]-bf2f(hv.w));
        size_t co=((size_t)bh*Ndim+cc)*256+rb;
        *(ushort4*)(Cth+co)=hv;
        if(MODE!=4) *(ushort4*)(Ctl+co)=lv;
      }
    }
}

// ---------------- attn3@v : MFMA flash, split-K 16 chunks --------------------
__global__ __launch_bounds__(512) void k_attn3m(
    const unsigned short* __restrict__ qlb,
    const unsigned short* __restrict__ kb,
    const unsigned short* __restrict__ vtb,
    float* __restrict__ pacc, float* __restrict__ pms)
{
  __shared__ unsigned short Ks[64*72];
  __shared__ unsigned short Vs[64*72];
  int ck=blockIdx.x, bh=blockIdx.y;
  int t=threadIdx.x, lane=t&63, w=t>>6;
  int c=lane&15, g=lane>>4;
  short8v Qf[2][2];
  #pragma unroll
  for(int n=0;n<2;n++)
    #pragma unroll
    for(int kw=0;kw<2;kw++)
      Qf[n][kw]=*(const short8v*)(qlb + ((size_t)bh*LM + w*32 + n*16 + c)*HD + kw*32 + g*8);
  f32x4 accO[4][2];
  float mrun[2], srun[2];
  #pragma unroll
  for(int n=0;n<2;n++){
    mrun[n]=-3e38f; srun[n]=0.f;
    #pragma unroll
    for(int d=0;d<4;d++) accO[d][n]=(f32x4){0.f,0.f,0.f,0.f};
  }
  int sr=t>>3, sgk=t&7;
  for(int sc=0;sc<16;++sc){
    int key0=ck*1024 + sc*64;
    __syncthreads();
    *(short8v*)(Ks + sr*72 + sgk*8) =
      *(const short8v*)(kb + ((size_t)bh*NPAD + key0 + sr)*HD + sgk*8);
    *(short8v*)(Vs + sr*72 + sgk*8) =
      *(const short8v*)(vtb + ((size_t)bh*HD + sr)*NPAD + key0 + sgk*8);
    __syncthreads();
    f32x4 s[4][2];
    #pragma unroll
    for(int mt=0;mt<4;mt++){
      short8v a0=*(const short8v*)(Ks + (mt*16+c)*72 + g*8);
      short8v a1=*(const short8v*)(Ks + (mt*16+c)*72 + 32 + g*8);
      #pragma unroll
      for(int n=0;n<2;n++){
        f32x4 z=(f32x4){0.f,0.f,0.f,0.f};
        z=__builtin_amdgcn_mfma_f32_16x16x32_bf16(a0,Qf[n][0],z,0,0,0);
        z=__builtin_amdgcn_mfma_f32_16x16x32_bf16(a1,Qf[n][1],z,0,0,0);
        s[mt][n]=z;
      }
    }
    unsigned U[2][4][2];
    #pragma unroll
    for(int n=0;n<2;n++){
      float cm=-3e38f;
      #pragma unroll
      for(int mt=0;mt<4;mt++)
        #pragma unroll
        for(int j=0;j<4;j++) cm=fmaxf(cm,s[mt][n][j]);
      cm=fmaxf(cm,__shfl_xor(cm,16));
      cm=fmaxf(cm,__shfl_xor(cm,32));
      float mnew=fmaxf(mrun[n],cm);
      float f=__expf(mrun[n]-mnew);
      mrun[n]=mnew;
      float ps=0.f;
      #pragma unroll
      for(int mt=0;mt<4;mt++){
        float p0=__expf(s[mt][n][0]-mnew);
        float p1=__expf(s[mt][n][1]-mnew);
        float p2=__expf(s[mt][n][2]-mnew);
        float p3=__expf(s[mt][n][3]-mnew);
        ps+=p0+p1+p2+p3;
        U[n][mt][0]=cvtpk(p0,p1);
        U[n][mt][1]=cvtpk(p2,p3);
      }
      ps+=__shfl_xor(ps,16); ps+=__shfl_xor(ps,32);
      srun[n]=srun[n]*f+ps;
      #pragma unroll
      for(int d=0;d<4;d++){
        accO[d][n][0]*=f; accO[d][n][1]*=f; accO[d][n][2]*=f; accO[d][n][3]*=f;
      }
    }
    #pragma unroll
    for(int kw=0;kw<2;kw++){
      short8v pf[2];
      #pragma unroll
      for(int n=0;n<2;n++){
        union{unsigned u[4]; short8v v;} pk;
        #pragma unroll
        for(int wd=0;wd<4;wd++){
          int sl=c+16*(((g&1)<<1)+(wd>>1));
          unsigned va=(unsigned)__shfl((int)U[n][kw*2  ][wd&1],sl);
          unsigned vb=(unsigned)__shfl((int)U[n][kw*2+1][wd&1],sl);
          pk.u[wd]=(lane>=32)?vb:va;
        }
        pf[n]=pk.v;
      }
      #pragma unroll
      for(int d=0;d<4;d++){
        short8v vf=*(const short8v*)(Vs + (d*16+c)*72 + kw*32 + g*8);
        accO[d][0]=__builtin_amdgcn_mfma_f32_16x16x32_bf16(vf,pf[0],accO[d][0],0,0,0);
        accO[d][1]=__builtin_amdgcn_mfma_f32_16x16x32_bf16(vf,pf[1],accO[d][1],0,0,0);
      }
    }
  }
  size_t pb=((size_t)bh*16+ck)*LM;
  #pragma unroll
  for(int n=0;n<2;n++){
    int q=w*32+n*16+c;
    #pragma unroll
    for(int d=0;d<4;d++)
      *(f32x4*)(pacc + (pb+q)*HD + d*16 + g*4)=accO[d][n];
    if(g==0){ pms[(pb+q)*2]=mrun[n]; pms[(pb+q)*2+1]=srun[n]; }
  }
}
__global__ __launch_bounds__(256) void k_attn3vc(
    const float* __restrict__ pacc, const float* __restrict__ pms,
    unsigned short* __restrict__ a3vth, unsigned short* __restrict__ a3vtl)
{
  int gid=blockIdx.x*4+(threadIdx.x>>6);
  int bh=gid>>8, row=gid&255, lane=threadIdx.x&63;
  float M=-3e38f;
  float ms[16], ss[16];
  #pragma unroll
  for(int c=0;c<16;c++){
    size_t pb=((size_t)bh*16+c)*LM+row;
    ms[c]=pms[pb*2]; ss[c]=pms[pb*2+1];
    M=fmaxf(M,ms[c]);
  }
  float S=0.f,a=0.f;
  #pragma unroll
  for(int c=0;c<16;c++){
    float f=__expf(ms[c]-M);
    S+=ss[c]*f;
    a+=pacc[(((size_t)bh*16+c)*LM+row)*HD+lane]*f;
  }
  float v=a/S;
  unsigned short hi=f2bf(v);
  a3vth[((size_t)bh*HD+lane)*LM+row]=hi;
  a3vtl[((size_t)bh*HD+lane)*LM+row]=f2bf(v-bf2f(hi));
}

// ---------------- attn1 @ W2 : MFMA, 256 landmarks one-shot ------------------
__global__ __launch_bounds__(512) void k_attn1m(
    const unsigned short* __restrict__ qb,
    const unsigned short* __restrict__ klb,
    const unsigned short* __restrict__ w2t,
    float* __restrict__ aoh)
{
  __shared__ unsigned short klS[256*72];
  __shared__ unsigned short w2S[64*264];
  int qt=blockIdx.x, bh=blockIdx.y;
  int t=threadIdx.x, lane=t&63, w=t>>6;
  int c=lane&15, g=lane>>4;
  {
    int r=t>>1, hf=t&1;
    const short8v* s=(const short8v*)(klb + ((size_t)bh*LM+r)*HD + hf*32);
    short8v* d=(short8v*)(klS + r*72 + hf*32);
    d[0]=s[0]; d[1]=s[1]; d[2]=s[2]; d[3]=s[3];
    int r2=t>>3, sg2=t&7;
    const short8v* s2=(const short8v*)(w2t + ((size_t)bh*HD+r2)*LM + sg2*32);
    short8v* d2=(short8v*)(w2S + r2*264 + sg2*32);
    d2[0]=s2[0]; d2[1]=s2[1]; d2[2]=s2[2]; d2[3]=s2[3];
  }
  __syncthreads();
  int q0=qt*256 + w*32;
  #pragma unroll
  for(int n=0;n<2;n++){
    const unsigned short* qrow=qb + ((size_t)bh*NPAD + q0 + n*16 + c)*HD;
    short8v qf0=*(const short8v*)(qrow + g*8);
    short8v qf1=*(const short8v*)(qrow + 32 + g*8);
    f32x4 s[16];
    #pragma unroll
    for(int mt=0;mt<16;mt++){
      short8v a0=*(const short8v*)(klS + (mt*16+c)*72 + g*8);
      short8v a1=*(const short8v*)(klS + (mt*16+c)*72 + 32 + g*8);
      f32x4 z=(f32x4){0.f,0.f,0.f,0.f};
      z=__builtin_amdgcn_mfma_f32_16x16x32_bf16(a0,qf0,z,0,0,0);
      z=__builtin_amdgcn_mfma_f32_16x16x32_bf16(a1,qf1,z,0,0,0);
      s[mt]=z;
    }
    float M=-3e38f;
    #pragma unroll
    for(int mt=0;mt<16;mt++)
      #pragma unroll
      for(int j=0;j<4;j++) M=fmaxf(M,s[mt][j]);
    M=fmaxf(M,__shfl_xor(M,16));
    M=fmaxf(M,__shfl_xor(M,32));
    float sum=0.f;
    unsigned U[16][2];
    #pragma unroll
    for(int mt=0;mt<16;mt++){
      float p0=__expf(s[mt][0]-M);
      float p1=__expf(s[mt][1]-M);
      float p2=__expf(s[mt][2]-M);
      float p3=__expf(s[mt][3]-M);
      sum+=p0+p1+p2+p3;
      U[mt][0]=cvtpk(p0,p1);
      U[mt][1]=cvtpk(p2,p3);
    }
    sum+=__shfl_xor(sum,16); sum+=__shfl_xor(sum,32);
    float inv=1.f/sum;
    f32x4 accO[4];
    #pragma unroll
    for(int d=0;d<4;d++) accO[d]=(f32x4){0.f,0.f,0.f,0.f};
    #pragma unroll
    for(int kw=0;kw<8;kw++){
      union{unsigned u[4]; short8v v;} pk;
      #pragma unroll
      for(int wd=0;wd<4;wd++){
        int sl=c+16*(((g&1)<<1)+(wd>>1));
        unsigned va=(unsigned)__shfl((int)U[kw*2  ][wd&1],sl);
        unsigned vb=(unsigned)__shfl((int)U[kw*2+1][wd&1],sl);
        pk.u[wd]=(lane>=32)?vb:va;
      }
      #pragma unroll
      for(int d=0;d<4;d++){
        short8v vf=*(const short8v*)(w2S + (d*16+c)*264 + kw*32 + g*8);
        accO[d]=__builtin_amdgcn_mfma_f32_16x16x32_bf16(vf,pk.v,accO[d],0,0,0);
      }
    }
    int q=q0+n*16+c;
    #pragma unroll
    for(int d=0;d<4;d++){
      f32x4 o=accO[d];
      o[0]*=inv; o[1]*=inv; o[2]*=inv; o[3]*=inv;
      *(f32x4*)(aoh + ((size_t)bh*NPAD+q)*HD + d*16 + g*4)=o;
    }
  }
}

// ---------------- depthwise 33-tap conv on v, += into aoh (4 pos/thread) ----
__global__ void k_resconv(const float* __restrict__ vv, const float* __restrict__ rw,
                          float* __restrict__ aoh){
  size_t idx=(size_t)blockIdx.x*256+threadIdx.x;  // 2*8*4096*64
  int d=(int)(idx&63); size_t r=idx>>6;
  int i4=(int)(r&4095)*4; int bh=(int)(r>>12); int hh=bh&7;
  const float* vb=vv+((size_t)bh*NPAD)*HD+d;
  float wv[36];
  #pragma unroll
  for(int t2=0;t2<36;t2++){
    int src=i4-16+t2;
    wv[t2]=(src>=0&&src<NPAD)?vb[(size_t)src*HD]:0.f;
  }
  const float* wt=rw+hh*33;
  #pragma unroll
  for(int p=0;p<4;p++){
    float a=0.f;
    #pragma unroll
    for(int tk=0;tk<33;tk++) a+=wv[p+tk]*wt[tk];
    aoh[((size_t)bh*NPAD+i4+p)*HD+d]+=a;
  }
}

// ---------------- head-major -> row-major merge -> bf16 ----------------
__global__ void k_headmerge(const float* __restrict__ aoh, unsigned short* __restrict__ ao){
  size_t idx=(size_t)blockIdx.x*256+threadIdx.x;
  int c=idx&511; size_t r=idx>>9; int i=r&16383; int bb=(int)(r>>14);
  int hh=c>>6, dd=c&63;
  ao[idx]=f2bf(aoh[(((size_t)bb*NH+hh)*NPAD+i)*HD+dd]);
}

// ---------------- PPEG weight prep: combined 7x7 tap table (bf16) -----------
__global__ void k_wprep(const float* __restrict__ w7, const float* __restrict__ b7,
                        const float* __restrict__ w5, const float* __restrict__ b5,
                        const float* __restrict__ w3, const float* __restrict__ b3,
                        unsigned short* __restrict__ wcat){
  int t=blockIdx.x*256+threadIdx.x;
  if(t>=50*512) return;
  int r=t>>9, c=t&511;
  float v;
  if(r<49){
    int ky=r/7, kx=r%7;
    v=w7[(size_t)c*49+r];
    if(ky>=1&&ky<=5&&kx>=1&&kx<=5) v+=w5[(size_t)c*25+(ky-1)*5+(kx-1)];
    if(ky>=2&&ky<=4&&kx>=2&&kx<=4) v+=w3[(size_t)c*9+(ky-2)*3+(kx-2)];
  } else {
    v=b7[c]+b5[c]+b3[c];
  }
  wcat[t]=f2bf(v);
}

// ---------------- PPEG: LDS-tiled 6x6x64ch combined 7x7 stencil -------------
// reads h (f32), writes dst; identity term read in f32 (exact pass-through)
__global__ __launch_bounds__(256,4) void k_ppeg3(
    const float* __restrict__ src, const unsigned short* __restrict__ wcat,
    float* __restrict__ dst)
{
  __shared__ unsigned short patch[144][64];
  __shared__ unsigned short ws[50][64];
  int gx=blockIdx.x%22, gy=blockIdx.x/22;
  int cz=blockIdx.y, bb=blockIdx.z;
  int t=threadIdx.x, c=t&63, g=t>>6;
  int ty0=gy*6, tx0=gx*6;
  const float* base=src+((size_t)bb*NTOK+1)*DM + cz*64 + c;
  #pragma unroll
  for(int i=0;i<36;i++){
    int p=g+4*i;
    int py=p/12, px=p%12;
    int yy=ty0-3+py, xx=tx0-3+px;
    float v=0.f;
    if(yy>=0&&yy<127&&xx>=0&&xx<127) v=base[(size_t)(yy*127+xx)*DM];
    patch[p][c]=f2bf(v);
  }
  #pragma unroll
  for(int i=0;i<13;i++){
    int r=g+4*i; if(r<50) ws[r][c]=wcat[(size_t)r*DM + cz*64 + c];
  }
  __syncthreads();
  float acc[9];
  int oy[9], ox[9];
  float bias=bf2f(ws[49][c]);
  #pragma unroll
  for(int i=0;i<9;i++){
    int p=g*9+i; oy[i]=p/6; ox[i]=p%6;
    int y=ty0+oy[i], x=tx0+ox[i];
    float ident=0.f;
    if(y<127&&x<127) ident=base[(size_t)(y*127+x)*DM];
    acc[i]=ident+bias;
  }
  for(int ky=0;ky<7;ky++)
    for(int kx=0;kx<7;kx++){
      float wv=bf2f(ws[ky*7+kx][c]);
      #pragma unroll
      for(int i=0;i<9;i++)
        acc[i]+=bf2f(patch[(oy[i]+ky)*12+ox[i]+kx][c])*wv;
    }
  #pragma unroll
  for(int i=0;i<9;i++){
    int y=ty0+oy[i], x=tx0+ox[i];
    if(y<127&&x<127)
      dst[((size_t)bb*NTOK+1+(size_t)(y*127+x))*DM + cz*64 + c]=acc[i];
  }
}

// copy cls row h -> dst (so full-buffer copy-back is valid)
__global__ void k_cpcls(const float* __restrict__ h, float* __restrict__ dst){
  int t=blockIdx.x*256+threadIdx.x;
  if(t<2*DM) dst[(size_t)(t>>9)*NTOK*DM + (t&511)]=h[(size_t)(t>>9)*NTOK*DM + (t&511)];
}

// ---------------- final: LN(h[:,0]) @ fc2 + b ----------------
__global__ __launch_bounds__(256) void k_final(
    const float* __restrict__ h, const float* __restrict__ g, const float* __restrict__ bta,
    const float* __restrict__ w, const float* __restrict__ fb, float* __restrict__ out)
{
  int bb=blockIdx.x, t=threadIdx.x;
  const float* src=h+(size_t)bb*NTOK*DM;
  float x0=src[t], x1=src[t+256];
  __shared__ float s4[4];
  float mu=block_sum256(x0+x1,s4)*(1.f/512.f);
  float d0=x0-mu, d1=x1-mu;
  float var=block_sum256(d0*d0+d1*d1,s4)*(1.f/512.f);
  float rst=rsqrtf(var+1e-5f);
  float y0=d0*rst*g[t]+bta[t], y1=d1*rst*g[t+256]+bta[t+256];
  float dot=block_sum256(y0*w[t]+y1*w[t+256],s4);
  if(t==0) out[bb]=dot+fb[0];
}

// =======================================================================
extern "C" void kernel_launch(void* const* d_in, const int* in_sizes, int n_in,
                              void* d_out, int out_size, void* d_ws, size_t ws_size,
                              hipStream_t stream){
  (void)in_sizes; (void)n_in; (void)out_size; (void)ws_size;
  const float* features=(const float*)d_in[0];
  const float* fc1_w  =(const float*)d_in[1];
  const float* fc1_b  =(const float*)d_in[2];
  const float* cls_tok=(const float*)d_in[3];
  const float* fc2_w  =(const float*)d_in[24];
  const float* fc2_b  =(const float*)d_in[25];
  float* out=(float*)d_out;

  char* wp=(char*)d_ws;
  auto allocB=[&](size_t bytes)->char*{
    char* p=wp; wp+=((bytes+255)/256)*256; return p;
  };
  float* h    =(float*)allocB((size_t)NB*NTOK*DM*4);
  float* v    =(float*)allocB((size_t)NB*NPAD*DM*4);
  unsigned short* xlnb=(unsigned short*)allocB((size_t)NB*NPAD*DM*2);
  unsigned short* qb  =(unsigned short*)allocB((size_t)NB*NPAD*DM*2);
  unsigned short* kb  =(unsigned short*)allocB((size_t)NB*NPAD*DM*2);
  unsigned short* vtb =(unsigned short*)allocB((size_t)NB*NPAD*DM*2);
  float* aoh  =(float*)allocB((size_t)NB*NPAD*DM*4);
  unsigned short* wtf=(unsigned short*)allocB((size_t)512*1024*2);
  unsigned short* wtq=(unsigned short*)allocB((size_t)1536*512*2);
  unsigned short* wtp=(unsigned short*)allocB((size_t)512*512*2);
  float* ql =(float*)allocB((size_t)16*LM*HD*4);
  float* kl =(float*)allocB((size_t)16*LM*HD*4);
  unsigned short* qlb=(unsigned short*)allocB((size_t)16*LM*HD*2);
  unsigned short* klb=(unsigned short*)allocB((size_t)16*LM*HD*2);
  float* attn2=(float*)allocB((size_t)16*LM*LM*4);
  unsigned short* a2h=(unsigned short*)allocB((size_t)16*LM*LM*2);
  unsigned short* a2l=(unsigned short*)allocB((size_t)16*LM*LM*2);
  unsigned short* zb[8];
  for(int i=0;i<8;i++) zb[i]=(unsigned short*)allocB((size_t)16*LM*LM*2);
  unsigned short* Abh=(unsigned short*)allocB((size_t)16*LM*LM*2);
  unsigned short* Abl=(unsigned short*)allocB((size_t)16*LM*LM*2);
  unsigned short* Abth=(unsigned short*)allocB((size_t)16*LM*LM*2);
  unsigned short* Abtl=(unsigned short*)allocB((size_t)16*LM*LM*2);
  unsigned short* Ubth=(unsigned short*)allocB((size_t)16*LM*LM*2);
  unsigned short* Ubtl=(unsigned short*)allocB((size_t)16*LM*LM*2);
  unsigned short* Tbth=(unsigned short*)allocB((size_t)16*LM*LM*2);
  unsigned short* Tbtl=(unsigned short*)allocB((size_t)16*LM*LM*2);
  unsigned short* a3vth=(unsigned short*)allocB((size_t)16*HD*LM*2);
  unsigned short* a3vtl=(unsigned short*)allocB((size_t)16*HD*LM*2);
  unsigned short* w2t=(unsigned short*)allocB((size_t)16*HD*LM*2);
  float* pacc=(float*)allocB((size_t)16*16*LM*HD*4);
  float* pms =(float*)allocB((size_t)16*16*LM*2*4);
  float* cs  =(float*)allocB(4096*4);
  float* scl =(float*)allocB(64*4);

  unsigned short* ao=xlnb;   // reuse: xln dead after qkv

  auto nystrom=[&](const float* ng, const float* nbias, const float* qkvw,
                   const float* outw, const float* outb, const float* resw){
    k_lnpad<<<NB*NPAD,256,0,stream>>>(h, ng, nbias, xlnb);
    k_wconv_t<<<(512*1536+255)/256,256,0,stream>>>(qkvw, wtq, 512, 1536);
    k_mfma_gemm<1,0><<<dim3(12,256),256,0,stream>>>(xlnb, wtq, 32768,1536,512,
                                                    nullptr, qb, kb, v);
    k_lmean<<<4096,64,0,stream>>>(qb, ql, qlb);
    k_lmean<<<4096,64,0,stream>>>(kb, kl, klb);
    k_vtrans<<<dim3(256,16),256,0,stream>>>(v, vtb);
    k_attn2<<<4096,256,0,stream>>>(ql, kl, attn2, a2h, a2l);
    k_colsum<<<16,256,0,stream>>>(attn2, cs);
    k_pinvscale<<<1,256,0,stream>>>(cs, scl);
    k_zinit_hl<<<4096,256,0,stream>>>(attn2, scl, zb[0],zb[1],zb[2],zb[3]);
    unsigned short *zch=zb[0],*zcl=zb[1],*zcth=zb[2],*zctl=zb[3];
    unsigned short *znh=zb[4],*znl=zb[5],*znth=zb[6],*zntl=zb[7];
    for(int it=0;it<6;it++){
      if(it<4){
        k_bmm3<0,0><<<dim3(4,4,16),256,0,stream>>>(a2h,a2l, zcth,zctl, nullptr,nullptr,
                                                   Abh,Abl, Abth,Abtl, 256);
        k_bmm3<1,0><<<dim3(4,4,16),256,0,stream>>>(Abh,Abl, Abth,Abtl, Abh,Abl,
                                                   nullptr,nullptr, Ubth,Ubtl, 256);
        k_bmm3<2,0><<<dim3(4,4,16),256,0,stream>>>(Abh,Abl, Ubth,Ubtl, nullptr,nullptr,
                                                   nullptr,nullptr, Tbth,Tbtl, 256);
        k_bmm3<3,0><<<dim3(4,4,16),256,0,stream>>>(zch,zcl, Tbth,Tbtl, nullptr,nullptr,
                                                   znh,znl, znth,zntl, 256);
      } else {
        k_bmm3<0,1><<<dim3(4,4,16),256,0,stream>>>(a2h,a2l, zcth,zctl, nullptr,nullptr,
                                                   Abh,Abl, Abth,Abtl, 256);
        k_bmm3<1,1><<<dim3(4,4,16),256,0,stream>>>(Abh,Abl, Abth,Abtl, Abh,Abl,
                                                   nullptr,nullptr, Ubth,Ubtl, 256);
        k_bmm3<2,1><<<dim3(4,4,16),256,0,stream>>>(Abh,Abl, Ubth,Ubtl, nullptr,nullptr,
                                                   nullptr,nullptr, Tbth,Tbtl, 256);
        k_bmm3<3,1><<<dim3(4,4,16),256,0,stream>>>(zch,zcl, Tbth,Tbtl, nullptr,nullptr,
                                                   znh,znl, znth,zntl, 256);
      }
      unsigned short* tp;
      tp=zch; zch=znh; znh=tp;  tp=zcl; zcl=znl; znl=tp;
      tp=zcth; zcth=znth; znth=tp;  tp=zctl; zctl=zntl; zntl=tp;
    }
    k_attn3m<<<dim3(16,16),512,0,stream>>>(qlb, kb, vtb, pacc, pms);
    k_attn3vc<<<1024,256,0,stream>>>(pacc, pms, a3vth, a3vtl);
    k_bmm3<4,1><<<dim3(1,4,16),256,0,stream>>>(zch,zcl, a3vth,a3vtl, nullptr,nullptr,
                                               nullptr,nullptr, w2t,nullptr, 64);
    k_attn1m<<<dim3(64,16),512,0,stream>>>(qb, klb, w2t, aoh);
    k_resconv<<<16384,256,0,stream>>>(v, resw, aoh);
    k_headmerge<<<65536,256,0,stream>>>(aoh, ao);
    k_wconv_t<<<(512*512+255)/256,256,0,stream>>>(outw, wtp, 512, 512);
    k_mfma_gemm<2,0><<<dim3(4,256),256,0,stream>>>(ao, wtp, 32768,512,512,
                                                   outb, h, nullptr, nullptr);
  };

  // fc1 + relu + dup + cls (bf16 MFMA, fused f32->bf16 A staging)
  k_wconv_t<<<(1024*512+255)/256,256,0,stream>>>(fc1_w, wtf, 1024, 512);
  k_mfma_gemm<0,1><<<dim3(4,250),256,0,stream>>>(features, wtf, 32000,512,1024,
                                                 fc1_b, h, nullptr, nullptr);
  k_cls<<<4,256,0,stream>>>(cls_tok, h);

  // layer 1 attention
  nystrom((const float*)d_in[4],(const float*)d_in[5],(const float*)d_in[6],
          (const float*)d_in[7],(const float*)d_in[8],(const float*)d_in[9]);

  // PPEG: combined-tap stencil h -> aoh, then copy back into h
  {
    unsigned short* wcat=(unsigned short*)attn2;  // free at this point
    k_wprep<<<100,256,0,stream>>>(
        (const float*)d_in[10],(const float*)d_in[11],
        (const float*)d_in[12],(const float*)d_in[13],
        (const float*)d_in[14],(const float*)d_in[15], wcat);
    k_cpcls<<<4,256,0,stream>>>(h, aoh);
    k_ppeg3<<<dim3(484,8,2),256,0,stream>>>(h, wcat, aoh);
    hipMemcpyAsync(h, aoh, (size_t)NB*NTOK*DM*4, hipMemcpyDeviceToDevice, stream);
  }

  // layer 2 attention
  nystrom((const float*)d_in[16],(const float*)d_in[17],(const float*)d_in[18],
          (const float*)d_in[19],(const float*)d_in[20],(const float*)d_in[21]);

  // final LN(row0) @ fc2
  k_final<<<2,256,0,stream>>>(h,(const float*)d_in[22],(const float*)d_in[23],
                              fc2_w, fc2_b, out);
}

// Round 7
// 1632.232 us; speedup vs baseline: 11.4299x; 1.0250x over previous
//
#include <hip/hip_runtime.h>
#include <math.h>

#define NTOK 16130   // 1 + 127*127
#define NPAD 16384
#define PADF 254
#define NB   2
#define DM   512
#define NH   8
#define HD   64
#define LM   256
#define SEG  64

typedef __attribute__((ext_vector_type(8))) short short8v;
typedef __attribute__((ext_vector_type(4))) float f32x4;

// ---------------- helpers ----------------
__device__ __forceinline__ float wred_max(float v){
  #pragma unroll
  for(int o=32;o;o>>=1) v=fmaxf(v,__shfl_xor(v,o));
  return v;
}
__device__ __forceinline__ float wred_sum(float v){
  #pragma unroll
  for(int o=32;o;o>>=1) v+=__shfl_xor(v,o);
  return v;
}
__device__ __forceinline__ float block_max256(float v, float* s4){
  v=wred_max(v);
  if((threadIdx.x&63)==0) s4[threadIdx.x>>6]=v;
  __syncthreads();
  v=fmaxf(fmaxf(s4[0],s4[1]),fmaxf(s4[2],s4[3]));
  __syncthreads();
  return v;
}
__device__ __forceinline__ float block_sum256(float v, float* s4){
  v=wred_sum(v);
  if((threadIdx.x&63)==0) s4[threadIdx.x>>6]=v;
  __syncthreads();
  v=s4[0]+s4[1]+s4[2]+s4[3];
  __syncthreads();
  return v;
}
__device__ __forceinline__ unsigned short f2bf(float f){
  unsigned u=__float_as_uint(f);
  u = u + 0x7FFFu + ((u>>16)&1u);
  return (unsigned short)(u>>16);
}
__device__ __forceinline__ float bf2f(unsigned short u){
  return __uint_as_float(((unsigned)u)<<16);
}
__device__ __forceinline__ unsigned cvtpk(float a, float b){
  unsigned r;
  asm("v_cvt_pk_bf16_f32 %0, %1, %2" : "=v"(r) : "v"(a), "v"(b));
  return r;
}

// ---------------- conversions ----------------
// W[K][N] f32 -> Wt[N][K] bf16
__global__ void k_wconv_t(const float* __restrict__ W, unsigned short* __restrict__ Wt,
                          int K, int N){
  int idx=blockIdx.x*256+threadIdx.x; if(idx>=K*N) return;
  int k=idx/N, n=idx%N;
  Wt[(size_t)n*K+k]=f2bf(W[idx]);
}

// ---------------- MFMA bf16 GEMM: 128x128 tile, BK=32, XCD swizzle -----------
// ASRC 0: A bf16 row-major; ASRC 1: A f32 row-major (cvt in staging)
// ASRC 2: A f32 head-major [bb][8][NPAD][64] (cvt + headmerge in staging)
template<int MODE, int ASRC>
__global__ __launch_bounds__(256) void k_mfma_gemm(
    const void* __restrict__ Ap, const unsigned short* __restrict__ Bt,
    int M, int N, int K,
    const float* __restrict__ bias,
    void* __restrict__ o0, void* __restrict__ o1, void* __restrict__ o2)
{
  __shared__ unsigned short As[128*32];
  __shared__ unsigned short Bs[128*32];
  int t=threadIdx.x;
  int bx=blockIdx.x, by=blockIdx.y;
  { // bijective XCD swizzle (grid size divisible by 8)
    int gx=gridDim.x; int wg=by*gx+bx; int nwg=gx*gridDim.y;
    int cpx=nwg>>3; int x2=(wg&7)*cpx+(wg>>3);
    by=x2/gx; bx=x2-by*gx;
  }
  int row0=by*128, col0=bx*128;
  int lane=t&63, w=t>>6, wr=w>>1, wc=w&1, lr=lane&15, kg=lane>>4;
  f32x4 acc[4][4];
  #pragma unroll
  for(int m=0;m<4;m++)
    #pragma unroll
    for(int n=0;n<4;n++) acc[m][n]=(f32x4){0.f,0.f,0.f,0.f};

  auto loadA=[&](int r,int kofs)->short8v{
    if constexpr(ASRC==0){
      return *(const short8v*)((const unsigned short*)Ap+(size_t)(row0+r)*K+kofs);
    } else if constexpr(ASRC==1){
      const float* Af=(const float*)Ap;
      float4 f0=*(const float4*)(Af+(size_t)(row0+r)*K+kofs);
      float4 f1=*(const float4*)(Af+(size_t)(row0+r)*K+kofs+4);
      union{unsigned u[4]; short8v v;} pk;
      pk.u[0]=cvtpk(f0.x,f0.y); pk.u[1]=cvtpk(f0.z,f0.w);
      pk.u[2]=cvtpk(f1.x,f1.y); pk.u[3]=cvtpk(f1.z,f1.w);
      return pk.v;
    } else {
      const float* Af=(const float*)Ap;
      int rr2=row0+r; int bb=rr2>>14, ri=rr2&16383;
      int head=kofs>>6, dd=kofs&63;
      const float* p=Af + (((size_t)bb*NH+head)*NPAD+ri)*HD + dd;
      float4 f0=*(const float4*)p;
      float4 f1=*(const float4*)(p+4);
      union{unsigned u[4]; short8v v;} pk;
      pk.u[0]=cvtpk(f0.x,f0.y); pk.u[1]=cvtpk(f0.z,f0.w);
      pk.u[2]=cvtpk(f1.x,f1.y); pk.u[3]=cvtpk(f1.z,f1.w);
      return pk.v;
    }
  };

  short8v ra[2], rb[2];
  #pragma unroll
  for(int i=0;i<2;i++){
    int flat=i*256+t, r=flat>>2, k8=flat&3;
    ra[i]=loadA(r, k8*8);
    rb[i]=*(const short8v*)(Bt+(size_t)(col0+r)*K + k8*8);
  }
  int k0=0;
  for(;;){
    __syncthreads();
    #pragma unroll
    for(int i=0;i<2;i++){
      int flat=i*256+t;
      *(short8v*)(As+flat*8)=ra[i];
      *(short8v*)(Bs+flat*8)=rb[i];
    }
    __syncthreads();
    k0+=32;
    if(k0<K){
      #pragma unroll
      for(int i=0;i<2;i++){
        int flat=i*256+t, r=flat>>2, k8=flat&3;
        ra[i]=loadA(r, k0+k8*8);
        rb[i]=*(const short8v*)(Bt+(size_t)(col0+r)*K + k0 + k8*8);
      }
    }
    short8v af[4], bf[4];
    #pragma unroll
    for(int m=0;m<4;m++) af[m]=*(const short8v*)(As+(wr*64+m*16+lr)*32 + kg*8);
    #pragma unroll
    for(int n=0;n<4;n++) bf[n]=*(const short8v*)(Bs+(wc*64+n*16+lr)*32 + kg*8);
    #pragma unroll
    for(int m=0;m<4;m++)
      #pragma unroll
      for(int n=0;n<4;n++)
        acc[m][n]=__builtin_amdgcn_mfma_f32_16x16x32_bf16(af[m],bf[n],acc[m][n],0,0,0);
    if(k0>=K) break;
  }
  // epilogue
  #pragma unroll
  for(int m=0;m<4;m++){
    int rbase=row0 + wr*64 + m*16 + kg*4;
    #pragma unroll
    for(int j=0;j<4;j++){
      int r=rbase+j;
      #pragma unroll
      for(int n=0;n<4;n++){
        int c=col0 + wc*64 + n*16 + lr;
        float val=acc[m][n][j];
        if(MODE==0){
          float* h=(float*)o0;
          int bb=(r>=16000)?1:0, ii=r-bb*16000;
          float vv=fmaxf(val+bias[c],0.f);
          h[((size_t)bb*NTOK + 1 + ii)*DM + c]=vv;
          if(ii<129) h[((size_t)bb*NTOK + 16001 + ii)*DM + c]=vv;
        } else if(MODE==1){
          int bb=r>>14, rr=r&16383;
          int which=c>>9, hcol=c&511, head=hcol>>6, dd=hcol&63;
          size_t o=(((size_t)bb*NH+head)*NPAD + rr)*HD + dd;
          if(which==0)      ((unsigned short*)o0)[o]=f2bf(val*0.125f);
          else if(which==1) ((unsigned short*)o1)[o]=f2bf(val);
          else              ((float*)o2)[o]=val;
        } else {
          float* h=(float*)o0;
          int bb=r>>14, rr=r&16383;
          if(rr>=PADF)
            h[((size_t)bb*NTOK + (rr-PADF))*DM + c]+=val+bias[c];
        }
      }
    }
  }
}

__global__ void k_cls(const float* __restrict__ cls, float* __restrict__ h){
  int t=blockIdx.x*256+threadIdx.x;
  if(t<2*DM) h[(size_t)(t>>9)*NTOK*DM + (t&511)]=cls[t&511];
}

// ---------------- layernorm + front zero-pad -> bf16 ----------------
__global__ __launch_bounds__(256) void k_lnpad(
    const float* __restrict__ h, const float* __restrict__ g,
    const float* __restrict__ bta, unsigned short* __restrict__ xln)
{
  int r=blockIdx.x;
  int bb=r>>14, i=r&16383;
  int t=threadIdx.x;
  unsigned short* dst=xln+(size_t)r*DM;
  if(i<PADF){ dst[t]=0; dst[t+256]=0; return; }
  const float* src=h+((size_t)bb*NTOK + (i-PADF))*DM;
  float x0=src[t], x1=src[t+256];
  __shared__ float s4[4];
  float mu=block_sum256(x0+x1,s4)*(1.f/512.f);
  float d0=x0-mu, d1=x1-mu;
  float var=block_sum256(d0*d0+d1*d1,s4)*(1.f/512.f);
  float rst=rsqrtf(var+1e-5f);
  dst[t]    =f2bf(d0*rst*g[t]    +bta[t]);
  dst[t+256]=f2bf(d1*rst*g[t+256]+bta[t+256]);
}

// ---------------- landmark means (bf16 in, f32+bf16 out) ----------------
__global__ void k_lmean(const unsigned short* __restrict__ src, float* __restrict__ dstf,
                        unsigned short* __restrict__ dstb){
  int bh=blockIdx.x>>8, s=blockIdx.x&255, d=threadIdx.x;  // 64 threads
  const unsigned short* p=src + (((size_t)bh*NPAD)+s*SEG)*HD + d;
  float acc=0.f;
  #pragma unroll
  for(int l=0;l<SEG;l++) acc+=bf2f(p[(size_t)l*HD]);
  float m=acc*(1.f/64.f);
  dstf[((size_t)bh*LM+s)*HD+d]=m;
  dstb[((size_t)bh*LM+s)*HD+d]=f2bf(m);
}

// ---------------- v f32 head-major -> vt bf16 [bh][64][NPAD] ----------------
__global__ __launch_bounds__(256) void k_vtrans(
    const float* __restrict__ v, unsigned short* __restrict__ vt)
{
  __shared__ unsigned short tile[64][72];
  int kt=blockIdx.x, bh=blockIdx.y;
  int t=threadIdx.x;
  int r=t>>2, sgq=t&3;
  const float* src=v + ((size_t)bh*NPAD + kt*64 + r)*HD + sgq*16;
  #pragma unroll
  for(int i=0;i<16;i+=4){
    float4 f4=*(const float4*)(src+i);
    tile[r][sgq*16+i  ]=f2bf(f4.x);
    tile[r][sgq*16+i+1]=f2bf(f4.y);
    tile[r][sgq*16+i+2]=f2bf(f4.z);
    tile[r][sgq*16+i+3]=f2bf(f4.w);
  }
  __syncthreads();
  int d=t>>2;
  union{unsigned short u[16]; short8v v8[2];} pk;
  #pragma unroll
  for(int i=0;i<16;i++) pk.u[i]=tile[sgq*16+i][d];
  short8v* dst=(short8v*)(vt + ((size_t)bh*HD + d)*NPAD + kt*64 + sgq*16);
  dst[0]=pk.v8[0]; dst[1]=pk.v8[1];
}

// ---------------- attn2 = softmax(ql @ kl^T) f32 + fused hi/lo split --------
__global__ __launch_bounds__(256) void k_attn2(
    const float* __restrict__ ql, const float* __restrict__ kl,
    float* __restrict__ attn2,
    unsigned short* __restrict__ a2h, unsigned short* __restrict__ a2l)
{
  __shared__ float qrow[64]; __shared__ float s4[4];
  int bh=blockIdx.x>>8, i=blockIdx.x&255, j=threadIdx.x;
  if(j<64) qrow[j]=ql[((size_t)bh*LM+i)*HD+j];
  __syncthreads();
  const float* kp=kl+((size_t)bh*LM+j)*HD;
  float l=0.f;
  #pragma unroll
  for(int d=0;d<64;d++) l+=qrow[d]*kp[d];
  float m=block_max256(l,s4);
  float e=__expf(l-m);
  float s=block_sum256(e,s4);
  float pv=e/s;
  size_t o=((size_t)bh*LM+i)*LM+j;
  attn2[o]=pv;
  unsigned short hh=f2bf(pv);
  a2h[o]=hh; a2l[o]=f2bf(pv-bf2f(hh));
}

// ---------------- pinv helpers (rowsum of softmax == 1, skip it) ------------
__global__ void k_colsum(const float* __restrict__ x, float* __restrict__ cs){
  int bh=blockIdx.x, j=threadIdx.x;
  const float* p=x+(size_t)bh*65536;
  float s=0.f;
  for(int i=0;i<256;i++) s+=p[(size_t)i*256+j];
  cs[bh*256+j]=s;
}
__global__ void k_pinvscale(const float* __restrict__ cs, float* __restrict__ scale){
  __shared__ float s4[4];
  float mc=-1e30f;
  for(int i=threadIdx.x;i<4096;i+=256) mc=fmaxf(mc,cs[i]);
  mc=block_max256(mc,s4);
  if(threadIdx.x==0) scale[0]=1.f/mc;
}
__global__ void k_zinit_hl(const float* __restrict__ x, const float* __restrict__ scale,
    unsigned short* __restrict__ zh, unsigned short* __restrict__ zl,
    unsigned short* __restrict__ zth, unsigned short* __restrict__ ztl){
  int bh=blockIdx.x>>8, i=blockIdx.x&255, j=threadIdx.x;
  float s=scale[0];
  size_t base=(size_t)bh*65536;
  float vn=x[base+(size_t)j*256+i]*s;   // z0[i][j] = X^T * s
  float vt=x[base+(size_t)i*256+j]*s;   // z0^T[i][j]
  size_t o=base+(size_t)i*256+j;
  unsigned short h=f2bf(vn); zh[o]=h; zl[o]=f2bf(vn-bf2f(h));
  h=f2bf(vt); zth[o]=h; ztl[o]=f2bf(vt-bf2f(h));
}

// ---------------- hi/lo split bf16 MFMA batched GEMM (pinv chain) -----------
// MODE 0: C=A@B (emit normal+trans)    MODE 1: C=15I-7X+acc (trans only)
// MODE 2: C=13I-acc (trans only)       MODE 3: C=0.25*acc (normal+trans)
// MODE 4: C=acc (trans only, hi only; Ndim=64)
// PREC 0: single bf16 product; PREC 1: hi/lo 3-product (f32-equivalent)
template<int MODE, int PREC>
__global__ __launch_bounds__(256) void k_bmm3(
    const unsigned short* __restrict__ Ah, const unsigned short* __restrict__ Al,
    const unsigned short* __restrict__ Bth, const unsigned short* __restrict__ Btl,
    const unsigned short* __restrict__ Xh, const unsigned short* __restrict__ Xl,
    unsigned short* __restrict__ Cnh, unsigned short* __restrict__ Cnl,
    unsigned short* __restrict__ Cth, unsigned short* __restrict__ Ctl,
    int Ndim)
{
  __shared__ unsigned short AsH[64*40], BsH[64*40];
  __shared__ unsigned short AsL[PREC?64*40:8], BsL[PREC?64*40:8];
  int bh=blockIdx.z;
  int n0=blockIdx.x*64, m0=blockIdx.y*64;
  int t=threadIdx.x, lane=t&63, w=t>>6;
  int c=lane&15, g=lane>>4;
  int wr=(w>>1)*32, wc=(w&1)*32;
  f32x4 acc[2][2];
  #pragma unroll
  for(int i=0;i<2;i++)
    #pragma unroll
    for(int j=0;j<2;j++) acc[i][j]=(f32x4){0.f,0.f,0.f,0.f};
  size_t Abase=(size_t)bh*65536;
  size_t Bbase=(size_t)bh*(size_t)Ndim*256;
  int r=t>>2, sg=t&3;
  const unsigned short* Aptr=Ah +Abase+(size_t)(m0+r)*256+sg*8;
  const unsigned short* Bptr=Bth+Bbase+(size_t)(n0+r)*256+sg*8;
  const unsigned short* Alptr=Al +Abase+(size_t)(m0+r)*256+sg*8;
  const unsigned short* Blptr=Btl+Bbase+(size_t)(n0+r)*256+sg*8;
  short8v rah, rbh, ral, rbl;
  rah=*(const short8v*)(Aptr);
  rbh=*(const short8v*)(Bptr);
  if constexpr(PREC==1){ ral=*(const short8v*)(Alptr); rbl=*(const short8v*)(Blptr); }
  int k0=0;
  for(;;){
    __syncthreads();
    *(short8v*)(AsH+r*40+sg*8)=rah;
    *(short8v*)(BsH+r*40+sg*8)=rbh;
    if constexpr(PREC==1){
      *(short8v*)(AsL+r*40+sg*8)=ral;
      *(short8v*)(BsL+r*40+sg*8)=rbl;
    }
    __syncthreads();
    int kn=k0+32;
    if(kn<256){
      rah=*(const short8v*)(Aptr+kn);
      rbh=*(const short8v*)(Bptr+kn);
      if constexpr(PREC==1){
        ral=*(const short8v*)(Alptr+kn);
        rbl=*(const short8v*)(Blptr+kn);
      }
    }
    short8v bhf[2], blf[2];
    #pragma unroll
    for(int nt=0;nt<2;nt++){
      bhf[nt]=*(const short8v*)(BsH+(wc+nt*16+c)*40+g*8);
      if constexpr(PREC==1) blf[nt]=*(const short8v*)(BsL+(wc+nt*16+c)*40+g*8);
    }
    #pragma unroll
    for(int mt=0;mt<2;mt++){
      short8v ahh=*(const short8v*)(AsH+(wr+mt*16+c)*40+g*8);
      short8v all;
      if constexpr(PREC==1) all=*(const short8v*)(AsL+(wr+mt*16+c)*40+g*8);
      #pragma unroll
      for(int nt=0;nt<2;nt++){
        acc[mt][nt]=__builtin_amdgcn_mfma_f32_16x16x32_bf16(ahh,bhf[nt],acc[mt][nt],0,0,0);
        if constexpr(PREC==1){
          acc[mt][nt]=__builtin_amdgcn_mfma_f32_16x16x32_bf16(ahh,blf[nt],acc[mt][nt],0,0,0);
          acc[mt][nt]=__builtin_amdgcn_mfma_f32_16x16x32_bf16(all,bhf[nt],acc[mt][nt],0,0,0);
        }
      }
    }
    if(kn>=256) break;
    k0=kn;
  }
  #pragma unroll
  for(int mt=0;mt<2;mt++)
    #pragma unroll
    for(int nt=0;nt<2;nt++){
      int rb=m0+wr+mt*16+g*4;
      int cc=n0+wc+nt*16+c;
      float vv[4];
      #pragma unroll
      for(int j=0;j<4;j++){
        float a=acc[mt][nt][j];
        int rr=rb+j;
        if(MODE==1){
          float xv=bf2f(Xh[Abase+(size_t)rr*256+cc])+bf2f(Xl[Abase+(size_t)rr*256+cc]);
          a=(rr==cc?15.f:0.f)-7.f*xv+a;
        } else if(MODE==2){
          a=(rr==cc?13.f:0.f)-a;
        } else if(MODE==3){
          a*=0.25f;
        }
        vv[j]=a;
      }
      if(MODE==0||MODE==3){
        #pragma unroll
        for(int j=0;j<4;j++){
          unsigned short h=f2bf(vv[j]);
          Cnh[Abase+(size_t)(rb+j)*256+cc]=h;
          Cnl[Abase+(size_t)(rb+j)*256+cc]=f2bf(vv[j]-bf2f(h));
        }
      }
      {
        ushort4 hv, lv;
        hv.x=f2bf(vv[0]); hv.y=f2bf(vv[1]); hv.z=f2bf(vv[2]); hv.w=f2bf(vv[3]);
        lv.x=f2bf(vv[0]-bf2f(hv.x)); lv.y=f2bf(vv[1]-bf2f(hv.y));
        lv.z=f2bf(vv[2]-bf2f(hv.z)); lv.w=f2bf(vv[3]-bf2f(hv.w));
        size_t co=((size_t)bh*Ndim+cc)*256+rb;
        *(ushort4*)(Cth+co)=hv;
        if(MODE!=4) *(ushort4*)(Ctl+co)=lv;
      }
    }
}

// ---------------- attn3@v : MFMA flash, split-K 16 chunks --------------------
__global__ __launch_bounds__(512) void k_attn3m(
    const unsigned short* __restrict__ qlb,
    const unsigned short* __restrict__ kb,
    const unsigned short* __restrict__ vtb,
    float* __restrict__ pacc, float* __restrict__ pms)
{
  __shared__ unsigned short Ks[64*72];
  __shared__ unsigned short Vs[64*72];
  int ck=blockIdx.x, bh=blockIdx.y;
  int t=threadIdx.x, lane=t&63, w=t>>6;
  int c=lane&15, g=lane>>4;
  short8v Qf[2][2];
  #pragma unroll
  for(int n=0;n<2;n++)
    #pragma unroll
    for(int kw=0;kw<2;kw++)
      Qf[n][kw]=*(const short8v*)(qlb + ((size_t)bh*LM + w*32 + n*16 + c)*HD + kw*32 + g*8);
  f32x4 accO[4][2];
  float mrun[2], srun[2];
  #pragma unroll
  for(int n=0;n<2;n++){
    mrun[n]=-3e38f; srun[n]=0.f;
    #pragma unroll
    for(int d=0;d<4;d++) accO[d][n]=(f32x4){0.f,0.f,0.f,0.f};
  }
  int sr=t>>3, sgk=t&7;
  for(int sc=0;sc<16;++sc){
    int key0=ck*1024 + sc*64;
    __syncthreads();
    *(short8v*)(Ks + sr*72 + sgk*8) =
      *(const short8v*)(kb + ((size_t)bh*NPAD + key0 + sr)*HD + sgk*8);
    *(short8v*)(Vs + sr*72 + sgk*8) =
      *(const short8v*)(vtb + ((size_t)bh*HD + sr)*NPAD + key0 + sgk*8);
    __syncthreads();
    f32x4 s[4][2];
    #pragma unroll
    for(int mt=0;mt<4;mt++){
      short8v a0=*(const short8v*)(Ks + (mt*16+c)*72 + g*8);
      short8v a1=*(const short8v*)(Ks + (mt*16+c)*72 + 32 + g*8);
      #pragma unroll
      for(int n=0;n<2;n++){
        f32x4 z=(f32x4){0.f,0.f,0.f,0.f};
        z=__builtin_amdgcn_mfma_f32_16x16x32_bf16(a0,Qf[n][0],z,0,0,0);
        z=__builtin_amdgcn_mfma_f32_16x16x32_bf16(a1,Qf[n][1],z,0,0,0);
        s[mt][n]=z;
      }
    }
    unsigned U[2][4][2];
    #pragma unroll
    for(int n=0;n<2;n++){
      float cm=-3e38f;
      #pragma unroll
      for(int mt=0;mt<4;mt++)
        #pragma unroll
        for(int j=0;j<4;j++) cm=fmaxf(cm,s[mt][n][j]);
      cm=fmaxf(cm,__shfl_xor(cm,16));
      cm=fmaxf(cm,__shfl_xor(cm,32));
      float mnew=fmaxf(mrun[n],cm);
      float f=__expf(mrun[n]-mnew);
      mrun[n]=mnew;
      float ps=0.f;
      #pragma unroll
      for(int mt=0;mt<4;mt++){
        float p0=__expf(s[mt][n][0]-mnew);
        float p1=__expf(s[mt][n][1]-mnew);
        float p2=__expf(s[mt][n][2]-mnew);
        float p3=__expf(s[mt][n][3]-mnew);
        ps+=p0+p1+p2+p3;
        U[n][mt][0]=cvtpk(p0,p1);
        U[n][mt][1]=cvtpk(p2,p3);
      }
      ps+=__shfl_xor(ps,16); ps+=__shfl_xor(ps,32);
      srun[n]=srun[n]*f+ps;
      #pragma unroll
      for(int d=0;d<4;d++){
        accO[d][n][0]*=f; accO[d][n][1]*=f; accO[d][n][2]*=f; accO[d][n][3]*=f;
      }
    }
    #pragma unroll
    for(int kw=0;kw<2;kw++){
      short8v pf[2];
      #pragma unroll
      for(int n=0;n<2;n++){
        union{unsigned u[4]; short8v v;} pk;
        #pragma unroll
        for(int wd=0;wd<4;wd++){
          int sl=c+16*(((g&1)<<1)+(wd>>1));
          unsigned va=(unsigned)__shfl((int)U[n][kw*2  ][wd&1],sl);
          unsigned vb=(unsigned)__shfl((int)U[n][kw*2+1][wd&1],sl);
          pk.u[wd]=(lane>=32)?vb:va;
        }
        pf[n]=pk.v;
      }
      #pragma unroll
      for(int d=0;d<4;d++){
        short8v vf=*(const short8v*)(Vs + (d*16+c)*72 + kw*32 + g*8);
        accO[d][0]=__builtin_amdgcn_mfma_f32_16x16x32_bf16(vf,pf[0],accO[d][0],0,0,0);
        accO[d][1]=__builtin_amdgcn_mfma_f32_16x16x32_bf16(vf,pf[1],accO[d][1],0,0,0);
      }
    }
  }
  size_t pb=((size_t)bh*16+ck)*LM;
  #pragma unroll
  for(int n=0;n<2;n++){
    int q=w*32+n*16+c;
    #pragma unroll
    for(int d=0;d<4;d++)
      *(f32x4*)(pacc + (pb+q)*HD + d*16 + g*4)=accO[d][n];
    if(g==0){ pms[(pb+q)*2]=mrun[n]; pms[(pb+q)*2+1]=srun[n]; }
  }
}
__global__ __launch_bounds__(256) void k_attn3vc(
    const float* __restrict__ pacc, const float* __restrict__ pms,
    unsigned short* __restrict__ a3vth, unsigned short* __restrict__ a3vtl)
{
  int gid=blockIdx.x*4+(threadIdx.x>>6);
  int bh=gid>>8, row=gid&255, lane=threadIdx.x&63;
  float M=-3e38f;
  float ms[16], ss[16];
  #pragma unroll
  for(int c=0;c<16;c++){
    size_t pb=((size_t)bh*16+c)*LM+row;
    ms[c]=pms[pb*2]; ss[c]=pms[pb*2+1];
    M=fmaxf(M,ms[c]);
  }
  float S=0.f,a=0.f;
  #pragma unroll
  for(int c=0;c<16;c++){
    float f=__expf(ms[c]-M);
    S+=ss[c]*f;
    a+=pacc[(((size_t)bh*16+c)*LM+row)*HD+lane]*f;
  }
  float v=a/S;
  unsigned short hi=f2bf(v);
  a3vth[((size_t)bh*HD+lane)*LM+row]=hi;
  a3vtl[((size_t)bh*HD+lane)*LM+row]=f2bf(v-bf2f(hi));
}

// ---------------- attn1 @ W2 : MFMA, 256 landmarks one-shot ------------------
__global__ __launch_bounds__(512) void k_attn1m(
    const unsigned short* __restrict__ qb,
    const unsigned short* __restrict__ klb,
    const unsigned short* __restrict__ w2t,
    float* __restrict__ aoh)
{
  __shared__ unsigned short klS[256*72];
  __shared__ unsigned short w2S[64*264];
  int qt=blockIdx.x, bh=blockIdx.y;
  int t=threadIdx.x, lane=t&63, w=t>>6;
  int c=lane&15, g=lane>>4;
  {
    int r=t>>1, hf=t&1;
    const short8v* s=(const short8v*)(klb + ((size_t)bh*LM+r)*HD + hf*32);
    short8v* d=(short8v*)(klS + r*72 + hf*32);
    d[0]=s[0]; d[1]=s[1]; d[2]=s[2]; d[3]=s[3];
    int r2=t>>3, sg2=t&7;
    const short8v* s2=(const short8v*)(w2t + ((size_t)bh*HD+r2)*LM + sg2*32);
    short8v* d2=(short8v*)(w2S + r2*264 + sg2*32);
    d2[0]=s2[0]; d2[1]=s2[1]; d2[2]=s2[2]; d2[3]=s2[3];
  }
  __syncthreads();
  int q0=qt*256 + w*32;
  #pragma unroll
  for(int n=0;n<2;n++){
    const unsigned short* qrow=qb + ((size_t)bh*NPAD + q0 + n*16 + c)*HD;
    short8v qf0=*(const short8v*)(qrow + g*8);
    short8v qf1=*(const short8v*)(qrow + 32 + g*8);
    f32x4 s[16];
    #pragma unroll
    for(int mt=0;mt<16;mt++){
      short8v a0=*(const short8v*)(klS + (mt*16+c)*72 + g*8);
      short8v a1=*(const short8v*)(klS + (mt*16+c)*72 + 32 + g*8);
      f32x4 z=(f32x4){0.f,0.f,0.f,0.f};
      z=__builtin_amdgcn_mfma_f32_16x16x32_bf16(a0,qf0,z,0,0,0);
      z=__builtin_amdgcn_mfma_f32_16x16x32_bf16(a1,qf1,z,0,0,0);
      s[mt]=z;
    }
    float M=-3e38f;
    #pragma unroll
    for(int mt=0;mt<16;mt++)
      #pragma unroll
      for(int j=0;j<4;j++) M=fmaxf(M,s[mt][j]);
    M=fmaxf(M,__shfl_xor(M,16));
    M=fmaxf(M,__shfl_xor(M,32));
    float sum=0.f;
    unsigned U[16][2];
    #pragma unroll
    for(int mt=0;mt<16;mt++){
      float p0=__expf(s[mt][0]-M);
      float p1=__expf(s[mt][1]-M);
      float p2=__expf(s[mt][2]-M);
      float p3=__expf(s[mt][3]-M);
      sum+=p0+p1+p2+p3;
      U[mt][0]=cvtpk(p0,p1);
      U[mt][1]=cvtpk(p2,p3);
    }
    sum+=__shfl_xor(sum,16); sum+=__shfl_xor(sum,32);
    float inv=1.f/sum;
    f32x4 accO[4];
    #pragma unroll
    for(int d=0;d<4;d++) accO[d]=(f32x4){0.f,0.f,0.f,0.f};
    #pragma unroll
    for(int kw=0;kw<8;kw++){
      union{unsigned u[4]; short8v v;} pk;
      #pragma unroll
      for(int wd=0;wd<4;wd++){
        int sl=c+16*(((g&1)<<1)+(wd>>1));
        unsigned va=(unsigned)__shfl((int)U[kw*2  ][wd&1],sl);
        unsigned vb=(unsigned)__shfl((int)U[kw*2+1][wd&1],sl);
        pk.u[wd]=(lane>=32)?vb:va;
      }
      #pragma unroll
      for(int d=0;d<4;d++){
        short8v vf=*(const short8v*)(w2S + (d*16+c)*264 + kw*32 + g*8);
        accO[d]=__builtin_amdgcn_mfma_f32_16x16x32_bf16(vf,pk.v,accO[d],0,0,0);
      }
    }
    int q=q0+n*16+c;
    #pragma unroll
    for(int d=0;d<4;d++){
      f32x4 o=accO[d];
      o[0]*=inv; o[1]*=inv; o[2]*=inv; o[3]*=inv;
      *(f32x4*)(aoh + ((size_t)bh*NPAD+q)*HD + d*16 + g*4)=o;
    }
  }
}

// ---------------- depthwise 33-tap conv on v, += into aoh (4 pos/thread) ----
__global__ void k_resconv(const float* __restrict__ vv, const float* __restrict__ rw,
                          float* __restrict__ aoh){
  size_t idx=(size_t)blockIdx.x*256+threadIdx.x;  // 2*8*4096*64
  int d=(int)(idx&63); size_t r=idx>>6;
  int i4=(int)(r&4095)*4; int bh=(int)(r>>12); int hh=bh&7;
  const float* vb=vv+((size_t)bh*NPAD)*HD+d;
  float wv[36];
  #pragma unroll
  for(int t2=0;t2<36;t2++){
    int src=i4-16+t2;
    wv[t2]=(src>=0&&src<NPAD)?vb[(size_t)src*HD]:0.f;
  }
  const float* wt=rw+hh*33;
  #pragma unroll
  for(int p=0;p<4;p++){
    float a=0.f;
    #pragma unroll
    for(int tk=0;tk<33;tk++) a+=wv[p+tk]*wt[tk];
    aoh[((size_t)bh*NPAD+i4+p)*HD+d]+=a;
  }
}

// ---------------- PPEG weight prep: combined 7x7 tap table (bf16) -----------
__global__ void k_wprep(const float* __restrict__ w7, const float* __restrict__ b7,
                        const float* __restrict__ w5, const float* __restrict__ b5,
                        const float* __restrict__ w3, const float* __restrict__ b3,
                        unsigned short* __restrict__ wcat){
  int t=blockIdx.x*256+threadIdx.x;
  if(t>=50*512) return;
  int r=t>>9, c=t&511;
  float v;
  if(r<49){
    int ky=r/7, kx=r%7;
    v=w7[(size_t)c*49+r];
    if(ky>=1&&ky<=5&&kx>=1&&kx<=5) v+=w5[(size_t)c*25+(ky-1)*5+(kx-1)];
    if(ky>=2&&ky<=4&&kx>=2&&kx<=4) v+=w3[(size_t)c*9+(ky-2)*3+(kx-2)];
  } else {
    v=b7[c]+b5[c]+b3[c];
  }
  wcat[t]=f2bf(v);
}

// ---------------- PPEG: LDS-tiled 6x6x64ch combined 7x7 stencil, f32 --------
__global__ __launch_bounds__(256,3) void k_ppeg3(
    const float* __restrict__ src, const unsigned short* __restrict__ wcat,
    float* __restrict__ dst)
{
  __shared__ float patch[144][64];
  __shared__ float wsf[50][64];
  int gx=blockIdx.x%22, gy=blockIdx.x/22;
  int cz=blockIdx.y, bb=blockIdx.z;
  int t=threadIdx.x, c=t&63, g=t>>6;
  int ty0=gy*6, tx0=gx*6;
  const float* base=src+((size_t)bb*NTOK+1)*DM + cz*64 + c;
  #pragma unroll
  for(int i=0;i<36;i++){
    int p=g+4*i;
    int py=p/12, px=p%12;
    int yy=ty0-3+py, xx=tx0-3+px;
    float v=0.f;
    if(yy>=0&&yy<127&&xx>=0&&xx<127) v=base[(size_t)(yy*127+xx)*DM];
    patch[p][c]=v;
  }
  #pragma unroll
  for(int i=0;i<13;i++){
    int r=g+4*i; if(r<50) wsf[r][c]=bf2f(wcat[(size_t)r*DM + cz*64 + c]);
  }
  __syncthreads();
  float acc[9];
  int oy[9], ox[9];
  float bias=wsf[49][c];
  #pragma unroll
  for(int i=0;i<9;i++){
    int p=g*9+i; oy[i]=p/6; ox[i]=p%6;
    acc[i]=patch[(oy[i]+3)*12+(ox[i]+3)][c]+bias;   // exact identity from f32 patch
  }
  for(int ky=0;ky<7;ky++)
    for(int kx=0;kx<7;kx++){
      float wv=wsf[ky*7+kx][c];
      #pragma unroll
      for(int i=0;i<9;i++)
        acc[i]+=patch[(oy[i]+ky)*12+ox[i]+kx][c]*wv;
    }
  #pragma unroll
  for(int i=0;i<9;i++){
    int y=ty0+oy[i], x=tx0+ox[i];
    if(y<127&&x<127)
      dst[((size_t)bb*NTOK+1+(size_t)(y*127+x))*DM + cz*64 + c]=acc[i];
  }
}

// copy cls row h -> dst (so full-buffer copy-back is valid)
__global__ void k_cpcls(const float* __restrict__ h, float* __restrict__ dst){
  int t=blockIdx.x*256+threadIdx.x;
  if(t<2*DM) dst[(size_t)(t>>9)*NTOK*DM + (t&511)]=h[(size_t)(t>>9)*NTOK*DM + (t&511)];
}

// ---------------- final: LN(h[:,0]) @ fc2 + b ----------------
__global__ __launch_bounds__(256) void k_final(
    const float* __restrict__ h, const float* __restrict__ g, const float* __restrict__ bta,
    const float* __restrict__ w, const float* __restrict__ fb, float* __restrict__ out)
{
  int bb=blockIdx.x, t=threadIdx.x;
  const float* src=h+(size_t)bb*NTOK*DM;
  float x0=src[t], x1=src[t+256];
  __shared__ float s4[4];
  float mu=block_sum256(x0+x1,s4)*(1.f/512.f);
  float d0=x0-mu, d1=x1-mu;
  float var=block_sum256(d0*d0+d1*d1,s4)*(1.f/512.f);
  float rst=rsqrtf(var+1e-5f);
  float y0=d0*rst*g[t]+bta[t], y1=d1*rst*g[t+256]+bta[t+256];
  float dot=block_sum256(y0*w[t]+y1*w[t+256],s4);
  if(t==0) out[bb]=dot+fb[0];
}

// =======================================================================
extern "C" void kernel_launch(void* const* d_in, const int* in_sizes, int n_in,
                              void* d_out, int out_size, void* d_ws, size_t ws_size,
                              hipStream_t stream){
  (void)in_sizes; (void)n_in; (void)out_size; (void)ws_size;
  const float* features=(const float*)d_in[0];
  const float* fc1_w  =(const float*)d_in[1];
  const float* fc1_b  =(const float*)d_in[2];
  const float* cls_tok=(const float*)d_in[3];
  const float* fc2_w  =(const float*)d_in[24];
  const float* fc2_b  =(const float*)d_in[25];
  float* out=(float*)d_out;

  char* wp=(char*)d_ws;
  auto allocB=[&](size_t bytes)->char*{
    char* p=wp; wp+=((bytes+255)/256)*256; return p;
  };
  float* h    =(float*)allocB((size_t)NB*NTOK*DM*4);
  float* v    =(float*)allocB((size_t)NB*NPAD*DM*4);
  unsigned short* xlnb=(unsigned short*)allocB((size_t)NB*NPAD*DM*2);
  unsigned short* qb  =(unsigned short*)allocB((size_t)NB*NPAD*DM*2);
  unsigned short* kb  =(unsigned short*)allocB((size_t)NB*NPAD*DM*2);
  unsigned short* vtb =(unsigned short*)allocB((size_t)NB*NPAD*DM*2);
  float* aoh  =(float*)allocB((size_t)NB*NPAD*DM*4);
  unsigned short* wtf=(unsigned short*)allocB((size_t)512*1024*2);
  unsigned short* wtq=(unsigned short*)allocB((size_t)1536*512*2);
  unsigned short* wtp=(unsigned short*)allocB((size_t)512*512*2);
  float* ql =(float*)allocB((size_t)16*LM*HD*4);
  float* kl =(float*)allocB((size_t)16*LM*HD*4);
  unsigned short* qlb=(unsigned short*)allocB((size_t)16*LM*HD*2);
  unsigned short* klb=(unsigned short*)allocB((size_t)16*LM*HD*2);
  float* attn2=(float*)allocB((size_t)16*LM*LM*4);
  unsigned short* a2h=(unsigned short*)allocB((size_t)16*LM*LM*2);
  unsigned short* a2l=(unsigned short*)allocB((size_t)16*LM*LM*2);
  unsigned short* zb[8];
  for(int i=0;i<8;i++) zb[i]=(unsigned short*)allocB((size_t)16*LM*LM*2);
  unsigned short* Abh=(unsigned short*)allocB((size_t)16*LM*LM*2);
  unsigned short* Abl=(unsigned short*)allocB((size_t)16*LM*LM*2);
  unsigned short* Abth=(unsigned short*)allocB((size_t)16*LM*LM*2);
  unsigned short* Abtl=(unsigned short*)allocB((size_t)16*LM*LM*2);
  unsigned short* Ubth=(unsigned short*)allocB((size_t)16*LM*LM*2);
  unsigned short* Ubtl=(unsigned short*)allocB((size_t)16*LM*LM*2);
  unsigned short* Tbth=(unsigned short*)allocB((size_t)16*LM*LM*2);
  unsigned short* Tbtl=(unsigned short*)allocB((size_t)16*LM*LM*2);
  unsigned short* a3vth=(unsigned short*)allocB((size_t)16*HD*LM*2);
  unsigned short* a3vtl=(unsigned short*)allocB((size_t)16*HD*LM*2);
  unsigned short* w2t=(unsigned short*)allocB((size_t)16*HD*LM*2);
  float* pacc=(float*)allocB((size_t)16*16*LM*HD*4);
  float* pms =(float*)allocB((size_t)16*16*LM*2*4);
  float* cs  =(float*)allocB(4096*4);
  float* scl =(float*)allocB(64*4);

  auto nystrom=[&](const float* ng, const float* nbias, const float* qkvw,
                   const float* outw, const float* outb, const float* resw){
    k_lnpad<<<NB*NPAD,256,0,stream>>>(h, ng, nbias, xlnb);
    k_wconv_t<<<(512*1536+255)/256,256,0,stream>>>(qkvw, wtq, 512, 1536);
    k_mfma_gemm<1,0><<<dim3(12,256),256,0,stream>>>(xlnb, wtq, 32768,1536,512,
                                                    nullptr, qb, kb, v);
    k_lmean<<<4096,64,0,stream>>>(qb, ql, qlb);
    k_lmean<<<4096,64,0,stream>>>(kb, kl, klb);
    k_vtrans<<<dim3(256,16),256,0,stream>>>(v, vtb);
    k_attn2<<<4096,256,0,stream>>>(ql, kl, attn2, a2h, a2l);
    k_colsum<<<16,256,0,stream>>>(attn2, cs);
    k_pinvscale<<<1,256,0,stream>>>(cs, scl);
    k_zinit_hl<<<4096,256,0,stream>>>(attn2, scl, zb[0],zb[1],zb[2],zb[3]);
    unsigned short *zch=zb[0],*zcl=zb[1],*zcth=zb[2],*zctl=zb[3];
    unsigned short *znh=zb[4],*znl=zb[5],*znth=zb[6],*zntl=zb[7];
    for(int it=0;it<6;it++){
      if(it<5){
        k_bmm3<0,0><<<dim3(4,4,16),256,0,stream>>>(a2h,a2l, zcth,zctl, nullptr,nullptr,
                                                   Abh,Abl, Abth,Abtl, 256);
        k_bmm3<1,0><<<dim3(4,4,16),256,0,stream>>>(Abh,Abl, Abth,Abtl, Abh,Abl,
                                                   nullptr,nullptr, Ubth,Ubtl, 256);
        k_bmm3<2,0><<<dim3(4,4,16),256,0,stream>>>(Abh,Abl, Ubth,Ubtl, nullptr,nullptr,
                                                   nullptr,nullptr, Tbth,Tbtl, 256);
        k_bmm3<3,0><<<dim3(4,4,16),256,0,stream>>>(zch,zcl, Tbth,Tbtl, nullptr,nullptr,
                                                   znh,znl, znth,zntl, 256);
      } else {
        k_bmm3<0,1><<<dim3(4,4,16),256,0,stream>>>(a2h,a2l, zcth,zctl, nullptr,nullptr,
                                                   Abh,Abl, Abth,Abtl, 256);
        k_bmm3<1,1><<<dim3(4,4,16),256,0,stream>>>(Abh,Abl, Abth,Abtl, Abh,Abl,
                                                   nullptr,nullptr, Ubth,Ubtl, 256);
        k_bmm3<2,1><<<dim3(4,4,16),256,0,stream>>>(Abh,Abl, Ubth,Ubtl, nullptr,nullptr,
                                                   nullptr,nullptr, Tbth,Tbtl, 256);
        k_bmm3<3,1><<<dim3(4,4,16),256,0,stream>>>(zch,zcl, Tbth,Tbtl, nullptr,nullptr,
                                                   znh,znl, znth,zntl, 256);
      }
      unsigned short* tp;
      tp=zch; zch=znh; znh=tp;  tp=zcl; zcl=znl; znl=tp;
      tp=zcth; zcth=znth; znth=tp;  tp=zctl; zctl=zntl; zntl=tp;
    }
    k_attn3m<<<dim3(16,16),512,0,stream>>>(qlb, kb, vtb, pacc, pms);
    k_attn3vc<<<1024,256,0,stream>>>(pacc, pms, a3vth, a3vtl);
    k_bmm3<4,1><<<dim3(1,4,16),256,0,stream>>>(zch,zcl, a3vth,a3vtl, nullptr,nullptr,
                                               nullptr,nullptr, w2t,nullptr, 64);
    k_attn1m<<<dim3(64,16),512,0,stream>>>(qb, klb, w2t, aoh);
    k_resconv<<<16384,256,0,stream>>>(v, resw, aoh);
    k_wconv_t<<<(512*512+255)/256,256,0,stream>>>(outw, wtp, 512, 512);
    k_mfma_gemm<2,2><<<dim3(4,256),256,0,stream>>>(aoh, wtp, 32768,512,512,
                                                   outb, h, nullptr, nullptr);
  };

  // fc1 + relu + dup + cls (bf16 MFMA, fused f32->bf16 A staging)
  k_wconv_t<<<(1024*512+255)/256,256,0,stream>>>(fc1_w, wtf, 1024, 512);
  k_mfma_gemm<0,1><<<dim3(4,250),256,0,stream>>>(features, wtf, 32000,512,1024,
                                                 fc1_b, h, nullptr, nullptr);
  k_cls<<<4,256,0,stream>>>(cls_tok, h);

  // layer 1 attention
  nystrom((const float*)d_in[4],(const float*)d_in[5],(const float*)d_in[6],
          (const float*)d_in[7],(const float*)d_in[8],(const float*)d_in[9]);

  // PPEG: combined-tap stencil h -> aoh, then copy back into h
  {
    unsigned short* wcat=(unsigned short*)attn2;  // free at this point
    k_wprep<<<100,256,0,stream>>>(
        (const float*)d_in[10],(const float*)d_in[11],
        (const float*)d_in[12],(const float*)d_in[13],
        (const float*)d_in[14],(const float*)d_in[15], wcat);
    k_cpcls<<<4,256,0,stream>>>(h, aoh);
    k_ppeg3<<<dim3(484,8,2),256,0,stream>>>(h, wcat, aoh);
    hipMemcpyAsync(h, aoh, (size_t)NB*NTOK*DM*4, hipMemcpyDeviceToDevice, stream);
  }

  // layer 2 attention
  nystrom((const float*)d_in[16],(const float*)d_in[17],(const float*)d_in[18],
          (const float*)d_in[19],(const float*)d_in[20],(const float*)d_in[21]);

  // final LN(row0) @ fc2
  k_final<<<2,256,0,stream>>>(h,(const float*)d_in[22],(const float*)d_in[23],
                              fc2_w, fc2_b, out);
}